// Round 4
// baseline (24717.470 us; speedup 1.0000x reference)
//
#include <hip/hip_runtime.h>
#include <hip/hip_bf16.h>

#define NB   16384
#define TT   50
#define HH   30
#define IND  8
#define CTXD 80
#define IN2  82
#define F2   52
#define NOUT 50
#define HID  100
#define CVD  20
#define ROWS 64
#define GRP  16
#define SSTR 36   // LDS h row stride (floats)

// transposed weight table offsets (floats) in global ws
#define WTX0 0
#define WTH0 1024
#define WTX1 4864
#define WTH1 8704
#define DTC  12544
#define DTTY 22784
#define DTH0 23040
#define DTX1 26880
#define DTH1 30720
#define WTTOT 34560
// encoder LDS copy: wt[0 .. 12544)
#define ENC_WL 12544
// dec LDS copy: wt[22784 .. 34560) -> local offsets
#define DEC_WL   11776
#define LTT      0
#define LTY      128
#define LWH0     256
#define LWX1     4096
#define LWH1     7936

__device__ __forceinline__ float sg(float x){
  x = fminf(fmaxf(x, -30.f), 30.f);
  return 1.f/(1.f+__expf(-x));
}
__device__ __forceinline__ float th(float x){
  x = fminf(fmaxf(x, -15.f), 15.f);
  float e = __expf(2.f*x);
  return (e-1.f)/(e+1.f);
}
__device__ __forceinline__ float ldv(const float* p){ return *p; }
__device__ __forceinline__ float ldv(const __hip_bfloat16* p){ return __bfloat162float(*p); }
__device__ __forceinline__ void stv(float* p, float v){ *p = v; }
__device__ __forceinline__ void stv(__hip_bfloat16* p, float v){ *p = __float2bfloat16(v); }

// ---------------- weight transpose into ws: wt[sec][k][j*4+g] ----------------
__global__ void k_tw(const float* __restrict__ wih0, const float* __restrict__ whh0,
                     const float* __restrict__ wih1, const float* __restrict__ whh1,
                     const float* __restrict__ w2ih0, const float* __restrict__ w2hh0,
                     const float* __restrict__ w2ih1, const float* __restrict__ w2hh1,
                     float* __restrict__ wt)
{
  int idx = blockIdx.x*256 + threadIdx.x;
  if (idx >= WTTOT) return;
  int start, sel;
  if      (idx < WTH0){ start = WTX0; sel = 0; }
  else if (idx < WTX1){ start = WTH0; sel = 1; }
  else if (idx < WTH1){ start = WTX1; sel = 2; }
  else if (idx < DTC ){ start = WTH1; sel = 3; }
  else if (idx < DTTY){ start = DTC;  sel = 4; }
  else if (idx < DTH0){ start = DTTY; sel = 5; }
  else if (idx < DTX1){ start = DTH0; sel = 6; }
  else if (idx < DTH1){ start = DTX1; sel = 7; }
  else               { start = DTH1; sel = 8; }
  int local = idx - start;
  int k = local >> 7;          // /128
  int col = local & 127;
  int j = col >> 2, g = col & 3;
  int jc = j < HH ? j : HH-1;
  int row = g*HH + jc;
  float v;
  switch (sel){
    case 0: v = wih0[(size_t)row*IND + k]; break;
    case 1: v = whh0[(size_t)row*HH + k]; break;
    case 2: v = wih1[(size_t)row*HH + k]; break;
    case 3: v = whh1[(size_t)row*HH + k]; break;
    case 4: v = w2ih0[(size_t)row*IN2 + k]; break;
    case 5: v = w2ih0[(size_t)row*IN2 + 80 + k]; break;
    case 6: v = w2hh0[(size_t)row*HH + k]; break;
    case 7: v = w2ih1[(size_t)row*HH + k]; break;
    default: v = w2hh1[(size_t)row*HH + k]; break;
  }
  wt[idx] = v;
}

// ---------------- zero BN1 accumulators ----------------
__global__ void k_zero(double* a){
  int i = threadIdx.x;
  if (i < CTXD*2) a[i] = 0.0;
}

// ---------------- encoder LSTM ----------------
__global__ __launch_bounds__(ROWS*GRP) void k_encoder(
    const float* __restrict__ x, const float* __restrict__ h0i, const float* __restrict__ c0i,
    const float* __restrict__ bih0, const float* __restrict__ bhh0,
    const float* __restrict__ bih1, const float* __restrict__ bhh1,
    const float* __restrict__ wt,
    float* __restrict__ h0f, float* __restrict__ h1f,
    float* __restrict__ c0f, float* __restrict__ c1f)
{
  __shared__ float WL[ENC_WL];
  __shared__ float HA[2*ROWS*SSTR];
  __shared__ float HB[2*ROWS*SSTR];
  const int r  = threadIdx.x;
  const int b  = blockIdx.x*ROWS + r;
  const int tid = threadIdx.y*ROWS + r;
  for (int i = tid; i < ENC_WL; i += ROWS*GRP) WL[i] = wt[i];
  const int wy = __builtin_amdgcn_readfirstlane((int)threadIdx.y);
  const int ub = 2*wy;
  const int j4 = 8*wy;
  const float* __restrict__ Wx0 = WL + WTX0 + j4;
  const float* __restrict__ Wh0 = WL + WTH0 + j4;
  const float* __restrict__ Wx1 = WL + WTX1 + j4;
  const float* __restrict__ Wh1 = WL + WTH1 + j4;
  float c0[2], c1[2], bs0[8], bs1[8];
  #pragma unroll
  for (int jj=0;jj<2;++jj){
    const int jc = (ub+jj)<HH ? (ub+jj) : HH-1;
    c0[jj] = c0i[jc]; c1[jj] = c0i[HH+jc];
    #pragma unroll
    for (int g=0;g<4;++g){
      bs0[jj*4+g] = bih0[g*HH+jc] + bhh0[g*HH+jc];
      bs1[jj*4+g] = bih1[g*HH+jc] + bhh1[g*HH+jc];
    }
  }
  #pragma unroll
  for (int jj=0;jj<2;++jj){
    const int j = ub+jj;
    float v0 = (j<HH) ? h0i[j]    : 0.f;
    float v1 = (j<HH) ? h0i[HH+j] : 0.f;
    if (j < 32){ HA[(0*ROWS+r)*SSTR + j] = v0; HB[(0*ROWS+r)*SSTR + j] = v1; }
  }
  __syncthreads();
  int cur = 0;
  for (int t=0;t<TT;++t){
    const int nxt = cur^1;
    const float4* xp = (const float4*)(x + ((size_t)b*TT + t)*IND);
    float4 xa = xp[0], xb = xp[1];
    float xv[8] = {xa.x,xa.y,xa.z,xa.w, xb.x,xb.y,xb.z,xb.w};
    float hr0[32];
    {
      const float4* hp = (const float4*)&HA[(cur*ROWS+r)*SSTR];
      #pragma unroll
      for (int i=0;i<8;++i){ float4 v = hp[i]; hr0[4*i]=v.x; hr0[4*i+1]=v.y; hr0[4*i+2]=v.z; hr0[4*i+3]=v.w; }
    }
    float acc[8];
    #pragma unroll
    for (int i=0;i<8;++i) acc[i] = bs0[i];
    #pragma unroll
    for (int k=0;k<IND;++k){
      const float v = xv[k];
      float4 wa = *(const float4*)(Wx0 + k*128);
      float4 wb = *(const float4*)(Wx0 + k*128 + 4);
      acc[0]+=v*wa.x; acc[1]+=v*wa.y; acc[2]+=v*wa.z; acc[3]+=v*wa.w;
      acc[4]+=v*wb.x; acc[5]+=v*wb.y; acc[6]+=v*wb.z; acc[7]+=v*wb.w;
    }
    #pragma unroll
    for (int k=0;k<HH;++k){
      const float v = hr0[k];
      float4 wa = *(const float4*)(Wh0 + k*128);
      float4 wb = *(const float4*)(Wh0 + k*128 + 4);
      acc[0]+=v*wa.x; acc[1]+=v*wa.y; acc[2]+=v*wa.z; acc[3]+=v*wa.w;
      acc[4]+=v*wb.x; acc[5]+=v*wb.y; acc[6]+=v*wb.z; acc[7]+=v*wb.w;
    }
    #pragma unroll
    for (int jj=0;jj<2;++jj){
      float iv=sg(acc[jj*4+0]), fv=sg(acc[jj*4+1]), gv=th(acc[jj*4+2]), ov=sg(acc[jj*4+3]);
      float cn = fv*c0[jj] + iv*gv;
      c0[jj] = cn;
      if (ub+jj<HH) HA[(nxt*ROWS+r)*SSTR + ub+jj] = ov*th(cn);
      else if (ub+jj<32) HA[(nxt*ROWS+r)*SSTR + ub+jj] = 0.f;
    }
    __syncthreads();
    float hr0n[32], hr1[32];
    {
      const float4* hp = (const float4*)&HA[(nxt*ROWS+r)*SSTR];
      const float4* hq = (const float4*)&HB[(cur*ROWS+r)*SSTR];
      #pragma unroll
      for (int i=0;i<8;++i){
        float4 v = hp[i]; hr0n[4*i]=v.x; hr0n[4*i+1]=v.y; hr0n[4*i+2]=v.z; hr0n[4*i+3]=v.w;
        float4 u = hq[i]; hr1[4*i]=u.x;  hr1[4*i+1]=u.y;  hr1[4*i+2]=u.z;  hr1[4*i+3]=u.w;
      }
    }
    #pragma unroll
    for (int i=0;i<8;++i) acc[i] = bs1[i];
    #pragma unroll
    for (int k=0;k<HH;++k){
      const float a = hr0n[k], bb = hr1[k];
      float4 wa = *(const float4*)(Wx1 + k*128);
      float4 wb = *(const float4*)(Wx1 + k*128 + 4);
      float4 ua = *(const float4*)(Wh1 + k*128);
      float4 ub4 = *(const float4*)(Wh1 + k*128 + 4);
      acc[0]+=a*wa.x+bb*ua.x; acc[1]+=a*wa.y+bb*ua.y; acc[2]+=a*wa.z+bb*ua.z; acc[3]+=a*wa.w+bb*ua.w;
      acc[4]+=a*wb.x+bb*ub4.x; acc[5]+=a*wb.y+bb*ub4.y; acc[6]+=a*wb.z+bb*ub4.z; acc[7]+=a*wb.w+bb*ub4.w;
    }
    #pragma unroll
    for (int jj=0;jj<2;++jj){
      float iv=sg(acc[jj*4+0]), fv=sg(acc[jj*4+1]), gv=th(acc[jj*4+2]), ov=sg(acc[jj*4+3]);
      float cn = fv*c1[jj] + iv*gv;
      c1[jj] = cn;
      if (ub+jj<HH) HB[(nxt*ROWS+r)*SSTR + ub+jj] = ov*th(cn);
      else if (ub+jj<32) HB[(nxt*ROWS+r)*SSTR + ub+jj] = 0.f;
    }
    __syncthreads();
    cur = nxt;
  }
  #pragma unroll
  for (int jj=0;jj<2;++jj){
    const int j = ub+jj;
    if (j<HH){
      h0f[(size_t)b*HH+j] = HA[(cur*ROWS+r)*SSTR + j];
      h1f[(size_t)b*HH+j] = HB[(cur*ROWS+r)*SSTR + j];
      c0f[(size_t)b*HH+j] = c0[jj];
      c1f[(size_t)b*HH+j] = c1[jj];
    }
  }
}

// ---------------- conv path ----------------
__global__ __launch_bounds__(64) void k_conv(
    const float* __restrict__ x,
    const float* __restrict__ w1, const float* __restrict__ b1,
    const float* __restrict__ w2, const float* __restrict__ b2,
    const float* __restrict__ w3, const float* __restrict__ b3,
    const float* __restrict__ fw, const float* __restrict__ fb,
    float* __restrict__ xcg)
{
  __shared__ float xr[IND][TT];
  __shared__ float p1[32][23];
  __shared__ float p2[64][11];
  __shared__ float p3[512];
  __shared__ float red[64][21];
  const int b = blockIdx.x, tid = threadIdx.x;
  for (int i=tid;i<TT*IND;i+=64){
    float v = x[(size_t)b*(TT*IND) + i];
    xr[i % IND][i / IND] = v;
  }
  __syncthreads();
  if (tid < 23){
    float a0[32], a1[32];
    #pragma unroll
    for (int oc=0;oc<32;++oc){ float bb=b1[oc]; a0[oc]=bb; a1[oc]=bb; }
    for (int ic=0;ic<IND;++ic){
      float xw[6];
      #pragma unroll
      for (int q=0;q<6;++q) xw[q] = xr[ic][2*tid+q];
      #pragma unroll
      for (int kk=0;kk<5;++kk){
        float va = xw[kk], vb = xw[kk+1];
        #pragma unroll
        for (int oc=0;oc<32;++oc){
          float w = w1[(size_t)(oc*IND+ic)*5 + kk];
          a0[oc] += w*va; a1[oc] += w*vb;
        }
      }
    }
    #pragma unroll
    for (int oc=0;oc<32;++oc)
      p1[oc][tid] = fmaxf(fmaxf(a0[oc],0.f), fmaxf(a1[oc],0.f));
  }
  __syncthreads();
  {
    float acc[21];
    #pragma unroll
    for (int t=0;t<21;++t) acc[t] = b2[tid];
    for (int ic=0;ic<32;++ic){
      float xv[23];
      #pragma unroll
      for (int q=0;q<23;++q) xv[q] = p1[ic][q];
      #pragma unroll
      for (int kk=0;kk<3;++kk){
        float w = w2[(size_t)(tid*32+ic)*3 + kk];
        #pragma unroll
        for (int t=0;t<21;++t) acc[t] += w*xv[t+kk];
      }
    }
    #pragma unroll
    for (int p=0;p<10;++p)
      p2[tid][p] = fmaxf(fmaxf(acc[2*p],0.f), fmaxf(acc[2*p+1],0.f));
  }
  __syncthreads();
  {
    float a0[8], a1[8];
    #pragma unroll
    for (int t=0;t<8;++t){ a0[t]=b3[tid]; a1[t]=b3[tid+64]; }
    for (int ic=0;ic<64;++ic){
      float xv[10];
      #pragma unroll
      for (int q=0;q<10;++q) xv[q] = p2[ic][q];
      #pragma unroll
      for (int kk=0;kk<3;++kk){
        float wa = w3[(size_t)(tid*64+ic)*3 + kk];
        float wb = w3[(size_t)((tid+64)*64+ic)*3 + kk];
        #pragma unroll
        for (int t=0;t<8;++t){ a0[t]+=wa*xv[t+kk]; a1[t]+=wb*xv[t+kk]; }
      }
    }
    #pragma unroll
    for (int p=0;p<4;++p){
      p3[tid*4+p]      = fmaxf(fmaxf(a0[2*p],0.f), fmaxf(a0[2*p+1],0.f));
      p3[(tid+64)*4+p] = fmaxf(fmaxf(a1[2*p],0.f), fmaxf(a1[2*p+1],0.f));
    }
  }
  __syncthreads();
  {
    float xs[8];
    #pragma unroll
    for (int q=0;q<8;++q) xs[q] = p3[tid*8+q];
    float acc[20];
    #pragma unroll
    for (int j=0;j<20;++j){
      float a = 0.f;
      #pragma unroll
      for (int q=0;q<8;++q) a += xs[q] * fw[(size_t)j*512 + tid*8 + q];
      acc[j] = a;
    }
    #pragma unroll
    for (int j=0;j<20;++j) red[tid][j] = acc[j];
  }
  __syncthreads();
  if (tid < 20){
    float s = fb[tid];
    for (int l=0;l<64;++l) s += red[l][tid];
    xcg[(size_t)b*CVD + tid] = fmaxf(s, 0.f);
  }
}

// ---------------- BN1 stats ----------------
__global__ __launch_bounds__(128) void k_bn1s(const float* __restrict__ h0f, const float* __restrict__ h1f,
    const float* __restrict__ xcg, double* __restrict__ s1)
{
  int f = threadIdx.x;
  if (f >= CTXD) return;
  int r0 = blockIdx.x*128;
  double s=0.0, q=0.0;
  for (int i=0;i<128;++i){
    int r = r0+i;
    float v = (f<HH) ? h0f[(size_t)r*HH+f] : (f<2*HH) ? h1f[(size_t)r*HH + f-HH] : xcg[(size_t)r*CVD + f-2*HH];
    s += (double)v; q += (double)v*(double)v;
  }
  atomicAdd(&s1[f*2],   s);
  atomicAdd(&s1[f*2+1], q);
}

__global__ void k_fin1(const double* __restrict__ s1, float* __restrict__ st1){
  int f = threadIdx.x;
  if (f >= CTXD) return;
  double m = s1[f*2]/(double)NB;
  double var = s1[f*2+1]/(double)NB - m*m;
  if (var < 0.0) var = 0.0;
  st1[f*2]   = (float)m;
  st1[f*2+1] = (float)(1.0/sqrt(var + 1e-5));
}

__global__ __launch_bounds__(256) void k_context(const float* __restrict__ h0f, const float* __restrict__ h1f,
    const float* __restrict__ xcg, const float* __restrict__ st1,
    const float* __restrict__ g1, const float* __restrict__ bb1, float* __restrict__ ctx)
{
  int idx = blockIdx.x*256 + threadIdx.x;
  if (idx >= NB*CTXD) return;
  int rr = idx / CTXD, f = idx - rr*CTXD;
  float v = (f<HH) ? h0f[(size_t)rr*HH+f] : (f<2*HH) ? h1f[(size_t)rr*HH + f-HH] : xcg[(size_t)rr*CVD + f-2*HH];
  ctx[idx] = (v - st1[f*2]) * st1[f*2+1] * g1[f] + bb1[f];
}

// ---------------- decoder pass 1: LSTM chain + h1n store (NO stats) ----------------
template<typename ST>
__global__ __launch_bounds__(ROWS*GRP) void k_dec1(
    const float* __restrict__ x, const float* __restrict__ y,
    const float* __restrict__ ctx,
    const float* __restrict__ b2ih0, const float* __restrict__ b2hh0,
    const float* __restrict__ b2ih1, const float* __restrict__ b2hh1,
    const float* __restrict__ wt,
    const float* __restrict__ h0fi, const float* __restrict__ h1fi,
    const float* __restrict__ c0fi, const float* __restrict__ c1fi,
    ST* __restrict__ h1n)
{
  __shared__ float WL[DEC_WL];
  __shared__ float HA[2*ROWS*SSTR];
  __shared__ float HB[2*ROWS*SSTR];
  const int r = threadIdx.x;
  const int b = blockIdx.x*ROWS + r;
  const int tid = threadIdx.y*ROWS + r;
  for (int i = tid; i < DEC_WL; i += ROWS*GRP) WL[i] = wt[DTTY + i];
  const int wy = __builtin_amdgcn_readfirstlane((int)threadIdx.y);
  const int ub = 2*wy;
  const int j4 = 8*wy;
  const float* __restrict__ Wh0 = WL + LWH0 + j4;
  const float* __restrict__ Wx1 = WL + LWX1 + j4;
  const float* __restrict__ Wh1 = WL + LWH1 + j4;
  float c0[2], c1[2], bs1[8], pc[8], wtt[8], wty[8];
  #pragma unroll
  for (int jj=0;jj<2;++jj){
    const int jc = (ub+jj)<HH ? (ub+jj) : HH-1;
    c0[jj] = c0fi[(size_t)b*HH + jc];
    c1[jj] = c1fi[(size_t)b*HH + jc];
    #pragma unroll
    for (int g=0;g<4;++g){
      const int row = g*HH+jc;
      pc[jj*4+g]  = b2ih0[row] + b2hh0[row];
      bs1[jj*4+g] = b2ih1[row] + b2hh1[row];
    }
  }
  #pragma unroll
  for (int i=0;i<8;++i){ wtt[i] = wt[DTTY + j4 + i]; wty[i] = wt[DTTY + 128 + j4 + i]; }
  // fold step-invariant context contribution into pc (weights via scalar loads, one-time)
  for (int k0=0;k0<CTXD;k0+=4){
    float4 cv = *(const float4*)(ctx + (size_t)b*CTXD + k0);
    float cvv[4] = {cv.x, cv.y, cv.z, cv.w};
    #pragma unroll
    for (int kk=0;kk<4;++kk){
      const float v = cvv[kk];
      #pragma unroll
      for (int i=0;i<8;++i) pc[i] += v * wt[DTC + (k0+kk)*128 + j4 + i];
    }
  }
  #pragma unroll
  for (int jj=0;jj<2;++jj){
    const int j = ub+jj;
    float v0 = (j<HH) ? h0fi[(size_t)b*HH + j] : 0.f;
    float v1 = (j<HH) ? h1fi[(size_t)b*HH + j] : 0.f;
    if (j < 32){ HA[(0*ROWS+r)*SSTR + j] = v0; HB[(0*ROWS+r)*SSTR + j] = v1; }
  }
  float tcur = x[(size_t)b*(TT*IND) + (TT-1)*IND + 7];
  float yi   = x[(size_t)b*(TT*IND) + (TT-1)*IND + 0];
  __syncthreads();
  int cur = 0;
  for (int s=0; s<NOUT; ++s){
    const int nxt = cur^1;
    tcur = fmodf(tcur + 15.f, 1440.f);
    float hr0[32];
    {
      const float4* hp = (const float4*)&HA[(cur*ROWS+r)*SSTR];
      #pragma unroll
      for (int i=0;i<8;++i){ float4 v = hp[i]; hr0[4*i]=v.x; hr0[4*i+1]=v.y; hr0[4*i+2]=v.z; hr0[4*i+3]=v.w; }
    }
    float acc[8];
    #pragma unroll
    for (int i=0;i<8;++i) acc[i] = pc[i] + tcur*wtt[i] + yi*wty[i];
    #pragma unroll
    for (int k=0;k<HH;++k){
      const float v = hr0[k];
      float4 wa = *(const float4*)(Wh0 + k*128);
      float4 wb = *(const float4*)(Wh0 + k*128 + 4);
      acc[0]+=v*wa.x; acc[1]+=v*wa.y; acc[2]+=v*wa.z; acc[3]+=v*wa.w;
      acc[4]+=v*wb.x; acc[5]+=v*wb.y; acc[6]+=v*wb.z; acc[7]+=v*wb.w;
    }
    #pragma unroll
    for (int jj=0;jj<2;++jj){
      float iv=sg(acc[jj*4+0]), fv=sg(acc[jj*4+1]), gv=th(acc[jj*4+2]), ov=sg(acc[jj*4+3]);
      float cn = fv*c0[jj] + iv*gv;
      c0[jj] = cn;
      if (ub+jj<HH) HA[(nxt*ROWS+r)*SSTR + ub+jj] = ov*th(cn);
      else if (ub+jj<32) HA[(nxt*ROWS+r)*SSTR + ub+jj] = 0.f;
    }
    __syncthreads();
    float hr0n[32], hr1[32];
    {
      const float4* hp = (const float4*)&HA[(nxt*ROWS+r)*SSTR];
      const float4* hq = (const float4*)&HB[(cur*ROWS+r)*SSTR];
      #pragma unroll
      for (int i=0;i<8;++i){
        float4 v = hp[i]; hr0n[4*i]=v.x; hr0n[4*i+1]=v.y; hr0n[4*i+2]=v.z; hr0n[4*i+3]=v.w;
        float4 u = hq[i]; hr1[4*i]=u.x;  hr1[4*i+1]=u.y;  hr1[4*i+2]=u.z;  hr1[4*i+3]=u.w;
      }
    }
    #pragma unroll
    for (int i=0;i<8;++i) acc[i] = bs1[i];
    #pragma unroll
    for (int k=0;k<HH;++k){
      const float a = hr0n[k], bb = hr1[k];
      float4 wa = *(const float4*)(Wx1 + k*128);
      float4 wb = *(const float4*)(Wx1 + k*128 + 4);
      float4 ua = *(const float4*)(Wh1 + k*128);
      float4 ub4 = *(const float4*)(Wh1 + k*128 + 4);
      acc[0]+=a*wa.x+bb*ua.x; acc[1]+=a*wa.y+bb*ua.y; acc[2]+=a*wa.z+bb*ua.z; acc[3]+=a*wa.w+bb*ua.w;
      acc[4]+=a*wb.x+bb*ub4.x; acc[5]+=a*wb.y+bb*ub4.y; acc[6]+=a*wb.z+bb*ub4.z; acc[7]+=a*wb.w+bb*ub4.w;
    }
    float h1v[2];
    #pragma unroll
    for (int jj=0;jj<2;++jj){
      float iv=sg(acc[jj*4+0]), fv=sg(acc[jj*4+1]), gv=th(acc[jj*4+2]), ov=sg(acc[jj*4+3]);
      float cn = fv*c1[jj] + iv*gv;
      c1[jj] = cn;
      h1v[jj] = ov*th(cn);
      if (ub+jj<HH) HB[(nxt*ROWS+r)*SSTR + ub+jj] = h1v[jj];
      else if (ub+jj<32) HB[(nxt*ROWS+r)*SSTR + ub+jj] = 0.f;
    }
    __syncthreads();
    #pragma unroll
    for (int jj=0;jj<2;++jj){
      const int j = ub+jj;
      if (j<HH) stv(&h1n[((size_t)s*HH+j)*NB + b], h1v[jj]);
    }
    yi = y[(size_t)b*NOUT + s];
    cur = nxt;
  }
}

// ---------------- BN2 stats from h1n/xcg/x/y ----------------
template<typename ST>
__global__ __launch_bounds__(256) void k_bn2s(
    const ST* __restrict__ h1n, const float* __restrict__ xcg,
    const float* __restrict__ x, const float* __restrict__ y,
    float* __restrict__ m2, float* __restrict__ r2)
{
  __shared__ double sd[256];
  __shared__ double qd[256];
  const int s = blockIdx.x;
  const int f = blockIdx.y;
  double sv = 0.0, sq = 0.0;
  if (f < HH){
    const ST* p = h1n + ((size_t)s*HH + f)*NB;
    for (int i = threadIdx.x*8; i < NB; i += 256*8){
      #pragma unroll
      for (int u=0;u<8;++u){ float v = ldv(p + i + u); sv += v; sq += (double)v*(double)v; }
    }
  } else if (f < HH+CVD){
    const float* p = xcg + (f-HH);
    for (int i = threadIdx.x; i < NB; i += 256){
      float v = p[(size_t)i*CVD]; sv += v; sq += (double)v*(double)v;
    }
  } else if (f == HH+CVD){
    for (int i = threadIdx.x; i < NB; i += 256){
      float t = x[(size_t)i*(TT*IND) + (TT-1)*IND + 7];
      for (int k=0;k<=s;++k) t = fmodf(t + 15.f, 1440.f);
      sv += t; sq += (double)t*(double)t;
    }
  } else {
    for (int i = threadIdx.x; i < NB; i += 256){
      float v = (s==0) ? x[(size_t)i*(TT*IND) + (TT-1)*IND + 0] : y[(size_t)i*NOUT + (s-1)];
      sv += v; sq += (double)v*(double)v;
    }
  }
  sd[threadIdx.x] = sv; qd[threadIdx.x] = sq;
  __syncthreads();
  for (int st=128; st>0; st>>=1){
    if ((int)threadIdx.x < st){
      sd[threadIdx.x] += sd[threadIdx.x+st];
      qd[threadIdx.x] += qd[threadIdx.x+st];
    }
    __syncthreads();
  }
  if (threadIdx.x == 0){
    double m = sd[0]/(double)NB;
    double var = qd[0]/(double)NB - m*m;
    if (var < 0.0) var = 0.0;
    m2[s*F2+f] = (float)m;
    r2[s*F2+f] = (float)(1.0/sqrt(var + 1e-5));
  }
}

// ---------------- decoder pass 2: BN2 + dense readout ----------------
template<typename ST>
__global__ __launch_bounds__(256) void k_readout(
    const float* __restrict__ x, const float* __restrict__ y, const ST* __restrict__ h1n,
    const float* __restrict__ xcg, const float* __restrict__ m2, const float* __restrict__ r2,
    const float* __restrict__ g2, const float* __restrict__ b2,
    const float* __restrict__ Wd, const float* __restrict__ Bd,
    const float* __restrict__ Ud, const float* __restrict__ Cd, float* __restrict__ out)
{
  const int s  = blockIdx.y;
  const int rr = blockIdx.x*256 + threadIdx.x;
  float feat[F2];
  #pragma unroll
  for (int f=0; f<HH; ++f) feat[f] = ldv(&h1n[((size_t)s*HH+f)*NB + rr]);
  #pragma unroll
  for (int f=0; f<CVD; ++f) feat[HH+f] = xcg[(size_t)rr*CVD + f];
  float t0 = x[(size_t)rr*(TT*IND) + (TT-1)*IND + 7];
  for (int i=0;i<=s;++i) t0 = fmodf(t0 + 15.f, 1440.f);
  feat[HH+CVD] = t0;
  feat[HH+CVD+1] = (s==0) ? x[(size_t)rr*(TT*IND) + (TT-1)*IND + 0] : y[(size_t)rr*NOUT + (s-1)];
  #pragma unroll
  for (int f=0; f<F2; ++f)
    feat[f] = (feat[f] - m2[s*F2+f]) * r2[s*F2+f] * g2[f] + b2[f];
  float yv = Cd[s];
  #pragma unroll 1
  for (int jb=0; jb<HID; jb+=10){
    float a[10];
    #pragma unroll
    for (int jt=0;jt<10;++jt) a[jt] = Bd[(size_t)s*HID + jb + jt];
    #pragma unroll 4
    for (int k=0;k<F2;++k){
      const float v = feat[k];
      #pragma unroll
      for (int jt=0;jt<10;++jt)
        a[jt] += v * Wd[((size_t)s*F2 + k)*HID + jb + jt];
    }
    #pragma unroll
    for (int jt=0;jt<10;++jt)
      yv += fmaxf(a[jt], 0.f) * Ud[(size_t)s*HID + jb + jt];
  }
  out[(size_t)rr*NOUT + s] = yv;
}

// ---------------- host ----------------
extern "C" void kernel_launch(void* const* d_in, const int* in_sizes, int n_in,
                              void* d_out, int out_size, void* d_ws, size_t ws_size,
                              hipStream_t stream)
{
  const float* x    = (const float*)d_in[0];
  const float* y    = (const float*)d_in[1];
  const float* h0i  = (const float*)d_in[2];
  const float* c0i  = (const float*)d_in[3];
  const float* wih0 = (const float*)d_in[4];
  const float* whh0 = (const float*)d_in[5];
  const float* bih0 = (const float*)d_in[6];
  const float* bhh0 = (const float*)d_in[7];
  const float* wih1 = (const float*)d_in[8];
  const float* whh1 = (const float*)d_in[9];
  const float* bih1 = (const float*)d_in[10];
  const float* bhh1 = (const float*)d_in[11];
  const float* w2ih0= (const float*)d_in[12];
  const float* w2hh0= (const float*)d_in[13];
  const float* b2ih0= (const float*)d_in[14];
  const float* b2hh0= (const float*)d_in[15];
  const float* w2ih1= (const float*)d_in[16];
  const float* w2hh1= (const float*)d_in[17];
  const float* b2ih1= (const float*)d_in[18];
  const float* b2hh1= (const float*)d_in[19];
  const float* c1w  = (const float*)d_in[20];
  const float* c1b  = (const float*)d_in[21];
  const float* c2w  = (const float*)d_in[22];
  const float* c2b  = (const float*)d_in[23];
  const float* c3w  = (const float*)d_in[24];
  const float* c3b  = (const float*)d_in[25];
  const float* fcw  = (const float*)d_in[26];
  const float* fcb  = (const float*)d_in[27];
  const float* bn1g = (const float*)d_in[28];
  const float* bn1b = (const float*)d_in[29];
  const float* bn2g = (const float*)d_in[30];
  const float* bn2b = (const float*)d_in[31];
  const float* Wd   = (const float*)d_in[32];
  const float* Bd   = (const float*)d_in[33];
  const float* Ud   = (const float*)d_in[34];
  const float* Cd   = (const float*)d_in[35];
  float* out = (float*)d_out;

  char* base = (char*)d_ws;
  size_t off = 0;
  auto take = [&](size_t bytes)->char*{
    char* p = base + off;
    off = (off + bytes + 255) & ~(size_t)255;
    return p;
  };
  float*  h0f = (float*) take((size_t)NB*HH*sizeof(float));
  float*  h1f = (float*) take((size_t)NB*HH*sizeof(float));
  float*  c0f = (float*) take((size_t)NB*HH*sizeof(float));
  float*  c1f = (float*) take((size_t)NB*HH*sizeof(float));
  float*  xcg = (float*) take((size_t)NB*CVD*sizeof(float));
  float*  ctx = (float*) take((size_t)NB*CTXD*sizeof(float));
  double* s1  = (double*)take((size_t)CTXD*2*sizeof(double));
  float*  st1 = (float*) take((size_t)CTXD*2*sizeof(float));
  float*  m2  = (float*) take((size_t)NOUT*F2*sizeof(float));
  float*  r2  = (float*) take((size_t)NOUT*F2*sizeof(float));
  float*  wtb = (float*) take((size_t)WTTOT*sizeof(float));
  size_t fixed = off;
  size_t rem = (ws_size > fixed) ? (ws_size - fixed) : 0;
  bool f32st = rem >= (size_t)NOUT*HH*NB*sizeof(float);
  void* h1n = (void*)(base + off);

  k_tw<<<dim3((WTTOT+255)/256), dim3(256), 0, stream>>>(wih0, whh0, wih1, whh1,
      w2ih0, w2hh0, w2ih1, w2hh1, wtb);
  k_zero<<<dim3(1), dim3(256), 0, stream>>>(s1);
  k_encoder<<<dim3(NB/ROWS), dim3(ROWS,GRP), 0, stream>>>(x, h0i, c0i,
      bih0, bhh0, bih1, bhh1, wtb, h0f, h1f, c0f, c1f);
  k_conv<<<dim3(NB), dim3(64), 0, stream>>>(x, c1w, c1b, c2w, c2b, c3w, c3b, fcw, fcb, xcg);
  k_bn1s<<<dim3(NB/128), dim3(128), 0, stream>>>(h0f, h1f, xcg, s1);
  k_fin1<<<dim3(1), dim3(128), 0, stream>>>(s1, st1);
  k_context<<<dim3((NB*CTXD + 255)/256), dim3(256), 0, stream>>>(h0f, h1f, xcg, st1, bn1g, bn1b, ctx);
  if (f32st){
    k_dec1<float><<<dim3(NB/ROWS), dim3(ROWS,GRP), 0, stream>>>(x, y, ctx,
        b2ih0, b2hh0, b2ih1, b2hh1, wtb, h0f, h1f, c0f, c1f, (float*)h1n);
    k_bn2s<float><<<dim3(NOUT, F2), dim3(256), 0, stream>>>((const float*)h1n, xcg, x, y, m2, r2);
    k_readout<float><<<dim3(NB/256, NOUT), dim3(256), 0, stream>>>(x, y, (const float*)h1n,
        xcg, m2, r2, bn2g, bn2b, Wd, Bd, Ud, Cd, out);
  } else {
    k_dec1<__hip_bfloat16><<<dim3(NB/ROWS), dim3(ROWS,GRP), 0, stream>>>(x, y, ctx,
        b2ih0, b2hh0, b2ih1, b2hh1, wtb, h0f, h1f, c0f, c1f, (__hip_bfloat16*)h1n);
    k_bn2s<__hip_bfloat16><<<dim3(NOUT, F2), dim3(256), 0, stream>>>((const __hip_bfloat16*)h1n, xcg, x, y, m2, r2);
    k_readout<__hip_bfloat16><<<dim3(NB/256, NOUT), dim3(256), 0, stream>>>(x, y, (const __hip_bfloat16*)h1n,
        xcg, m2, r2, bn2g, bn2b, Wd, Bd, Ud, Cd, out);
  }
}

// Round 5
// 2095.008 us; speedup vs baseline: 11.7983x; 11.7983x over previous
//
#include <hip/hip_runtime.h>
#include <hip/hip_bf16.h>

#define NB   16384
#define TT   50
#define HH   30
#define IND  8
#define CTXD 80
#define IN2  82
#define F2   52
#define NOUT 50
#define HID  100
#define CVD  20
#define ROWS 64
#define GRP  16
#define HSTR 31   // LDS h row stride in words: coprime with 32 banks -> conflict-free scalar reads

// transposed weight table offsets (floats) in global ws
#define WTX0 0
#define WTH0 1024
#define WTX1 4864
#define WTH1 8704
#define DTC  12544
#define DTTY 22784
#define DTH0 23040
#define DTX1 26880
#define DTH1 30720
#define WTTOT 34560
// encoder LDS copy: wt[0 .. 12544)
#define ENC_WL 12544
// dec LDS copy: wt[22784 .. 34560) -> local offsets
#define DEC_WL   11776
#define LTT      0
#define LTY      128
#define LWH0     256
#define LWX1     4096
#define LWH1     7936

__device__ __forceinline__ float sg(float x){
  x = fminf(fmaxf(x, -30.f), 30.f);
  return 1.f/(1.f+__expf(-x));
}
__device__ __forceinline__ float th(float x){
  x = fminf(fmaxf(x, -15.f), 15.f);
  float e = __expf(2.f*x);
  return (e-1.f)/(e+1.f);
}
__device__ __forceinline__ float ldv(const float* p){ return *p; }
__device__ __forceinline__ float ldv(const __hip_bfloat16* p){ return __bfloat162float(*p); }
__device__ __forceinline__ void stv(float* p, float v){ *p = v; }
__device__ __forceinline__ void stv(__hip_bfloat16* p, float v){ *p = __float2bfloat16(v); }

// ---------------- weight transpose into ws: wt[sec][k][j*4+g] ----------------
__global__ void k_tw(const float* __restrict__ wih0, const float* __restrict__ whh0,
                     const float* __restrict__ wih1, const float* __restrict__ whh1,
                     const float* __restrict__ w2ih0, const float* __restrict__ w2hh0,
                     const float* __restrict__ w2ih1, const float* __restrict__ w2hh1,
                     float* __restrict__ wt)
{
  int idx = blockIdx.x*256 + threadIdx.x;
  if (idx >= WTTOT) return;
  int start, sel;
  if      (idx < WTH0){ start = WTX0; sel = 0; }
  else if (idx < WTX1){ start = WTH0; sel = 1; }
  else if (idx < WTH1){ start = WTX1; sel = 2; }
  else if (idx < DTC ){ start = WTH1; sel = 3; }
  else if (idx < DTTY){ start = DTC;  sel = 4; }
  else if (idx < DTH0){ start = DTTY; sel = 5; }
  else if (idx < DTX1){ start = DTH0; sel = 6; }
  else if (idx < DTH1){ start = DTX1; sel = 7; }
  else               { start = DTH1; sel = 8; }
  int local = idx - start;
  int k = local >> 7;          // /128
  int col = local & 127;
  int j = col >> 2, g = col & 3;
  int jc = j < HH ? j : HH-1;
  int row = g*HH + jc;
  float v;
  switch (sel){
    case 0: v = wih0[(size_t)row*IND + k]; break;
    case 1: v = whh0[(size_t)row*HH + k]; break;
    case 2: v = wih1[(size_t)row*HH + k]; break;
    case 3: v = whh1[(size_t)row*HH + k]; break;
    case 4: v = w2ih0[(size_t)row*IN2 + k]; break;
    case 5: v = w2ih0[(size_t)row*IN2 + 80 + k]; break;
    case 6: v = w2hh0[(size_t)row*HH + k]; break;
    case 7: v = w2ih1[(size_t)row*HH + k]; break;
    default: v = w2hh1[(size_t)row*HH + k]; break;
  }
  wt[idx] = v;
}

// ---------------- zero BN1 accumulators ----------------
__global__ void k_zero(double* a){
  int i = threadIdx.x;
  if (i < CTXD*2) a[i] = 0.0;
}

// ---------------- encoder LSTM ----------------
__global__ __launch_bounds__(ROWS*GRP, 4) void k_encoder(
    const float* __restrict__ x, const float* __restrict__ h0i, const float* __restrict__ c0i,
    const float* __restrict__ bih0, const float* __restrict__ bhh0,
    const float* __restrict__ bih1, const float* __restrict__ bhh1,
    const float* __restrict__ wt,
    float* __restrict__ h0f, float* __restrict__ h1f,
    float* __restrict__ c0f, float* __restrict__ c1f)
{
  __shared__ float WL[ENC_WL];
  __shared__ float HA[2*ROWS*HSTR];
  __shared__ float HB[2*ROWS*HSTR];
  const int r  = threadIdx.x;
  const int b  = blockIdx.x*ROWS + r;
  const int tid = threadIdx.y*ROWS + r;
  for (int i = tid; i < ENC_WL; i += ROWS*GRP) WL[i] = wt[i];
  const int wy = __builtin_amdgcn_readfirstlane((int)threadIdx.y);
  const int ub = 2*wy;
  const int j4 = 8*wy;
  const float* __restrict__ Wx0 = WL + WTX0 + j4;
  const float* __restrict__ Wh0 = WL + WTH0 + j4;
  const float* __restrict__ Wx1 = WL + WTX1 + j4;
  const float* __restrict__ Wh1 = WL + WTH1 + j4;
  float c0[2], c1[2], bs0[8], bs1[8];
  #pragma unroll
  for (int jj=0;jj<2;++jj){
    const int jc = (ub+jj)<HH ? (ub+jj) : HH-1;
    c0[jj] = c0i[jc]; c1[jj] = c0i[HH+jc];
    #pragma unroll
    for (int g=0;g<4;++g){
      bs0[jj*4+g] = bih0[g*HH+jc] + bhh0[g*HH+jc];
      bs1[jj*4+g] = bih1[g*HH+jc] + bhh1[g*HH+jc];
    }
  }
  #pragma unroll
  for (int jj=0;jj<2;++jj){
    const int j = ub+jj;
    if (j < HH){
      HA[(0*ROWS+r)*HSTR + j] = h0i[j];
      HB[(0*ROWS+r)*HSTR + j] = h0i[HH+j];
    }
  }
  __syncthreads();
  int cur = 0;
  for (int t=0;t<TT;++t){
    const int nxt = cur^1;
    const float4* xp = (const float4*)(x + ((size_t)b*TT + t)*IND);
    float4 xa = xp[0], xb = xp[1];
    float xv[8] = {xa.x,xa.y,xa.z,xa.w, xb.x,xb.y,xb.z,xb.w};
    const float* __restrict__ h0c = &HA[(cur*ROWS+r)*HSTR];
    float acc[8];
    #pragma unroll
    for (int i=0;i<8;++i) acc[i] = bs0[i];
    #pragma unroll
    for (int k=0;k<IND;++k){
      const float v = xv[k];
      float4 wa = *(const float4*)(Wx0 + k*128);
      float4 wb = *(const float4*)(Wx0 + k*128 + 4);
      acc[0]+=v*wa.x; acc[1]+=v*wa.y; acc[2]+=v*wa.z; acc[3]+=v*wa.w;
      acc[4]+=v*wb.x; acc[5]+=v*wb.y; acc[6]+=v*wb.z; acc[7]+=v*wb.w;
    }
    #pragma unroll 6
    for (int k=0;k<HH;++k){
      const float v = h0c[k];
      float4 wa = *(const float4*)(Wh0 + k*128);
      float4 wb = *(const float4*)(Wh0 + k*128 + 4);
      acc[0]+=v*wa.x; acc[1]+=v*wa.y; acc[2]+=v*wa.z; acc[3]+=v*wa.w;
      acc[4]+=v*wb.x; acc[5]+=v*wb.y; acc[6]+=v*wb.z; acc[7]+=v*wb.w;
    }
    #pragma unroll
    for (int jj=0;jj<2;++jj){
      float iv=sg(acc[jj*4+0]), fv=sg(acc[jj*4+1]), gv=th(acc[jj*4+2]), ov=sg(acc[jj*4+3]);
      float cn = fv*c0[jj] + iv*gv;
      c0[jj] = cn;
      if (ub+jj<HH) HA[(nxt*ROWS+r)*HSTR + ub+jj] = ov*th(cn);
    }
    __syncthreads();
    const float* __restrict__ h0n = &HA[(nxt*ROWS+r)*HSTR];
    const float* __restrict__ h1c = &HB[(cur*ROWS+r)*HSTR];
    #pragma unroll
    for (int i=0;i<8;++i) acc[i] = bs1[i];
    #pragma unroll 6
    for (int k=0;k<HH;++k){
      const float a = h0n[k], bb = h1c[k];
      float4 wa = *(const float4*)(Wx1 + k*128);
      float4 wb = *(const float4*)(Wx1 + k*128 + 4);
      float4 ua = *(const float4*)(Wh1 + k*128);
      float4 ub4 = *(const float4*)(Wh1 + k*128 + 4);
      acc[0]+=a*wa.x+bb*ua.x; acc[1]+=a*wa.y+bb*ua.y; acc[2]+=a*wa.z+bb*ua.z; acc[3]+=a*wa.w+bb*ua.w;
      acc[4]+=a*wb.x+bb*ub4.x; acc[5]+=a*wb.y+bb*ub4.y; acc[6]+=a*wb.z+bb*ub4.z; acc[7]+=a*wb.w+bb*ub4.w;
    }
    #pragma unroll
    for (int jj=0;jj<2;++jj){
      float iv=sg(acc[jj*4+0]), fv=sg(acc[jj*4+1]), gv=th(acc[jj*4+2]), ov=sg(acc[jj*4+3]);
      float cn = fv*c1[jj] + iv*gv;
      c1[jj] = cn;
      if (ub+jj<HH) HB[(nxt*ROWS+r)*HSTR + ub+jj] = ov*th(cn);
    }
    __syncthreads();
    cur = nxt;
  }
  #pragma unroll
  for (int jj=0;jj<2;++jj){
    const int j = ub+jj;
    if (j<HH){
      h0f[(size_t)b*HH+j] = HA[(cur*ROWS+r)*HSTR + j];
      h1f[(size_t)b*HH+j] = HB[(cur*ROWS+r)*HSTR + j];
      c0f[(size_t)b*HH+j] = c0[jj];
      c1f[(size_t)b*HH+j] = c1[jj];
    }
  }
}

// ---------------- conv path ----------------
__global__ __launch_bounds__(64) void k_conv(
    const float* __restrict__ x,
    const float* __restrict__ w1, const float* __restrict__ b1,
    const float* __restrict__ w2, const float* __restrict__ b2,
    const float* __restrict__ w3, const float* __restrict__ b3,
    const float* __restrict__ fw, const float* __restrict__ fb,
    float* __restrict__ xcg)
{
  __shared__ float xr[IND][TT];
  __shared__ float p1[32][23];
  __shared__ float p2[64][11];
  __shared__ float p3[512];
  __shared__ float red[64][21];
  const int b = blockIdx.x, tid = threadIdx.x;
  for (int i=tid;i<TT*IND;i+=64){
    float v = x[(size_t)b*(TT*IND) + i];
    xr[i % IND][i / IND] = v;
  }
  __syncthreads();
  if (tid < 23){
    float a0[32], a1[32];
    #pragma unroll
    for (int oc=0;oc<32;++oc){ float bb=b1[oc]; a0[oc]=bb; a1[oc]=bb; }
    for (int ic=0;ic<IND;++ic){
      float xw[6];
      #pragma unroll
      for (int q=0;q<6;++q) xw[q] = xr[ic][2*tid+q];
      #pragma unroll
      for (int kk=0;kk<5;++kk){
        float va = xw[kk], vb = xw[kk+1];
        #pragma unroll
        for (int oc=0;oc<32;++oc){
          float w = w1[(size_t)(oc*IND+ic)*5 + kk];
          a0[oc] += w*va; a1[oc] += w*vb;
        }
      }
    }
    #pragma unroll
    for (int oc=0;oc<32;++oc)
      p1[oc][tid] = fmaxf(fmaxf(a0[oc],0.f), fmaxf(a1[oc],0.f));
  }
  __syncthreads();
  {
    float acc[21];
    #pragma unroll
    for (int t=0;t<21;++t) acc[t] = b2[tid];
    for (int ic=0;ic<32;++ic){
      float xv[23];
      #pragma unroll
      for (int q=0;q<23;++q) xv[q] = p1[ic][q];
      #pragma unroll
      for (int kk=0;kk<3;++kk){
        float w = w2[(size_t)(tid*32+ic)*3 + kk];
        #pragma unroll
        for (int t=0;t<21;++t) acc[t] += w*xv[t+kk];
      }
    }
    #pragma unroll
    for (int p=0;p<10;++p)
      p2[tid][p] = fmaxf(fmaxf(acc[2*p],0.f), fmaxf(acc[2*p+1],0.f));
  }
  __syncthreads();
  {
    float a0[8], a1[8];
    #pragma unroll
    for (int t=0;t<8;++t){ a0[t]=b3[tid]; a1[t]=b3[tid+64]; }
    for (int ic=0;ic<64;++ic){
      float xv[10];
      #pragma unroll
      for (int q=0;q<10;++q) xv[q] = p2[ic][q];
      #pragma unroll
      for (int kk=0;kk<3;++kk){
        float wa = w3[(size_t)(tid*64+ic)*3 + kk];
        float wb = w3[(size_t)((tid+64)*64+ic)*3 + kk];
        #pragma unroll
        for (int t=0;t<8;++t){ a0[t]+=wa*xv[t+kk]; a1[t]+=wb*xv[t+kk]; }
      }
    }
    #pragma unroll
    for (int p=0;p<4;++p){
      p3[tid*4+p]      = fmaxf(fmaxf(a0[2*p],0.f), fmaxf(a0[2*p+1],0.f));
      p3[(tid+64)*4+p] = fmaxf(fmaxf(a1[2*p],0.f), fmaxf(a1[2*p+1],0.f));
    }
  }
  __syncthreads();
  {
    float xs[8];
    #pragma unroll
    for (int q=0;q<8;++q) xs[q] = p3[tid*8+q];
    float acc[20];
    #pragma unroll
    for (int j=0;j<20;++j){
      float a = 0.f;
      #pragma unroll
      for (int q=0;q<8;++q) a += xs[q] * fw[(size_t)j*512 + tid*8 + q];
      acc[j] = a;
    }
    #pragma unroll
    for (int j=0;j<20;++j) red[tid][j] = acc[j];
  }
  __syncthreads();
  if (tid < 20){
    float s = fb[tid];
    for (int l=0;l<64;++l) s += red[l][tid];
    xcg[(size_t)b*CVD + tid] = fmaxf(s, 0.f);
  }
}

// ---------------- BN1 stats ----------------
__global__ __launch_bounds__(128) void k_bn1s(const float* __restrict__ h0f, const float* __restrict__ h1f,
    const float* __restrict__ xcg, double* __restrict__ s1)
{
  int f = threadIdx.x;
  if (f >= CTXD) return;
  int r0 = blockIdx.x*128;
  double s=0.0, q=0.0;
  for (int i=0;i<128;++i){
    int r = r0+i;
    float v = (f<HH) ? h0f[(size_t)r*HH+f] : (f<2*HH) ? h1f[(size_t)r*HH + f-HH] : xcg[(size_t)r*CVD + f-2*HH];
    s += (double)v; q += (double)v*(double)v;
  }
  atomicAdd(&s1[f*2],   s);
  atomicAdd(&s1[f*2+1], q);
}

__global__ void k_fin1(const double* __restrict__ s1, float* __restrict__ st1){
  int f = threadIdx.x;
  if (f >= CTXD) return;
  double m = s1[f*2]/(double)NB;
  double var = s1[f*2+1]/(double)NB - m*m;
  if (var < 0.0) var = 0.0;
  st1[f*2]   = (float)m;
  st1[f*2+1] = (float)(1.0/sqrt(var + 1e-5));
}

__global__ __launch_bounds__(256) void k_context(const float* __restrict__ h0f, const float* __restrict__ h1f,
    const float* __restrict__ xcg, const float* __restrict__ st1,
    const float* __restrict__ g1, const float* __restrict__ bb1, float* __restrict__ ctx)
{
  int idx = blockIdx.x*256 + threadIdx.x;
  if (idx >= NB*CTXD) return;
  int rr = idx / CTXD, f = idx - rr*CTXD;
  float v = (f<HH) ? h0f[(size_t)rr*HH+f] : (f<2*HH) ? h1f[(size_t)rr*HH + f-HH] : xcg[(size_t)rr*CVD + f-2*HH];
  ctx[idx] = (v - st1[f*2]) * st1[f*2+1] * g1[f] + bb1[f];
}

// ---------------- decoder pass 1: LSTM chain + h1n store ----------------
template<typename ST>
__global__ __launch_bounds__(ROWS*GRP, 4) void k_dec1(
    const float* __restrict__ x, const float* __restrict__ y,
    const float* __restrict__ ctx,
    const float* __restrict__ b2ih0, const float* __restrict__ b2hh0,
    const float* __restrict__ b2ih1, const float* __restrict__ b2hh1,
    const float* __restrict__ wt,
    const float* __restrict__ h0fi, const float* __restrict__ h1fi,
    const float* __restrict__ c0fi, const float* __restrict__ c1fi,
    ST* __restrict__ h1n)
{
  __shared__ float WL[DEC_WL];
  __shared__ float HA[2*ROWS*HSTR];
  __shared__ float HB[2*ROWS*HSTR];
  const int r = threadIdx.x;
  const int b = blockIdx.x*ROWS + r;
  const int tid = threadIdx.y*ROWS + r;
  for (int i = tid; i < DEC_WL; i += ROWS*GRP) WL[i] = wt[DTTY + i];
  const int wy = __builtin_amdgcn_readfirstlane((int)threadIdx.y);
  const int ub = 2*wy;
  const int j4 = 8*wy;
  const float* __restrict__ Wh0 = WL + LWH0 + j4;
  const float* __restrict__ Wx1 = WL + LWX1 + j4;
  const float* __restrict__ Wh1 = WL + LWH1 + j4;
  float c0[2], c1[2], bs1[8], pc[8], wtt[8], wty[8];
  #pragma unroll
  for (int jj=0;jj<2;++jj){
    const int jc = (ub+jj)<HH ? (ub+jj) : HH-1;
    c0[jj] = c0fi[(size_t)b*HH + jc];
    c1[jj] = c1fi[(size_t)b*HH + jc];
    #pragma unroll
    for (int g=0;g<4;++g){
      const int row = g*HH+jc;
      pc[jj*4+g]  = b2ih0[row] + b2hh0[row];
      bs1[jj*4+g] = b2ih1[row] + b2hh1[row];
    }
  }
  #pragma unroll
  for (int i=0;i<8;++i){ wtt[i] = wt[DTTY + j4 + i]; wty[i] = wt[DTTY + 128 + j4 + i]; }
  // fold step-invariant context contribution into pc (one-time, wave-uniform s_loads)
  for (int k0=0;k0<CTXD;k0+=4){
    float4 cv = *(const float4*)(ctx + (size_t)b*CTXD + k0);
    float cvv[4] = {cv.x, cv.y, cv.z, cv.w};
    #pragma unroll
    for (int kk=0;kk<4;++kk){
      const float v = cvv[kk];
      #pragma unroll
      for (int i=0;i<8;++i) pc[i] += v * wt[DTC + (k0+kk)*128 + j4 + i];
    }
  }
  #pragma unroll
  for (int jj=0;jj<2;++jj){
    const int j = ub+jj;
    if (j<HH){
      HA[(0*ROWS+r)*HSTR + j] = h0fi[(size_t)b*HH + j];
      HB[(0*ROWS+r)*HSTR + j] = h1fi[(size_t)b*HH + j];
    }
  }
  float tcur = x[(size_t)b*(TT*IND) + (TT-1)*IND + 7];
  float yi   = x[(size_t)b*(TT*IND) + (TT-1)*IND + 0];
  __syncthreads();
  int cur = 0;
  for (int s=0; s<NOUT; ++s){
    const int nxt = cur^1;
    tcur = fmodf(tcur + 15.f, 1440.f);
    const float* __restrict__ h0c = &HA[(cur*ROWS+r)*HSTR];
    float acc[8];
    #pragma unroll
    for (int i=0;i<8;++i) acc[i] = pc[i] + tcur*wtt[i] + yi*wty[i];
    #pragma unroll 6
    for (int k=0;k<HH;++k){
      const float v = h0c[k];
      float4 wa = *(const float4*)(Wh0 + k*128);
      float4 wb = *(const float4*)(Wh0 + k*128 + 4);
      acc[0]+=v*wa.x; acc[1]+=v*wa.y; acc[2]+=v*wa.z; acc[3]+=v*wa.w;
      acc[4]+=v*wb.x; acc[5]+=v*wb.y; acc[6]+=v*wb.z; acc[7]+=v*wb.w;
    }
    #pragma unroll
    for (int jj=0;jj<2;++jj){
      float iv=sg(acc[jj*4+0]), fv=sg(acc[jj*4+1]), gv=th(acc[jj*4+2]), ov=sg(acc[jj*4+3]);
      float cn = fv*c0[jj] + iv*gv;
      c0[jj] = cn;
      if (ub+jj<HH) HA[(nxt*ROWS+r)*HSTR + ub+jj] = ov*th(cn);
    }
    __syncthreads();
    const float* __restrict__ h0n = &HA[(nxt*ROWS+r)*HSTR];
    const float* __restrict__ h1c = &HB[(cur*ROWS+r)*HSTR];
    #pragma unroll
    for (int i=0;i<8;++i) acc[i] = bs1[i];
    #pragma unroll 6
    for (int k=0;k<HH;++k){
      const float a = h0n[k], bb = h1c[k];
      float4 wa = *(const float4*)(Wx1 + k*128);
      float4 wb = *(const float4*)(Wx1 + k*128 + 4);
      float4 ua = *(const float4*)(Wh1 + k*128);
      float4 ub4 = *(const float4*)(Wh1 + k*128 + 4);
      acc[0]+=a*wa.x+bb*ua.x; acc[1]+=a*wa.y+bb*ua.y; acc[2]+=a*wa.z+bb*ua.z; acc[3]+=a*wa.w+bb*ua.w;
      acc[4]+=a*wb.x+bb*ub4.x; acc[5]+=a*wb.y+bb*ub4.y; acc[6]+=a*wb.z+bb*ub4.z; acc[7]+=a*wb.w+bb*ub4.w;
    }
    float h1v[2];
    #pragma unroll
    for (int jj=0;jj<2;++jj){
      float iv=sg(acc[jj*4+0]), fv=sg(acc[jj*4+1]), gv=th(acc[jj*4+2]), ov=sg(acc[jj*4+3]);
      float cn = fv*c1[jj] + iv*gv;
      c1[jj] = cn;
      h1v[jj] = ov*th(cn);
      if (ub+jj<HH) HB[(nxt*ROWS+r)*HSTR + ub+jj] = h1v[jj];
    }
    __syncthreads();
    #pragma unroll
    for (int jj=0;jj<2;++jj){
      const int j = ub+jj;
      if (j<HH) stv(&h1n[((size_t)s*HH+j)*NB + b], h1v[jj]);
    }
    yi = y[(size_t)b*NOUT + s];
    cur = nxt;
  }
}

// ---------------- BN2 stats from h1n/xcg/x/y ----------------
template<typename ST>
__global__ __launch_bounds__(256) void k_bn2s(
    const ST* __restrict__ h1n, const float* __restrict__ xcg,
    const float* __restrict__ x, const float* __restrict__ y,
    float* __restrict__ m2, float* __restrict__ r2)
{
  __shared__ double sd[256];
  __shared__ double qd[256];
  const int s = blockIdx.x;
  const int f = blockIdx.y;
  double sv = 0.0, sq = 0.0;
  if (f < HH){
    const ST* p = h1n + ((size_t)s*HH + f)*NB;
    for (int i = threadIdx.x*8; i < NB; i += 256*8){
      #pragma unroll
      for (int u=0;u<8;++u){ float v = ldv(p + i + u); sv += v; sq += (double)v*(double)v; }
    }
  } else if (f < HH+CVD){
    const float* p = xcg + (f-HH);
    for (int i = threadIdx.x; i < NB; i += 256){
      float v = p[(size_t)i*CVD]; sv += v; sq += (double)v*(double)v;
    }
  } else if (f == HH+CVD){
    for (int i = threadIdx.x; i < NB; i += 256){
      float t = x[(size_t)i*(TT*IND) + (TT-1)*IND + 7];
      for (int k=0;k<=s;++k) t = fmodf(t + 15.f, 1440.f);
      sv += t; sq += (double)t*(double)t;
    }
  } else {
    for (int i = threadIdx.x; i < NB; i += 256){
      float v = (s==0) ? x[(size_t)i*(TT*IND) + (TT-1)*IND + 0] : y[(size_t)i*NOUT + (s-1)];
      sv += v; sq += (double)v*(double)v;
    }
  }
  sd[threadIdx.x] = sv; qd[threadIdx.x] = sq;
  __syncthreads();
  for (int st=128; st>0; st>>=1){
    if ((int)threadIdx.x < st){
      sd[threadIdx.x] += sd[threadIdx.x+st];
      qd[threadIdx.x] += qd[threadIdx.x+st];
    }
    __syncthreads();
  }
  if (threadIdx.x == 0){
    double m = sd[0]/(double)NB;
    double var = qd[0]/(double)NB - m*m;
    if (var < 0.0) var = 0.0;
    m2[s*F2+f] = (float)m;
    r2[s*F2+f] = (float)(1.0/sqrt(var + 1e-5));
  }
}

// ---------------- decoder pass 2: BN2 + dense readout ----------------
template<typename ST>
__global__ __launch_bounds__(256) void k_readout(
    const float* __restrict__ x, const float* __restrict__ y, const ST* __restrict__ h1n,
    const float* __restrict__ xcg, const float* __restrict__ m2, const float* __restrict__ r2,
    const float* __restrict__ g2, const float* __restrict__ b2,
    const float* __restrict__ Wd, const float* __restrict__ Bd,
    const float* __restrict__ Ud, const float* __restrict__ Cd, float* __restrict__ out)
{
  const int s  = blockIdx.y;
  const int rr = blockIdx.x*256 + threadIdx.x;
  float feat[F2];
  #pragma unroll
  for (int f=0; f<HH; ++f) feat[f] = ldv(&h1n[((size_t)s*HH+f)*NB + rr]);
  #pragma unroll
  for (int f=0; f<CVD; ++f) feat[HH+f] = xcg[(size_t)rr*CVD + f];
  float t0 = x[(size_t)rr*(TT*IND) + (TT-1)*IND + 7];
  for (int i=0;i<=s;++i) t0 = fmodf(t0 + 15.f, 1440.f);
  feat[HH+CVD] = t0;
  feat[HH+CVD+1] = (s==0) ? x[(size_t)rr*(TT*IND) + (TT-1)*IND + 0] : y[(size_t)rr*NOUT + (s-1)];
  #pragma unroll
  for (int f=0; f<F2; ++f)
    feat[f] = (feat[f] - m2[s*F2+f]) * r2[s*F2+f] * g2[f] + b2[f];
  float yv = Cd[s];
  #pragma unroll 1
  for (int jb=0; jb<HID; jb+=10){
    float a[10];
    #pragma unroll
    for (int jt=0;jt<10;++jt) a[jt] = Bd[(size_t)s*HID + jb + jt];
    #pragma unroll 4
    for (int k=0;k<F2;++k){
      const float v = feat[k];
      #pragma unroll
      for (int jt=0;jt<10;++jt)
        a[jt] += v * Wd[((size_t)s*F2 + k)*HID + jb + jt];
    }
    #pragma unroll
    for (int jt=0;jt<10;++jt)
      yv += fmaxf(a[jt], 0.f) * Ud[(size_t)s*HID + jb + jt];
  }
  out[(size_t)rr*NOUT + s] = yv;
}

// ---------------- host ----------------
extern "C" void kernel_launch(void* const* d_in, const int* in_sizes, int n_in,
                              void* d_out, int out_size, void* d_ws, size_t ws_size,
                              hipStream_t stream)
{
  const float* x    = (const float*)d_in[0];
  const float* y    = (const float*)d_in[1];
  const float* h0i  = (const float*)d_in[2];
  const float* c0i  = (const float*)d_in[3];
  const float* wih0 = (const float*)d_in[4];
  const float* whh0 = (const float*)d_in[5];
  const float* bih0 = (const float*)d_in[6];
  const float* bhh0 = (const float*)d_in[7];
  const float* wih1 = (const float*)d_in[8];
  const float* whh1 = (const float*)d_in[9];
  const float* bih1 = (const float*)d_in[10];
  const float* bhh1 = (const float*)d_in[11];
  const float* w2ih0= (const float*)d_in[12];
  const float* w2hh0= (const float*)d_in[13];
  const float* b2ih0= (const float*)d_in[14];
  const float* b2hh0= (const float*)d_in[15];
  const float* w2ih1= (const float*)d_in[16];
  const float* w2hh1= (const float*)d_in[17];
  const float* b2ih1= (const float*)d_in[18];
  const float* b2hh1= (const float*)d_in[19];
  const float* c1w  = (const float*)d_in[20];
  const float* c1b  = (const float*)d_in[21];
  const float* c2w  = (const float*)d_in[22];
  const float* c2b  = (const float*)d_in[23];
  const float* c3w  = (const float*)d_in[24];
  const float* c3b  = (const float*)d_in[25];
  const float* fcw  = (const float*)d_in[26];
  const float* fcb  = (const float*)d_in[27];
  const float* bn1g = (const float*)d_in[28];
  const float* bn1b = (const float*)d_in[29];
  const float* bn2g = (const float*)d_in[30];
  const float* bn2b = (const float*)d_in[31];
  const float* Wd   = (const float*)d_in[32];
  const float* Bd   = (const float*)d_in[33];
  const float* Ud   = (const float*)d_in[34];
  const float* Cd   = (const float*)d_in[35];
  float* out = (float*)d_out;

  char* base = (char*)d_ws;
  size_t off = 0;
  auto take = [&](size_t bytes)->char*{
    char* p = base + off;
    off = (off + bytes + 255) & ~(size_t)255;
    return p;
  };
  float*  h0f = (float*) take((size_t)NB*HH*sizeof(float));
  float*  h1f = (float*) take((size_t)NB*HH*sizeof(float));
  float*  c0f = (float*) take((size_t)NB*HH*sizeof(float));
  float*  c1f = (float*) take((size_t)NB*HH*sizeof(float));
  float*  xcg = (float*) take((size_t)NB*CVD*sizeof(float));
  float*  ctx = (float*) take((size_t)NB*CTXD*sizeof(float));
  double* s1  = (double*)take((size_t)CTXD*2*sizeof(double));
  float*  st1 = (float*) take((size_t)CTXD*2*sizeof(float));
  float*  m2  = (float*) take((size_t)NOUT*F2*sizeof(float));
  float*  r2  = (float*) take((size_t)NOUT*F2*sizeof(float));
  float*  wtb = (float*) take((size_t)WTTOT*sizeof(float));
  size_t fixed = off;
  size_t rem = (ws_size > fixed) ? (ws_size - fixed) : 0;
  bool f32st = rem >= (size_t)NOUT*HH*NB*sizeof(float);
  void* h1n = (void*)(base + off);

  k_tw<<<dim3((WTTOT+255)/256), dim3(256), 0, stream>>>(wih0, whh0, wih1, whh1,
      w2ih0, w2hh0, w2ih1, w2hh1, wtb);
  k_zero<<<dim3(1), dim3(256), 0, stream>>>(s1);
  k_encoder<<<dim3(NB/ROWS), dim3(ROWS,GRP), 0, stream>>>(x, h0i, c0i,
      bih0, bhh0, bih1, bhh1, wtb, h0f, h1f, c0f, c1f);
  k_conv<<<dim3(NB), dim3(64), 0, stream>>>(x, c1w, c1b, c2w, c2b, c3w, c3b, fcw, fcb, xcg);
  k_bn1s<<<dim3(NB/128), dim3(128), 0, stream>>>(h0f, h1f, xcg, s1);
  k_fin1<<<dim3(1), dim3(128), 0, stream>>>(s1, st1);
  k_context<<<dim3((NB*CTXD + 255)/256), dim3(256), 0, stream>>>(h0f, h1f, xcg, st1, bn1g, bn1b, ctx);
  if (f32st){
    k_dec1<float><<<dim3(NB/ROWS), dim3(ROWS,GRP), 0, stream>>>(x, y, ctx,
        b2ih0, b2hh0, b2ih1, b2hh1, wtb, h0f, h1f, c0f, c1f, (float*)h1n);
    k_bn2s<float><<<dim3(NOUT, F2), dim3(256), 0, stream>>>((const float*)h1n, xcg, x, y, m2, r2);
    k_readout<float><<<dim3(NB/256, NOUT), dim3(256), 0, stream>>>(x, y, (const float*)h1n,
        xcg, m2, r2, bn2g, bn2b, Wd, Bd, Ud, Cd, out);
  } else {
    k_dec1<__hip_bfloat16><<<dim3(NB/ROWS), dim3(ROWS,GRP), 0, stream>>>(x, y, ctx,
        b2ih0, b2hh0, b2ih1, b2hh1, wtb, h0f, h1f, c0f, c1f, (__hip_bfloat16*)h1n);
    k_bn2s<__hip_bfloat16><<<dim3(NOUT, F2), dim3(256), 0, stream>>>((const __hip_bfloat16*)h1n, xcg, x, y, m2, r2);
    k_readout<__hip_bfloat16><<<dim3(NB/256, NOUT), dim3(256), 0, stream>>>(x, y, (const __hip_bfloat16*)h1n,
        xcg, m2, r2, bn2g, bn2b, Wd, Bd, Ud, Cd, out);
  }
}

// Round 6
// 1724.414 us; speedup vs baseline: 14.3338x; 1.2149x over previous
//
#include <hip/hip_runtime.h>
#include <hip/hip_bf16.h>

#define NB   16384
#define TT   50
#define HH   30
#define IND  8
#define CTXD 80
#define IN2  82
#define F2   52
#define NOUT 50
#define HID  100
#define CVD  20
#define ROWS 64
#define GRP  16
#define HSTR 31

// transposed weight table offsets (floats) in global ws (encoder still uses [0,12544))
#define WTX0 0
#define WTH0 1024
#define WTX1 4864
#define WTH1 8704
#define DTC  12544
#define DTTY 22784
#define DTH0 23040
#define DTX1 26880
#define DTH1 30720
#define WTTOT 34560
#define ENC_WL 12544

typedef __attribute__((ext_vector_type(8))) short s8v;
typedef __attribute__((ext_vector_type(4))) float f4v;

__device__ __forceinline__ float sg(float x){
  x = fminf(fmaxf(x, -30.f), 30.f);
  return 1.f/(1.f+__expf(-x));
}
__device__ __forceinline__ float th(float x){
  x = fminf(fmaxf(x, -15.f), 15.f);
  float e = __expf(2.f*x);
  return (e-1.f)/(e+1.f);
}
__device__ __forceinline__ float ldv(const float* p){ return *p; }
__device__ __forceinline__ float ldv(const __hip_bfloat16* p){ return __bfloat162float(*p); }
__device__ __forceinline__ void stv(float* p, float v){ *p = v; }
__device__ __forceinline__ void stv(__hip_bfloat16* p, float v){ *p = __float2bfloat16(v); }
__device__ __forceinline__ unsigned short f2b(float f){
  __hip_bfloat16 h = __float2bfloat16(f);
  return *reinterpret_cast<unsigned short*>(&h);
}
__device__ __forceinline__ float b2f(unsigned short u){
  __hip_bfloat16 h;
  *reinterpret_cast<unsigned short*>(&h) = u;
  return __bfloat162float(h);
}

// ---------------- weight transpose (encoder table) ----------------
__global__ void k_tw(const float* __restrict__ wih0, const float* __restrict__ whh0,
                     const float* __restrict__ wih1, const float* __restrict__ whh1,
                     const float* __restrict__ w2ih0, const float* __restrict__ w2hh0,
                     const float* __restrict__ w2ih1, const float* __restrict__ w2hh1,
                     float* __restrict__ wt)
{
  int idx = blockIdx.x*256 + threadIdx.x;
  if (idx >= WTTOT) return;
  int start, sel;
  if      (idx < WTH0){ start = WTX0; sel = 0; }
  else if (idx < WTX1){ start = WTH0; sel = 1; }
  else if (idx < WTH1){ start = WTX1; sel = 2; }
  else if (idx < DTC ){ start = WTH1; sel = 3; }
  else if (idx < DTTY){ start = DTC;  sel = 4; }
  else if (idx < DTH0){ start = DTTY; sel = 5; }
  else if (idx < DTX1){ start = DTH0; sel = 6; }
  else if (idx < DTH1){ start = DTX1; sel = 7; }
  else               { start = DTH1; sel = 8; }
  int local = idx - start;
  int k = local >> 7;
  int col = local & 127;
  int j = col >> 2, g = col & 3;
  int jc = j < HH ? j : HH-1;
  int row = g*HH + jc;
  float v;
  switch (sel){
    case 0: v = wih0[(size_t)row*IND + k]; break;
    case 1: v = whh0[(size_t)row*HH + k]; break;
    case 2: v = wih1[(size_t)row*HH + k]; break;
    case 3: v = whh1[(size_t)row*HH + k]; break;
    case 4: v = w2ih0[(size_t)row*IN2 + k]; break;
    case 5: v = w2ih0[(size_t)row*IN2 + 80 + k]; break;
    case 6: v = w2hh0[(size_t)row*HH + k]; break;
    case 7: v = w2ih1[(size_t)row*HH + k]; break;
    default: v = w2hh1[(size_t)row*HH + k]; break;
  }
  wt[idx] = v;
}

// ---------------- MFMA fragment tables for decoder ----------------
// frags: f=0..7 layer0 (Wh0, K=32), f=8..23 layer1 (ks0=Wx1,ks1=Wh1), f=24..47 ctx (3 ksteps)
// layout: wb2[(f*64 + lane)*8 + j]; B[k][col]: k = ks*32 + 8*(lane>>4)+j, col = ct*16 + (lane&15)
// gate-major columns: col = g*32 + u
__global__ void k_tw2(const float* __restrict__ w2ih0, const float* __restrict__ w2hh0,
                      const float* __restrict__ w2ih1, const float* __restrict__ w2hh1,
                      const float* __restrict__ b2ih0, const float* __restrict__ b2hh0,
                      const float* __restrict__ b2ih1, const float* __restrict__ b2hh1,
                      unsigned short* __restrict__ wb2, float* __restrict__ tb)
{
  int idx = blockIdx.x*256 + threadIdx.x;
  if (idx < 48*512){
    int f = idx >> 9, rem = idx & 511;
    int l = rem >> 3, j = rem & 7;
    int lr = l & 15, lq = l >> 4;
    float v = 0.f;
    if (f < 8){
      int ct = f, k = 8*lq + j, col = ct*16 + lr;
      int g = col>>5, u = col&31;
      if (k < HH && u < HH) v = w2hh0[(size_t)(g*HH+u)*HH + k];
    } else if (f < 24){
      int ct = (f-8)>>1, ks = (f-8)&1, k = 8*lq + j, col = ct*16 + lr;
      int g = col>>5, u = col&31;
      if (k < HH && u < HH) v = ks ? w2hh1[(size_t)(g*HH+u)*HH + k] : w2ih1[(size_t)(g*HH+u)*HH + k];
    } else {
      int ct = (f-24)/3, ks = (f-24)%3, k = ks*32 + 8*lq + j, col = ct*16 + lr;
      int g = col>>5, u = col&31;
      if (k < CTXD && u < HH) v = w2ih0[(size_t)(g*HH+u)*IN2 + k];
    }
    wb2[idx] = f2b(v);
  } else if (idx < 48*512 + 512){
    int t = idx - 48*512;
    int col = t & 127, sel = t >> 7;
    int g = col>>5, u = col&31;
    float v = 0.f;
    if (u < HH){
      int r = g*HH + u;
      if (sel == 0) v = b2ih0[r] + b2hh0[r];
      else if (sel == 1) v = b2ih1[r] + b2hh1[r];
      else if (sel == 2) v = w2ih0[(size_t)r*IN2 + 80];
      else v = w2ih0[(size_t)r*IN2 + 81];
    }
    tb[sel*128 + col] = v;
  }
}

// ---------------- zero BN1 accumulators ----------------
__global__ void k_zero(double* a){
  int i = threadIdx.x;
  if (i < CTXD*2) a[i] = 0.0;
}

// ---------------- encoder LSTM (unchanged from R5) ----------------
__global__ __launch_bounds__(ROWS*GRP, 4) void k_encoder(
    const float* __restrict__ x, const float* __restrict__ h0i, const float* __restrict__ c0i,
    const float* __restrict__ bih0, const float* __restrict__ bhh0,
    const float* __restrict__ bih1, const float* __restrict__ bhh1,
    const float* __restrict__ wt,
    float* __restrict__ h0f, float* __restrict__ h1f,
    float* __restrict__ c0f, float* __restrict__ c1f)
{
  __shared__ float WL[ENC_WL];
  __shared__ float HA[2*ROWS*HSTR];
  __shared__ float HB[2*ROWS*HSTR];
  const int r  = threadIdx.x;
  const int b  = blockIdx.x*ROWS + r;
  const int tid = threadIdx.y*ROWS + r;
  for (int i = tid; i < ENC_WL; i += ROWS*GRP) WL[i] = wt[i];
  const int wy = __builtin_amdgcn_readfirstlane((int)threadIdx.y);
  const int ub = 2*wy;
  const int j4 = 8*wy;
  const float* __restrict__ Wx0 = WL + WTX0 + j4;
  const float* __restrict__ Wh0 = WL + WTH0 + j4;
  const float* __restrict__ Wx1 = WL + WTX1 + j4;
  const float* __restrict__ Wh1 = WL + WTH1 + j4;
  float c0[2], c1[2], bs0[8], bs1[8];
  #pragma unroll
  for (int jj=0;jj<2;++jj){
    const int jc = (ub+jj)<HH ? (ub+jj) : HH-1;
    c0[jj] = c0i[jc]; c1[jj] = c0i[HH+jc];
    #pragma unroll
    for (int g=0;g<4;++g){
      bs0[jj*4+g] = bih0[g*HH+jc] + bhh0[g*HH+jc];
      bs1[jj*4+g] = bih1[g*HH+jc] + bhh1[g*HH+jc];
    }
  }
  #pragma unroll
  for (int jj=0;jj<2;++jj){
    const int j = ub+jj;
    if (j < HH){
      HA[(0*ROWS+r)*HSTR + j] = h0i[j];
      HB[(0*ROWS+r)*HSTR + j] = h0i[HH+j];
    }
  }
  __syncthreads();
  int cur = 0;
  for (int t=0;t<TT;++t){
    const int nxt = cur^1;
    const float4* xp = (const float4*)(x + ((size_t)b*TT + t)*IND);
    float4 xa = xp[0], xb = xp[1];
    float xv[8] = {xa.x,xa.y,xa.z,xa.w, xb.x,xb.y,xb.z,xb.w};
    const float* __restrict__ h0c = &HA[(cur*ROWS+r)*HSTR];
    float acc[8];
    #pragma unroll
    for (int i=0;i<8;++i) acc[i] = bs0[i];
    #pragma unroll
    for (int k=0;k<IND;++k){
      const float v = xv[k];
      float4 wa = *(const float4*)(Wx0 + k*128);
      float4 wb = *(const float4*)(Wx0 + k*128 + 4);
      acc[0]+=v*wa.x; acc[1]+=v*wa.y; acc[2]+=v*wa.z; acc[3]+=v*wa.w;
      acc[4]+=v*wb.x; acc[5]+=v*wb.y; acc[6]+=v*wb.z; acc[7]+=v*wb.w;
    }
    #pragma unroll 6
    for (int k=0;k<HH;++k){
      const float v = h0c[k];
      float4 wa = *(const float4*)(Wh0 + k*128);
      float4 wb = *(const float4*)(Wh0 + k*128 + 4);
      acc[0]+=v*wa.x; acc[1]+=v*wa.y; acc[2]+=v*wa.z; acc[3]+=v*wa.w;
      acc[4]+=v*wb.x; acc[5]+=v*wb.y; acc[6]+=v*wb.z; acc[7]+=v*wb.w;
    }
    #pragma unroll
    for (int jj=0;jj<2;++jj){
      float iv=sg(acc[jj*4+0]), fv=sg(acc[jj*4+1]), gv=th(acc[jj*4+2]), ov=sg(acc[jj*4+3]);
      float cn = fv*c0[jj] + iv*gv;
      c0[jj] = cn;
      if (ub+jj<HH) HA[(nxt*ROWS+r)*HSTR + ub+jj] = ov*th(cn);
    }
    __syncthreads();
    const float* __restrict__ h0n = &HA[(nxt*ROWS+r)*HSTR];
    const float* __restrict__ h1c = &HB[(cur*ROWS+r)*HSTR];
    #pragma unroll
    for (int i=0;i<8;++i) acc[i] = bs1[i];
    #pragma unroll 6
    for (int k=0;k<HH;++k){
      const float a = h0n[k], bb = h1c[k];
      float4 wa = *(const float4*)(Wx1 + k*128);
      float4 wb = *(const float4*)(Wx1 + k*128 + 4);
      float4 ua = *(const float4*)(Wh1 + k*128);
      float4 ub4 = *(const float4*)(Wh1 + k*128 + 4);
      acc[0]+=a*wa.x+bb*ua.x; acc[1]+=a*wa.y+bb*ua.y; acc[2]+=a*wa.z+bb*ua.z; acc[3]+=a*wa.w+bb*ua.w;
      acc[4]+=a*wb.x+bb*ub4.x; acc[5]+=a*wb.y+bb*ub4.y; acc[6]+=a*wb.z+bb*ub4.z; acc[7]+=a*wb.w+bb*ub4.w;
    }
    #pragma unroll
    for (int jj=0;jj<2;++jj){
      float iv=sg(acc[jj*4+0]), fv=sg(acc[jj*4+1]), gv=th(acc[jj*4+2]), ov=sg(acc[jj*4+3]);
      float cn = fv*c1[jj] + iv*gv;
      c1[jj] = cn;
      if (ub+jj<HH) HB[(nxt*ROWS+r)*HSTR + ub+jj] = ov*th(cn);
    }
    __syncthreads();
    cur = nxt;
  }
  #pragma unroll
  for (int jj=0;jj<2;++jj){
    const int j = ub+jj;
    if (j<HH){
      h0f[(size_t)b*HH+j] = HA[(cur*ROWS+r)*HSTR + j];
      h1f[(size_t)b*HH+j] = HB[(cur*ROWS+r)*HSTR + j];
      c0f[(size_t)b*HH+j] = c0[jj];
      c1f[(size_t)b*HH+j] = c1[jj];
    }
  }
}

// ---------------- conv path (unchanged) ----------------
__global__ __launch_bounds__(64) void k_conv(
    const float* __restrict__ x,
    const float* __restrict__ w1, const float* __restrict__ b1,
    const float* __restrict__ w2, const float* __restrict__ b2,
    const float* __restrict__ w3, const float* __restrict__ b3,
    const float* __restrict__ fw, const float* __restrict__ fb,
    float* __restrict__ xcg)
{
  __shared__ float xr[IND][TT];
  __shared__ float p1[32][23];
  __shared__ float p2[64][11];
  __shared__ float p3[512];
  __shared__ float red[64][21];
  const int b = blockIdx.x, tid = threadIdx.x;
  for (int i=tid;i<TT*IND;i+=64){
    float v = x[(size_t)b*(TT*IND) + i];
    xr[i % IND][i / IND] = v;
  }
  __syncthreads();
  if (tid < 23){
    float a0[32], a1[32];
    #pragma unroll
    for (int oc=0;oc<32;++oc){ float bb=b1[oc]; a0[oc]=bb; a1[oc]=bb; }
    for (int ic=0;ic<IND;++ic){
      float xw[6];
      #pragma unroll
      for (int q=0;q<6;++q) xw[q] = xr[ic][2*tid+q];
      #pragma unroll
      for (int kk=0;kk<5;++kk){
        float va = xw[kk], vb = xw[kk+1];
        #pragma unroll
        for (int oc=0;oc<32;++oc){
          float w = w1[(size_t)(oc*IND+ic)*5 + kk];
          a0[oc] += w*va; a1[oc] += w*vb;
        }
      }
    }
    #pragma unroll
    for (int oc=0;oc<32;++oc)
      p1[oc][tid] = fmaxf(fmaxf(a0[oc],0.f), fmaxf(a1[oc],0.f));
  }
  __syncthreads();
  {
    float acc[21];
    #pragma unroll
    for (int t=0;t<21;++t) acc[t] = b2[tid];
    for (int ic=0;ic<32;++ic){
      float xv[23];
      #pragma unroll
      for (int q=0;q<23;++q) xv[q] = p1[ic][q];
      #pragma unroll
      for (int kk=0;kk<3;++kk){
        float w = w2[(size_t)(tid*32+ic)*3 + kk];
        #pragma unroll
        for (int t=0;t<21;++t) acc[t] += w*xv[t+kk];
      }
    }
    #pragma unroll
    for (int p=0;p<10;++p)
      p2[tid][p] = fmaxf(fmaxf(acc[2*p],0.f), fmaxf(acc[2*p+1],0.f));
  }
  __syncthreads();
  {
    float a0[8], a1[8];
    #pragma unroll
    for (int t=0;t<8;++t){ a0[t]=b3[tid]; a1[t]=b3[tid+64]; }
    for (int ic=0;ic<64;++ic){
      float xv[10];
      #pragma unroll
      for (int q=0;q<10;++q) xv[q] = p2[ic][q];
      #pragma unroll
      for (int kk=0;kk<3;++kk){
        float wa = w3[(size_t)(tid*64+ic)*3 + kk];
        float wb = w3[(size_t)((tid+64)*64+ic)*3 + kk];
        #pragma unroll
        for (int t=0;t<8;++t){ a0[t]+=wa*xv[t+kk]; a1[t]+=wb*xv[t+kk]; }
      }
    }
    #pragma unroll
    for (int p=0;p<4;++p){
      p3[tid*4+p]      = fmaxf(fmaxf(a0[2*p],0.f), fmaxf(a0[2*p+1],0.f));
      p3[(tid+64)*4+p] = fmaxf(fmaxf(a1[2*p],0.f), fmaxf(a1[2*p+1],0.f));
    }
  }
  __syncthreads();
  {
    float xs[8];
    #pragma unroll
    for (int q=0;q<8;++q) xs[q] = p3[tid*8+q];
    float acc[20];
    #pragma unroll
    for (int j=0;j<20;++j){
      float a = 0.f;
      #pragma unroll
      for (int q=0;q<8;++q) a += xs[q] * fw[(size_t)j*512 + tid*8 + q];
      acc[j] = a;
    }
    #pragma unroll
    for (int j=0;j<20;++j) red[tid][j] = acc[j];
  }
  __syncthreads();
  if (tid < 20){
    float s = fb[tid];
    for (int l=0;l<64;++l) s += red[l][tid];
    xcg[(size_t)b*CVD + tid] = fmaxf(s, 0.f);
  }
}

// ---------------- BN1 stats ----------------
__global__ __launch_bounds__(128) void k_bn1s(const float* __restrict__ h0f, const float* __restrict__ h1f,
    const float* __restrict__ xcg, double* __restrict__ s1)
{
  int f = threadIdx.x;
  if (f >= CTXD) return;
  int r0 = blockIdx.x*128;
  double s=0.0, q=0.0;
  for (int i=0;i<128;++i){
    int r = r0+i;
    float v = (f<HH) ? h0f[(size_t)r*HH+f] : (f<2*HH) ? h1f[(size_t)r*HH + f-HH] : xcg[(size_t)r*CVD + f-2*HH];
    s += (double)v; q += (double)v*(double)v;
  }
  atomicAdd(&s1[f*2],   s);
  atomicAdd(&s1[f*2+1], q);
}

__global__ void k_fin1(const double* __restrict__ s1, float* __restrict__ st1){
  int f = threadIdx.x;
  if (f >= CTXD) return;
  double m = s1[f*2]/(double)NB;
  double var = s1[f*2+1]/(double)NB - m*m;
  if (var < 0.0) var = 0.0;
  st1[f*2]   = (float)m;
  st1[f*2+1] = (float)(1.0/sqrt(var + 1e-5));
}

__global__ __launch_bounds__(256) void k_context(const float* __restrict__ h0f, const float* __restrict__ h1f,
    const float* __restrict__ xcg, const float* __restrict__ st1,
    const float* __restrict__ g1, const float* __restrict__ bb1, float* __restrict__ ctx)
{
  int idx = blockIdx.x*256 + threadIdx.x;
  if (idx >= NB*CTXD) return;
  int rr = idx / CTXD, f = idx - rr*CTXD;
  float v = (f<HH) ? h0f[(size_t)rr*HH+f] : (f<2*HH) ? h1f[(size_t)rr*HH + f-HH] : xcg[(size_t)rr*CVD + f-2*HH];
  ctx[idx] = (v - st1[f*2]) * st1[f*2+1] * g1[f] + bb1[f];
}

// ---------------- decoder pass 1: MFMA LSTM ----------------
// block = 512 thr = 8 waves; wave w: sample-tile st=w&3 (16 samples), unit-group ug=w>>2.
// lane owns unit u=ug*16+(l&15), 4 samples st*16+4*(l>>4)+i; accs = {i,f,g,o} gates (gate-major cols).
template<typename ST>
__global__ __launch_bounds__(512, 2) void k_dec1m(
    const float* __restrict__ x, const float* __restrict__ y,
    const float* __restrict__ ctx,
    const unsigned short* __restrict__ wb2, const float* __restrict__ tb,
    const float* __restrict__ h0fi, const float* __restrict__ h1fi,
    const float* __restrict__ c0fi, const float* __restrict__ c1fi,
    ST* __restrict__ h1n)
{
  __shared__ __align__(16) unsigned short CT[64*96];     // ctx bf16, rows=samples, K=96 (80 data), 16B-chunk XOR swizzle
  __shared__ __align__(16) unsigned short Hh0[2][64*32]; // h0 bf16 (30 data + 2 zero pad)
  __shared__ __align__(16) unsigned short Hh1[2][64*32];
  const int tid = threadIdx.x;
  const int l  = tid & 63, w = tid >> 6;
  const int st = w & 3, ug = w >> 2;
  const int lr = l & 15, lq = l >> 4, l3 = l & 3;
  const int blk = blockIdx.x;

  for (int i = tid; i < 64*32; i += 512){
    Hh0[0][i] = 0; Hh0[1][i] = 0; Hh1[0][i] = 0; Hh1[1][i] = 0;
  }
  for (int i = tid; i < 64*96; i += 512) CT[i] = 0;
  __syncthreads();
  for (int i = tid; i < 64*CTXD; i += 512){
    int r = i / CTXD, kk = i - r*CTXD;
    float v = ctx[((size_t)blk*64 + r)*CTXD + kk];
    CT[r*96 + (((kk>>3) ^ (r&3))<<3) + (kk&7)] = f2b(v);
  }
  for (int i = tid; i < 64*HH; i += 512){
    int r = i / HH, u2 = i - r*HH;
    int off = r*32 + (((u2>>3) ^ (r&3))<<3) + (u2&7);
    Hh0[0][off] = f2b(h0fi[((size_t)blk*64 + r)*HH + u2]);
    Hh1[0][off] = f2b(h1fi[((size_t)blk*64 + r)*HH + u2]);
  }

  const int u  = ug*16 + lr;
  const int uc = u < HH ? u : HH-1;
  const int arow = st*16 + lr;
  const int aoff = arow*32 + ((lq ^ l3)<<3);   // arow&3 == l3

  int wr[4]; int gS[4];
  float c0[4], c1[4], tt[4], yv[4];
  #pragma unroll
  for (int i=0;i<4;++i){
    int smp = st*16 + 4*lq + i;
    gS[i] = blk*64 + smp;
    wr[i] = smp*32 + (((u>>3) ^ i)<<3) + (u&7);   // smp&3 == i
    c0[i] = c0fi[(size_t)gS[i]*HH + uc];
    c1[i] = c1fi[(size_t)gS[i]*HH + uc];
    tt[i] = x[(size_t)gS[i]*(TT*IND) + (TT-1)*IND + 7];
    yv[i] = x[(size_t)gS[i]*(TT*IND) + (TT-1)*IND + 0];
  }

  s8v B0[4], B10[4], B11[4], BC0[4], BC1[4], BC2[4];
  float bias0[4], bias1[4], wtt[4], wty[4];
  #pragma unroll
  for (int g=0; g<4; ++g){
    const int ct = g*2 + ug;
    const int col = ct*16 + lr;
    B0[g]  = *(const s8v*)(wb2 + ((size_t)(ct)*64 + l)*8);
    B10[g] = *(const s8v*)(wb2 + ((size_t)(8 + ct*2 + 0)*64 + l)*8);
    B11[g] = *(const s8v*)(wb2 + ((size_t)(8 + ct*2 + 1)*64 + l)*8);
    BC0[g] = *(const s8v*)(wb2 + ((size_t)(24 + ct*3 + 0)*64 + l)*8);
    BC1[g] = *(const s8v*)(wb2 + ((size_t)(24 + ct*3 + 1)*64 + l)*8);
    BC2[g] = *(const s8v*)(wb2 + ((size_t)(24 + ct*3 + 2)*64 + l)*8);
    bias0[g] = tb[col]; bias1[g] = tb[128+col];
    wtt[g] = tb[256+col]; wty[g] = tb[384+col];
  }
  __syncthreads();

  // pc = bias0 + ctx·Wc (3 K-steps of MFMA)
  f4v pc[4];
  #pragma unroll
  for (int g=0; g<4; ++g){
    f4v a = {bias0[g], bias0[g], bias0[g], bias0[g]};
    {
      const s8v av = *(const s8v*)&CT[arow*96 + (((0*4+lq) ^ l3)<<3)];
      a = __builtin_amdgcn_mfma_f32_16x16x32_bf16(av, BC0[g], a, 0, 0, 0);
    }
    {
      const s8v av = *(const s8v*)&CT[arow*96 + (((1*4+lq) ^ l3)<<3)];
      a = __builtin_amdgcn_mfma_f32_16x16x32_bf16(av, BC1[g], a, 0, 0, 0);
    }
    {
      const s8v av = *(const s8v*)&CT[arow*96 + (((2*4+lq) ^ l3)<<3)];
      a = __builtin_amdgcn_mfma_f32_16x16x32_bf16(av, BC2[g], a, 0, 0, 0);
    }
    pc[g] = a;
  }

  int cur = 0;
  for (int s = 0; s < NOUT; ++s){
    const int nxt = cur ^ 1;
    #pragma unroll
    for (int i=0;i<4;++i) tt[i] = fmodf(tt[i] + 15.f, 1440.f);
    // ---- layer 0 ----
    const s8v a0 = *(const s8v*)&Hh0[cur][aoff];
    f4v ac[4];
    #pragma unroll
    for (int g=0; g<4; ++g){
      f4v a = pc[g];
      #pragma unroll
      for (int i=0;i<4;++i) a[i] += tt[i]*wtt[g] + yv[i]*wty[g];
      ac[g] = __builtin_amdgcn_mfma_f32_16x16x32_bf16(a0, B0[g], a, 0, 0, 0);
    }
    unsigned short hw[4];
    #pragma unroll
    for (int i=0;i<4;++i){
      float iv = sg(ac[0][i]), fv = sg(ac[1][i]), gv = th(ac[2][i]), ov = sg(ac[3][i]);
      c0[i] = fv*c0[i] + iv*gv;
      hw[i] = f2b(ov*th(c0[i]));
    }
    if (u < HH){
      #pragma unroll
      for (int i=0;i<4;++i) Hh0[nxt][wr[i]] = hw[i];
    }
    __syncthreads();
    // ---- layer 1: K = [h0_new(32) ; h1_prev(32)] ----
    const s8v a1 = *(const s8v*)&Hh0[nxt][aoff];
    const s8v a2 = *(const s8v*)&Hh1[cur][aoff];
    #pragma unroll
    for (int g=0; g<4; ++g){
      f4v a = {bias1[g], bias1[g], bias1[g], bias1[g]};
      a = __builtin_amdgcn_mfma_f32_16x16x32_bf16(a1, B10[g], a, 0, 0, 0);
      ac[g] = __builtin_amdgcn_mfma_f32_16x16x32_bf16(a2, B11[g], a, 0, 0, 0);
    }
    #pragma unroll
    for (int i=0;i<4;++i){
      float iv = sg(ac[0][i]), fv = sg(ac[1][i]), gv = th(ac[2][i]), ov = sg(ac[3][i]);
      c1[i] = fv*c1[i] + iv*gv;
      hw[i] = f2b(ov*th(c1[i]));
    }
    if (u < HH){
      #pragma unroll
      for (int i=0;i<4;++i) Hh1[nxt][wr[i]] = hw[i];
    }
    __syncthreads();
    // ---- coalesced h1n writeback + teacher y for next step ----
    for (int i2 = tid; i2 < 64*HH; i2 += 512){
      int uu = i2 >> 6, sl = i2 & 63;
      unsigned short hv = Hh1[nxt][sl*32 + (((uu>>3) ^ (sl&3))<<3) + (uu&7)];
      stv(&h1n[((size_t)s*HH + uu)*NB + (size_t)blk*64 + sl], b2f(hv));
    }
    #pragma unroll
    for (int i=0;i<4;++i) yv[i] = y[(size_t)gS[i]*NOUT + s];
    cur = nxt;
  }
}

// ---------------- BN2 stats ----------------
template<typename ST>
__global__ __launch_bounds__(256) void k_bn2s(
    const ST* __restrict__ h1n, const float* __restrict__ xcg,
    const float* __restrict__ x, const float* __restrict__ y,
    float* __restrict__ m2, float* __restrict__ r2)
{
  __shared__ double sd[256];
  __shared__ double qd[256];
  const int s = blockIdx.x;
  const int f = blockIdx.y;
  double sv = 0.0, sq = 0.0;
  if (f < HH){
    const ST* p = h1n + ((size_t)s*HH + f)*NB;
    for (int i = threadIdx.x*8; i < NB; i += 256*8){
      #pragma unroll
      for (int u=0;u<8;++u){ float v = ldv(p + i + u); sv += v; sq += (double)v*(double)v; }
    }
  } else if (f < HH+CVD){
    const float* p = xcg + (f-HH);
    for (int i = threadIdx.x; i < NB; i += 256){
      float v = p[(size_t)i*CVD]; sv += v; sq += (double)v*(double)v;
    }
  } else if (f == HH+CVD){
    for (int i = threadIdx.x; i < NB; i += 256){
      float t = x[(size_t)i*(TT*IND) + (TT-1)*IND + 7];
      for (int k=0;k<=s;++k) t = fmodf(t + 15.f, 1440.f);
      sv += t; sq += (double)t*(double)t;
    }
  } else {
    for (int i = threadIdx.x; i < NB; i += 256){
      float v = (s==0) ? x[(size_t)i*(TT*IND) + (TT-1)*IND + 0] : y[(size_t)i*NOUT + (s-1)];
      sv += v; sq += (double)v*(double)v;
    }
  }
  sd[threadIdx.x] = sv; qd[threadIdx.x] = sq;
  __syncthreads();
  for (int st2=128; st2>0; st2>>=1){
    if ((int)threadIdx.x < st2){
      sd[threadIdx.x] += sd[threadIdx.x+st2];
      qd[threadIdx.x] += qd[threadIdx.x+st2];
    }
    __syncthreads();
  }
  if (threadIdx.x == 0){
    double m = sd[0]/(double)NB;
    double var = qd[0]/(double)NB - m*m;
    if (var < 0.0) var = 0.0;
    m2[s*F2+f] = (float)m;
    r2[s*F2+f] = (float)(1.0/sqrt(var + 1e-5));
  }
}

// ---------------- decoder pass 2: BN2 + dense readout ----------------
template<typename ST>
__global__ __launch_bounds__(256) void k_readout(
    const float* __restrict__ x, const float* __restrict__ y, const ST* __restrict__ h1n,
    const float* __restrict__ xcg, const float* __restrict__ m2, const float* __restrict__ r2,
    const float* __restrict__ g2, const float* __restrict__ b2,
    const float* __restrict__ Wd, const float* __restrict__ Bd,
    const float* __restrict__ Ud, const float* __restrict__ Cd, float* __restrict__ out)
{
  const int s  = blockIdx.y;
  const int rr = blockIdx.x*256 + threadIdx.x;
  float feat[F2];
  #pragma unroll
  for (int f=0; f<HH; ++f) feat[f] = ldv(&h1n[((size_t)s*HH+f)*NB + rr]);
  #pragma unroll
  for (int f=0; f<CVD; ++f) feat[HH+f] = xcg[(size_t)rr*CVD + f];
  float t0 = x[(size_t)rr*(TT*IND) + (TT-1)*IND + 7];
  for (int i=0;i<=s;++i) t0 = fmodf(t0 + 15.f, 1440.f);
  feat[HH+CVD] = t0;
  feat[HH+CVD+1] = (s==0) ? x[(size_t)rr*(TT*IND) + (TT-1)*IND + 0] : y[(size_t)rr*NOUT + (s-1)];
  #pragma unroll
  for (int f=0; f<F2; ++f)
    feat[f] = (feat[f] - m2[s*F2+f]) * r2[s*F2+f] * g2[f] + b2[f];
  float yvv = Cd[s];
  #pragma unroll 1
  for (int jb=0; jb<HID; jb+=10){
    float a[10];
    #pragma unroll
    for (int jt=0;jt<10;++jt) a[jt] = Bd[(size_t)s*HID + jb + jt];
    #pragma unroll 4
    for (int k=0;k<F2;++k){
      const float v = feat[k];
      #pragma unroll
      for (int jt=0;jt<10;++jt)
        a[jt] += v * Wd[((size_t)s*F2 + k)*HID + jb + jt];
    }
    #pragma unroll
    for (int jt=0;jt<10;++jt)
      yvv += fmaxf(a[jt], 0.f) * Ud[(size_t)s*HID + jb + jt];
  }
  out[(size_t)rr*NOUT + s] = yvv;
}

// ---------------- host ----------------
extern "C" void kernel_launch(void* const* d_in, const int* in_sizes, int n_in,
                              void* d_out, int out_size, void* d_ws, size_t ws_size,
                              hipStream_t stream)
{
  const float* x    = (const float*)d_in[0];
  const float* y    = (const float*)d_in[1];
  const float* h0i  = (const float*)d_in[2];
  const float* c0i  = (const float*)d_in[3];
  const float* wih0 = (const float*)d_in[4];
  const float* whh0 = (const float*)d_in[5];
  const float* bih0 = (const float*)d_in[6];
  const float* bhh0 = (const float*)d_in[7];
  const float* wih1 = (const float*)d_in[8];
  const float* whh1 = (const float*)d_in[9];
  const float* bih1 = (const float*)d_in[10];
  const float* bhh1 = (const float*)d_in[11];
  const float* w2ih0= (const float*)d_in[12];
  const float* w2hh0= (const float*)d_in[13];
  const float* b2ih0= (const float*)d_in[14];
  const float* b2hh0= (const float*)d_in[15];
  const float* w2ih1= (const float*)d_in[16];
  const float* w2hh1= (const float*)d_in[17];
  const float* b2ih1= (const float*)d_in[18];
  const float* b2hh1= (const float*)d_in[19];
  const float* c1w  = (const float*)d_in[20];
  const float* c1b  = (const float*)d_in[21];
  const float* c2w  = (const float*)d_in[22];
  const float* c2b  = (const float*)d_in[23];
  const float* c3w  = (const float*)d_in[24];
  const float* c3b  = (const float*)d_in[25];
  const float* fcw  = (const float*)d_in[26];
  const float* fcb  = (const float*)d_in[27];
  const float* bn1g = (const float*)d_in[28];
  const float* bn1b = (const float*)d_in[29];
  const float* bn2g = (const float*)d_in[30];
  const float* bn2b = (const float*)d_in[31];
  const float* Wd   = (const float*)d_in[32];
  const float* Bd   = (const float*)d_in[33];
  const float* Ud   = (const float*)d_in[34];
  const float* Cd   = (const float*)d_in[35];
  float* out = (float*)d_out;

  char* base = (char*)d_ws;
  size_t off = 0;
  auto take = [&](size_t bytes)->char*{
    char* p = base + off;
    off = (off + bytes + 255) & ~(size_t)255;
    return p;
  };
  float*  h0f = (float*) take((size_t)NB*HH*sizeof(float));
  float*  h1f = (float*) take((size_t)NB*HH*sizeof(float));
  float*  c0f = (float*) take((size_t)NB*HH*sizeof(float));
  float*  c1f = (float*) take((size_t)NB*HH*sizeof(float));
  float*  xcg = (float*) take((size_t)NB*CVD*sizeof(float));
  float*  ctx = (float*) take((size_t)NB*CTXD*sizeof(float));
  double* s1  = (double*)take((size_t)CTXD*2*sizeof(double));
  float*  st1 = (float*) take((size_t)CTXD*2*sizeof(float));
  float*  m2  = (float*) take((size_t)NOUT*F2*sizeof(float));
  float*  r2  = (float*) take((size_t)NOUT*F2*sizeof(float));
  float*  wtb = (float*) take((size_t)WTTOT*sizeof(float));
  unsigned short* wb2 = (unsigned short*) take((size_t)48*512*sizeof(unsigned short));
  float*  tb  = (float*) take((size_t)4*128*sizeof(float));
  size_t fixed = off;
  size_t rem = (ws_size > fixed) ? (ws_size - fixed) : 0;
  bool f32st = rem >= (size_t)NOUT*HH*NB*sizeof(float);
  void* h1n = (void*)(base + off);

  k_tw<<<dim3((WTTOT+255)/256), dim3(256), 0, stream>>>(wih0, whh0, wih1, whh1,
      w2ih0, w2hh0, w2ih1, w2hh1, wtb);
  k_tw2<<<dim3((48*512+512+255)/256), dim3(256), 0, stream>>>(w2ih0, w2hh0, w2ih1, w2hh1,
      b2ih0, b2hh0, b2ih1, b2hh1, wb2, tb);
  k_zero<<<dim3(1), dim3(256), 0, stream>>>(s1);
  k_encoder<<<dim3(NB/ROWS), dim3(ROWS,GRP), 0, stream>>>(x, h0i, c0i,
      bih0, bhh0, bih1, bhh1, wtb, h0f, h1f, c0f, c1f);
  k_conv<<<dim3(NB), dim3(64), 0, stream>>>(x, c1w, c1b, c2w, c2b, c3w, c3b, fcw, fcb, xcg);
  k_bn1s<<<dim3(NB/128), dim3(128), 0, stream>>>(h0f, h1f, xcg, s1);
  k_fin1<<<dim3(1), dim3(128), 0, stream>>>(s1, st1);
  k_context<<<dim3((NB*CTXD + 255)/256), dim3(256), 0, stream>>>(h0f, h1f, xcg, st1, bn1g, bn1b, ctx);
  if (f32st){
    k_dec1m<float><<<dim3(NB/64), dim3(512), 0, stream>>>(x, y, ctx, wb2, tb,
        h0f, h1f, c0f, c1f, (float*)h1n);
    k_bn2s<float><<<dim3(NOUT, F2), dim3(256), 0, stream>>>((const float*)h1n, xcg, x, y, m2, r2);
    k_readout<float><<<dim3(NB/256, NOUT), dim3(256), 0, stream>>>(x, y, (const float*)h1n,
        xcg, m2, r2, bn2g, bn2b, Wd, Bd, Ud, Cd, out);
  } else {
    k_dec1m<__hip_bfloat16><<<dim3(NB/64), dim3(512), 0, stream>>>(x, y, ctx, wb2, tb,
        h0f, h1f, c0f, c1f, (__hip_bfloat16*)h1n);
    k_bn2s<__hip_bfloat16><<<dim3(NOUT, F2), dim3(256), 0, stream>>>((const __hip_bfloat16*)h1n, xcg, x, y, m2, r2);
    k_readout<__hip_bfloat16><<<dim3(NB/256, NOUT), dim3(256), 0, stream>>>(x, y, (const __hip_bfloat16*)h1n,
        xcg, m2, r2, bn2g, bn2b, Wd, Bd, Ud, Cd, out);
  }
}

// Round 7
// 1336.755 us; speedup vs baseline: 18.4906x; 1.2900x over previous
//
#include <hip/hip_runtime.h>
#include <hip/hip_bf16.h>

#define NB   16384
#define TT   50
#define HH   30
#define IND  8
#define CTXD 80
#define IN2  82
#define F2   52
#define NOUT 50
#define HID  100
#define CVD  20

typedef __attribute__((ext_vector_type(8))) short s8v;
typedef __attribute__((ext_vector_type(4))) float f4v;

__device__ __forceinline__ float sg(float x){
  x = fminf(fmaxf(x, -30.f), 30.f);
  return 1.f/(1.f+__expf(-x));
}
__device__ __forceinline__ float th(float x){
  x = fminf(fmaxf(x, -15.f), 15.f);
  float e = __expf(2.f*x);
  return (e-1.f)/(e+1.f);
}
__device__ __forceinline__ float ldv(const float* p){ return *p; }
__device__ __forceinline__ float ldv(const __hip_bfloat16* p){ return __bfloat162float(*p); }
__device__ __forceinline__ void stv(float* p, float v){ *p = v; }
__device__ __forceinline__ void stv(__hip_bfloat16* p, float v){ *p = __float2bfloat16(v); }
__device__ __forceinline__ unsigned short f2b(float f){
  __hip_bfloat16 h = __float2bfloat16(f);
  return *reinterpret_cast<unsigned short*>(&h);
}
__device__ __forceinline__ float b2f(unsigned short u){
  __hip_bfloat16 h;
  *reinterpret_cast<unsigned short*>(&h) = u;
  return __bfloat162float(h);
}

// ---------------- decoder MFMA fragment tables ----------------
// frags: f=0..7 layer0 (Wh0), f=8..23 layer1 (ks0=Wx1,ks1=Wh1), f=24..47 ctx (3 ksteps)
// wb2[(f*64+lane)*8+j]; B[k][col]: k=ks*32+8*(lane>>4)+j, col=ct*16+(lane&15); col=g*32+u
__global__ void k_tw2(const float* __restrict__ w2ih0, const float* __restrict__ w2hh0,
                      const float* __restrict__ w2ih1, const float* __restrict__ w2hh1,
                      const float* __restrict__ b2ih0, const float* __restrict__ b2hh0,
                      const float* __restrict__ b2ih1, const float* __restrict__ b2hh1,
                      unsigned short* __restrict__ wb2, float* __restrict__ tb)
{
  int idx = blockIdx.x*256 + threadIdx.x;
  if (idx < 48*512){
    int f = idx >> 9, rem = idx & 511;
    int l = rem >> 3, j = rem & 7;
    int lr = l & 15, lq = l >> 4;
    float v = 0.f;
    if (f < 8){
      int ct = f, k = 8*lq + j, col = ct*16 + lr;
      int g = col>>5, u = col&31;
      if (k < HH && u < HH) v = w2hh0[(size_t)(g*HH+u)*HH + k];
    } else if (f < 24){
      int ct = (f-8)>>1, ks = (f-8)&1, k = 8*lq + j, col = ct*16 + lr;
      int g = col>>5, u = col&31;
      if (k < HH && u < HH) v = ks ? w2hh1[(size_t)(g*HH+u)*HH + k] : w2ih1[(size_t)(g*HH+u)*HH + k];
    } else {
      int ct = (f-24)/3, ks = (f-24)%3, k = ks*32 + 8*lq + j, col = ct*16 + lr;
      int g = col>>5, u = col&31;
      if (k < CTXD && u < HH) v = w2ih0[(size_t)(g*HH+u)*IN2 + k];
    }
    wb2[idx] = f2b(v);
  } else if (idx < 48*512 + 512){
    int t = idx - 48*512;
    int col = t & 127, sel = t >> 7;
    int g = col>>5, u = col&31;
    float v = 0.f;
    if (u < HH){
      int r = g*HH + u;
      if (sel == 0) v = b2ih0[r] + b2hh0[r];
      else if (sel == 1) v = b2ih1[r] + b2hh1[r];
      else if (sel == 2) v = w2ih0[(size_t)r*IN2 + 80];
      else v = w2ih0[(size_t)r*IN2 + 81];
    }
    tb[sel*128 + col] = v;
  }
}

// ---------------- encoder MFMA fragment tables ----------------
// f=0..7: Wx0 (K=32, 8 used); f=8..15: Wh0; f=16..31: layer1 (ks0=Wih1,ks1=Whh1)
__global__ void k_tw3(const float* __restrict__ wih0, const float* __restrict__ whh0,
                      const float* __restrict__ wih1, const float* __restrict__ whh1,
                      const float* __restrict__ bih0, const float* __restrict__ bhh0,
                      const float* __restrict__ bih1, const float* __restrict__ bhh1,
                      unsigned short* __restrict__ wb3, float* __restrict__ tbe)
{
  int idx = blockIdx.x*256 + threadIdx.x;
  if (idx < 32*512){
    int f = idx >> 9, rem = idx & 511;
    int l = rem >> 3, j = rem & 7;
    int lr = l & 15, lq = l >> 4;
    int k = 8*lq + j;
    float v = 0.f;
    if (f < 8){
      int col = f*16 + lr; int g = col>>5, u = col&31;
      if (k < IND && u < HH) v = wih0[(size_t)(g*HH+u)*IND + k];
    } else if (f < 16){
      int ct = f-8; int col = ct*16 + lr; int g = col>>5, u = col&31;
      if (k < HH && u < HH) v = whh0[(size_t)(g*HH+u)*HH + k];
    } else {
      int ct = (f-16)>>1, ks = (f-16)&1; int col = ct*16 + lr; int g = col>>5, u = col&31;
      if (k < HH && u < HH) v = ks ? whh1[(size_t)(g*HH+u)*HH + k] : wih1[(size_t)(g*HH+u)*HH + k];
    }
    wb3[idx] = f2b(v);
  } else if (idx < 32*512 + 256){
    int t2 = idx - 32*512;
    int col = t2 & 127, sel = t2 >> 7;
    int g = col>>5, u = col&31;
    float v = 0.f;
    if (u < HH){
      int r = g*HH + u;
      v = sel ? (bih1[r] + bhh1[r]) : (bih0[r] + bhh0[r]);
    }
    tbe[sel*128 + col] = v;
  }
}

// ---------------- zero BN1 accumulators ----------------
__global__ void k_zero(double* a){
  int i = threadIdx.x;
  if (i < CTXD*2) a[i] = 0.0;
}

// ---------------- encoder: MFMA LSTM ----------------
// 8 waves; wave w: sample-tile st=w&3, unit-group ug=w>>2; lane: unit u=ug*16+(l&15),
// 4 samples st*16+4*(l>>4)+i; gate-major cols (col=g*32+u), accs = {i,f,g,o}.
__global__ __launch_bounds__(512, 2) void k_encm(
    const float* __restrict__ x, const float* __restrict__ h0i, const float* __restrict__ c0i,
    const unsigned short* __restrict__ wb3, const float* __restrict__ tbe,
    float* __restrict__ h0f, float* __restrict__ h1f,
    float* __restrict__ c0f, float* __restrict__ c1f)
{
  __shared__ __align__(16) unsigned short XS[TT*64*8];   // x bf16 [t][smp][d]
  __shared__ __align__(16) unsigned short H0[2][64*32];
  __shared__ __align__(16) unsigned short H1[2][64*32];
  const int tid = threadIdx.x;
  const int l = tid & 63, w = tid >> 6;
  const int st = w & 3, ug = w >> 2;
  const int lr = l & 15, lq = l >> 4, l3 = l & 3;
  const int blk = blockIdx.x;

  for (int i = tid; i < 64*100; i += 512){
    int smp = i/100, q = i - smp*100;
    float4 v = ((const float4*)(x + (size_t)(blk*64+smp)*(TT*IND)))[q];
    int td = q*4;
    int t = td >> 3, d = td & 7;
    unsigned short* p = &XS[t*512 + smp*8 + d];
    p[0]=f2b(v.x); p[1]=f2b(v.y); p[2]=f2b(v.z); p[3]=f2b(v.w);
  }
  for (int i = tid; i < 64*32; i += 512){
    H0[0][i]=0; H0[1][i]=0; H1[0][i]=0; H1[1][i]=0;
  }
  __syncthreads();
  for (int i = tid; i < 64*HH; i += 512){
    int r = i/HH, u2 = i - r*HH;
    int off = r*32 + (((u2>>3) ^ (r&3))<<3) + (u2&7);
    H0[0][off] = f2b(h0i[u2]);
    H1[0][off] = f2b(h0i[HH+u2]);
  }

  const int u  = ug*16 + lr;
  const int uc = u < HH ? u : HH-1;
  const int arow = st*16 + lr;
  const int aoff = arow*32 + ((lq ^ l3)<<3);
  int wr[4];
  float c0[4], c1[4];
  #pragma unroll
  for (int i=0;i<4;++i){
    int smp = st*16 + 4*lq + i;
    wr[i] = smp*32 + (((u>>3) ^ i)<<3) + (u&7);
    c0[i] = c0i[uc];
    c1[i] = c0i[HH+uc];
  }
  s8v BX[4], BH[4], B10[4], B11[4];
  float b0v[4], b1v[4];
  #pragma unroll
  for (int g=0; g<4; ++g){
    const int ct = g*2 + ug;
    const int col = ct*16 + lr;
    BX[g]  = *(const s8v*)(wb3 + ((size_t)(ct)*64 + l)*8);
    BH[g]  = *(const s8v*)(wb3 + ((size_t)(8 + ct)*64 + l)*8);
    B10[g] = *(const s8v*)(wb3 + ((size_t)(16 + ct*2 + 0)*64 + l)*8);
    B11[g] = *(const s8v*)(wb3 + ((size_t)(16 + ct*2 + 1)*64 + l)*8);
    b0v[g] = tbe[col]; b1v[g] = tbe[128+col];
  }
  __syncthreads();

  int cur = 0;
  for (int t=0; t<TT; ++t){
    const int nxt = cur ^ 1;
    s8v ax = {0,0,0,0,0,0,0,0};
    if (lq == 0) ax = *(const s8v*)&XS[t*512 + arow*8];
    const s8v ah = *(const s8v*)&H0[cur][aoff];
    f4v ac[4];
    #pragma unroll
    for (int g=0; g<4; ++g){
      f4v a = {b0v[g], b0v[g], b0v[g], b0v[g]};
      a = __builtin_amdgcn_mfma_f32_16x16x32_bf16(ax, BX[g], a, 0, 0, 0);
      ac[g] = __builtin_amdgcn_mfma_f32_16x16x32_bf16(ah, BH[g], a, 0, 0, 0);
    }
    unsigned short hw[4];
    #pragma unroll
    for (int i=0;i<4;++i){
      float iv = sg(ac[0][i]), fv = sg(ac[1][i]), gv = th(ac[2][i]), ov = sg(ac[3][i]);
      c0[i] = fv*c0[i] + iv*gv;
      hw[i] = f2b(ov*th(c0[i]));
    }
    if (u < HH){
      #pragma unroll
      for (int i=0;i<4;++i) H0[nxt][wr[i]] = hw[i];
    }
    __syncthreads();
    const s8v a1 = *(const s8v*)&H0[nxt][aoff];
    const s8v a2 = *(const s8v*)&H1[cur][aoff];
    #pragma unroll
    for (int g=0; g<4; ++g){
      f4v a = {b1v[g], b1v[g], b1v[g], b1v[g]};
      a = __builtin_amdgcn_mfma_f32_16x16x32_bf16(a1, B10[g], a, 0, 0, 0);
      ac[g] = __builtin_amdgcn_mfma_f32_16x16x32_bf16(a2, B11[g], a, 0, 0, 0);
    }
    #pragma unroll
    for (int i=0;i<4;++i){
      float iv = sg(ac[0][i]), fv = sg(ac[1][i]), gv = th(ac[2][i]), ov = sg(ac[3][i]);
      c1[i] = fv*c1[i] + iv*gv;
      hw[i] = f2b(ov*th(c1[i]));
    }
    if (u < HH){
      #pragma unroll
      for (int i=0;i<4;++i) H1[nxt][wr[i]] = hw[i];
    }
    __syncthreads();
    cur = nxt;
  }
  for (int i2 = tid; i2 < 64*HH; i2 += 512){
    int sl = i2 / HH, uu = i2 - sl*HH;
    int off = sl*32 + (((uu>>3) ^ (sl&3))<<3) + (uu&7);
    h0f[((size_t)blk*64 + sl)*HH + uu] = b2f(H0[cur][off]);
    h1f[((size_t)blk*64 + sl)*HH + uu] = b2f(H1[cur][off]);
  }
  if (u < HH){
    #pragma unroll
    for (int i=0;i<4;++i){
      int gS = blk*64 + st*16 + 4*lq + i;
      c0f[(size_t)gS*HH + u] = c0[i];
      c1f[(size_t)gS*HH + u] = c1[i];
    }
  }
}

// ---------------- conv path ----------------
__global__ __launch_bounds__(64) void k_conv(
    const float* __restrict__ x,
    const float* __restrict__ w1, const float* __restrict__ b1,
    const float* __restrict__ w2, const float* __restrict__ b2,
    const float* __restrict__ w3, const float* __restrict__ b3,
    const float* __restrict__ fw, const float* __restrict__ fb,
    float* __restrict__ xcg)
{
  __shared__ float xr[IND][TT];
  __shared__ float p1[32][23];
  __shared__ float p2[64][11];
  __shared__ float p3[512];
  __shared__ float red[64][21];
  const int b = blockIdx.x, tid = threadIdx.x;
  for (int i=tid;i<TT*IND;i+=64){
    float v = x[(size_t)b*(TT*IND) + i];
    xr[i % IND][i / IND] = v;
  }
  __syncthreads();
  if (tid < 23){
    float a0[32], a1[32];
    #pragma unroll
    for (int oc=0;oc<32;++oc){ float bb=b1[oc]; a0[oc]=bb; a1[oc]=bb; }
    for (int ic=0;ic<IND;++ic){
      float xw[6];
      #pragma unroll
      for (int q=0;q<6;++q) xw[q] = xr[ic][2*tid+q];
      #pragma unroll
      for (int kk=0;kk<5;++kk){
        float va = xw[kk], vb = xw[kk+1];
        #pragma unroll
        for (int oc=0;oc<32;++oc){
          float w = w1[(size_t)(oc*IND+ic)*5 + kk];
          a0[oc] += w*va; a1[oc] += w*vb;
        }
      }
    }
    #pragma unroll
    for (int oc=0;oc<32;++oc)
      p1[oc][tid] = fmaxf(fmaxf(a0[oc],0.f), fmaxf(a1[oc],0.f));
  }
  __syncthreads();
  {
    float acc[21];
    #pragma unroll
    for (int t=0;t<21;++t) acc[t] = b2[tid];
    for (int ic=0;ic<32;++ic){
      float xv[23];
      #pragma unroll
      for (int q=0;q<23;++q) xv[q] = p1[ic][q];
      #pragma unroll
      for (int kk=0;kk<3;++kk){
        float w = w2[(size_t)(tid*32+ic)*3 + kk];
        #pragma unroll
        for (int t=0;t<21;++t) acc[t] += w*xv[t+kk];
      }
    }
    #pragma unroll
    for (int p=0;p<10;++p)
      p2[tid][p] = fmaxf(fmaxf(acc[2*p],0.f), fmaxf(acc[2*p+1],0.f));
  }
  __syncthreads();
  {
    float a0[8], a1[8];
    #pragma unroll
    for (int t=0;t<8;++t){ a0[t]=b3[tid]; a1[t]=b3[tid+64]; }
    for (int ic=0;ic<64;++ic){
      float xv[10];
      #pragma unroll
      for (int q=0;q<10;++q) xv[q] = p2[ic][q];
      #pragma unroll
      for (int kk=0;kk<3;++kk){
        float wa = w3[(size_t)(tid*64+ic)*3 + kk];
        float wb = w3[(size_t)((tid+64)*64+ic)*3 + kk];
        #pragma unroll
        for (int t=0;t<8;++t){ a0[t]+=wa*xv[t+kk]; a1[t]+=wb*xv[t+kk]; }
      }
    }
    #pragma unroll
    for (int p=0;p<4;++p){
      p3[tid*4+p]      = fmaxf(fmaxf(a0[2*p],0.f), fmaxf(a0[2*p+1],0.f));
      p3[(tid+64)*4+p] = fmaxf(fmaxf(a1[2*p],0.f), fmaxf(a1[2*p+1],0.f));
    }
  }
  __syncthreads();
  {
    float xs[8];
    #pragma unroll
    for (int q=0;q<8;++q) xs[q] = p3[tid*8+q];
    float acc[20];
    #pragma unroll
    for (int j=0;j<20;++j){
      float a = 0.f;
      #pragma unroll
      for (int q=0;q<8;++q) a += xs[q] * fw[(size_t)j*512 + tid*8 + q];
      acc[j] = a;
    }
    #pragma unroll
    for (int j=0;j<20;++j) red[tid][j] = acc[j];
  }
  __syncthreads();
  if (tid < 20){
    float s = fb[tid];
    for (int l=0;l<64;++l) s += red[l][tid];
    xcg[(size_t)b*CVD + tid] = fmaxf(s, 0.f);
  }
}

// ---------------- BN1 stats ----------------
__global__ __launch_bounds__(128) void k_bn1s(const float* __restrict__ h0f, const float* __restrict__ h1f,
    const float* __restrict__ xcg, double* __restrict__ s1)
{
  int f = threadIdx.x;
  if (f >= CTXD) return;
  int r0 = blockIdx.x*128;
  double s=0.0, q=0.0;
  for (int i=0;i<128;++i){
    int r = r0+i;
    float v = (f<HH) ? h0f[(size_t)r*HH+f] : (f<2*HH) ? h1f[(size_t)r*HH + f-HH] : xcg[(size_t)r*CVD + f-2*HH];
    s += (double)v; q += (double)v*(double)v;
  }
  atomicAdd(&s1[f*2],   s);
  atomicAdd(&s1[f*2+1], q);
}

__global__ void k_fin1(const double* __restrict__ s1, float* __restrict__ st1){
  int f = threadIdx.x;
  if (f >= CTXD) return;
  double m = s1[f*2]/(double)NB;
  double var = s1[f*2+1]/(double)NB - m*m;
  if (var < 0.0) var = 0.0;
  st1[f*2]   = (float)m;
  st1[f*2+1] = (float)(1.0/sqrt(var + 1e-5));
}

__global__ __launch_bounds__(256) void k_context(const float* __restrict__ h0f, const float* __restrict__ h1f,
    const float* __restrict__ xcg, const float* __restrict__ st1,
    const float* __restrict__ g1, const float* __restrict__ bb1, float* __restrict__ ctx)
{
  int idx = blockIdx.x*256 + threadIdx.x;
  if (idx >= NB*CTXD) return;
  int rr = idx / CTXD, f = idx - rr*CTXD;
  float v = (f<HH) ? h0f[(size_t)rr*HH+f] : (f<2*HH) ? h1f[(size_t)rr*HH + f-HH] : xcg[(size_t)rr*CVD + f-2*HH];
  ctx[idx] = (v - st1[f*2]) * st1[f*2+1] * g1[f] + bb1[f];
}

// ---------------- decoder pass 1: MFMA LSTM ----------------
template<typename ST>
__global__ __launch_bounds__(512, 2) void k_dec1m(
    const float* __restrict__ x, const float* __restrict__ y,
    const float* __restrict__ ctx,
    const unsigned short* __restrict__ wb2, const float* __restrict__ tb,
    const float* __restrict__ h0fi, const float* __restrict__ h1fi,
    const float* __restrict__ c0fi, const float* __restrict__ c1fi,
    ST* __restrict__ h1n)
{
  __shared__ __align__(16) unsigned short CT[64*96];
  __shared__ __align__(16) unsigned short Hh0[2][64*32];
  __shared__ __align__(16) unsigned short Hh1[2][64*32];
  const int tid = threadIdx.x;
  const int l  = tid & 63, w = tid >> 6;
  const int st = w & 3, ug = w >> 2;
  const int lr = l & 15, lq = l >> 4, l3 = l & 3;
  const int blk = blockIdx.x;

  for (int i = tid; i < 64*32; i += 512){
    Hh0[0][i] = 0; Hh0[1][i] = 0; Hh1[0][i] = 0; Hh1[1][i] = 0;
  }
  for (int i = tid; i < 64*96; i += 512) CT[i] = 0;
  __syncthreads();
  for (int i = tid; i < 64*CTXD; i += 512){
    int r = i / CTXD, kk = i - r*CTXD;
    float v = ctx[((size_t)blk*64 + r)*CTXD + kk];
    CT[r*96 + (((kk>>3) ^ (r&3))<<3) + (kk&7)] = f2b(v);
  }
  for (int i = tid; i < 64*HH; i += 512){
    int r = i / HH, u2 = i - r*HH;
    int off = r*32 + (((u2>>3) ^ (r&3))<<3) + (u2&7);
    Hh0[0][off] = f2b(h0fi[((size_t)blk*64 + r)*HH + u2]);
    Hh1[0][off] = f2b(h1fi[((size_t)blk*64 + r)*HH + u2]);
  }

  const int u  = ug*16 + lr;
  const int uc = u < HH ? u : HH-1;
  const int arow = st*16 + lr;
  const int aoff = arow*32 + ((lq ^ l3)<<3);

  int wr[4]; int gS[4];
  float c0[4], c1[4], tt[4], yv[4];
  #pragma unroll
  for (int i=0;i<4;++i){
    int smp = st*16 + 4*lq + i;
    gS[i] = blk*64 + smp;
    wr[i] = smp*32 + (((u>>3) ^ i)<<3) + (u&7);
    c0[i] = c0fi[(size_t)gS[i]*HH + uc];
    c1[i] = c1fi[(size_t)gS[i]*HH + uc];
    tt[i] = x[(size_t)gS[i]*(TT*IND) + (TT-1)*IND + 7];
    yv[i] = x[(size_t)gS[i]*(TT*IND) + (TT-1)*IND + 0];
  }

  s8v B0[4], B10[4], B11[4], BC0[4], BC1[4], BC2[4];
  float bias0[4], bias1[4], wtt[4], wty[4];
  #pragma unroll
  for (int g=0; g<4; ++g){
    const int ct = g*2 + ug;
    const int col = ct*16 + lr;
    B0[g]  = *(const s8v*)(wb2 + ((size_t)(ct)*64 + l)*8);
    B10[g] = *(const s8v*)(wb2 + ((size_t)(8 + ct*2 + 0)*64 + l)*8);
    B11[g] = *(const s8v*)(wb2 + ((size_t)(8 + ct*2 + 1)*64 + l)*8);
    BC0[g] = *(const s8v*)(wb2 + ((size_t)(24 + ct*3 + 0)*64 + l)*8);
    BC1[g] = *(const s8v*)(wb2 + ((size_t)(24 + ct*3 + 1)*64 + l)*8);
    BC2[g] = *(const s8v*)(wb2 + ((size_t)(24 + ct*3 + 2)*64 + l)*8);
    bias0[g] = tb[col]; bias1[g] = tb[128+col];
    wtt[g] = tb[256+col]; wty[g] = tb[384+col];
  }
  __syncthreads();

  f4v pc[4];
  #pragma unroll
  for (int g=0; g<4; ++g){
    f4v a = {bias0[g], bias0[g], bias0[g], bias0[g]};
    {
      const s8v av = *(const s8v*)&CT[arow*96 + (((0*4+lq) ^ l3)<<3)];
      a = __builtin_amdgcn_mfma_f32_16x16x32_bf16(av, BC0[g], a, 0, 0, 0);
    }
    {
      const s8v av = *(const s8v*)&CT[arow*96 + (((1*4+lq) ^ l3)<<3)];
      a = __builtin_amdgcn_mfma_f32_16x16x32_bf16(av, BC1[g], a, 0, 0, 0);
    }
    {
      const s8v av = *(const s8v*)&CT[arow*96 + (((2*4+lq) ^ l3)<<3)];
      a = __builtin_amdgcn_mfma_f32_16x16x32_bf16(av, BC2[g], a, 0, 0, 0);
    }
    pc[g] = a;
  }

  int cur = 0;
  for (int s = 0; s < NOUT; ++s){
    const int nxt = cur ^ 1;
    #pragma unroll
    for (int i=0;i<4;++i) tt[i] = fmodf(tt[i] + 15.f, 1440.f);
    const s8v a0 = *(const s8v*)&Hh0[cur][aoff];
    f4v ac[4];
    #pragma unroll
    for (int g=0; g<4; ++g){
      f4v a = pc[g];
      #pragma unroll
      for (int i=0;i<4;++i) a[i] += tt[i]*wtt[g] + yv[i]*wty[g];
      ac[g] = __builtin_amdgcn_mfma_f32_16x16x32_bf16(a0, B0[g], a, 0, 0, 0);
    }
    unsigned short hw[4];
    #pragma unroll
    for (int i=0;i<4;++i){
      float iv = sg(ac[0][i]), fv = sg(ac[1][i]), gv = th(ac[2][i]), ov = sg(ac[3][i]);
      c0[i] = fv*c0[i] + iv*gv;
      hw[i] = f2b(ov*th(c0[i]));
    }
    if (u < HH){
      #pragma unroll
      for (int i=0;i<4;++i) Hh0[nxt][wr[i]] = hw[i];
    }
    __syncthreads();
    const s8v a1 = *(const s8v*)&Hh0[nxt][aoff];
    const s8v a2 = *(const s8v*)&Hh1[cur][aoff];
    #pragma unroll
    for (int g=0; g<4; ++g){
      f4v a = {bias1[g], bias1[g], bias1[g], bias1[g]};
      a = __builtin_amdgcn_mfma_f32_16x16x32_bf16(a1, B10[g], a, 0, 0, 0);
      ac[g] = __builtin_amdgcn_mfma_f32_16x16x32_bf16(a2, B11[g], a, 0, 0, 0);
    }
    #pragma unroll
    for (int i=0;i<4;++i){
      float iv = sg(ac[0][i]), fv = sg(ac[1][i]), gv = th(ac[2][i]), ov = sg(ac[3][i]);
      c1[i] = fv*c1[i] + iv*gv;
      hw[i] = f2b(ov*th(c1[i]));
    }
    if (u < HH){
      #pragma unroll
      for (int i=0;i<4;++i) Hh1[nxt][wr[i]] = hw[i];
    }
    __syncthreads();
    for (int i2 = tid; i2 < 64*HH; i2 += 512){
      int uu = i2 >> 6, sl = i2 & 63;
      unsigned short hv = Hh1[nxt][sl*32 + (((uu>>3) ^ (sl&3))<<3) + (uu&7)];
      stv(&h1n[((size_t)s*HH + uu)*NB + (size_t)blk*64 + sl], b2f(hv));
    }
    #pragma unroll
    for (int i=0;i<4;++i) yv[i] = y[(size_t)gS[i]*NOUT + s];
    cur = nxt;
  }
}

// ---------------- BN2 stats ----------------
template<typename ST>
__global__ __launch_bounds__(256) void k_bn2s(
    const ST* __restrict__ h1n, const float* __restrict__ xcg,
    const float* __restrict__ x, const float* __restrict__ y,
    float* __restrict__ m2, float* __restrict__ r2)
{
  __shared__ double sd[256];
  __shared__ double qd[256];
  const int s = blockIdx.x;
  const int f = blockIdx.y;
  double sv = 0.0, sq = 0.0;
  if (f < HH){
    const ST* p = h1n + ((size_t)s*HH + f)*NB;
    for (int i = threadIdx.x*8; i < NB; i += 256*8){
      #pragma unroll
      for (int u=0;u<8;++u){ float v = ldv(p + i + u); sv += v; sq += (double)v*(double)v; }
    }
  } else if (f < HH+CVD){
    const float* p = xcg + (f-HH);
    for (int i = threadIdx.x; i < NB; i += 256){
      float v = p[(size_t)i*CVD]; sv += v; sq += (double)v*(double)v;
    }
  } else if (f == HH+CVD){
    for (int i = threadIdx.x; i < NB; i += 256){
      float t = x[(size_t)i*(TT*IND) + (TT-1)*IND + 7];
      for (int k=0;k<=s;++k) t = fmodf(t + 15.f, 1440.f);
      sv += t; sq += (double)t*(double)t;
    }
  } else {
    for (int i = threadIdx.x; i < NB; i += 256){
      float v = (s==0) ? x[(size_t)i*(TT*IND) + (TT-1)*IND + 0] : y[(size_t)i*NOUT + (s-1)];
      sv += v; sq += (double)v*(double)v;
    }
  }
  sd[threadIdx.x] = sv; qd[threadIdx.x] = sq;
  __syncthreads();
  for (int st2=128; st2>0; st2>>=1){
    if ((int)threadIdx.x < st2){
      sd[threadIdx.x] += sd[threadIdx.x+st2];
      qd[threadIdx.x] += qd[threadIdx.x+st2];
    }
    __syncthreads();
  }
  if (threadIdx.x == 0){
    double m = sd[0]/(double)NB;
    double var = qd[0]/(double)NB - m*m;
    if (var < 0.0) var = 0.0;
    m2[s*F2+f] = (float)m;
    r2[s*F2+f] = (float)(1.0/sqrt(var + 1e-5));
  }
}

// ---------------- decoder pass 2: BN2 + dense readout ----------------
template<typename ST>
__global__ __launch_bounds__(256) void k_readout(
    const float* __restrict__ x, const float* __restrict__ y, const ST* __restrict__ h1n,
    const float* __restrict__ xcg, const float* __restrict__ m2, const float* __restrict__ r2,
    const float* __restrict__ g2, const float* __restrict__ b2,
    const float* __restrict__ Wd, const float* __restrict__ Bd,
    const float* __restrict__ Ud, const float* __restrict__ Cd, float* __restrict__ out)
{
  const int s  = blockIdx.y;
  const int rr = blockIdx.x*256 + threadIdx.x;
  float feat[F2];
  #pragma unroll
  for (int f=0; f<HH; ++f) feat[f] = ldv(&h1n[((size_t)s*HH+f)*NB + rr]);
  #pragma unroll
  for (int f=0; f<CVD; ++f) feat[HH+f] = xcg[(size_t)rr*CVD + f];
  float t0 = x[(size_t)rr*(TT*IND) + (TT-1)*IND + 7];
  for (int i=0;i<=s;++i) t0 = fmodf(t0 + 15.f, 1440.f);
  feat[HH+CVD] = t0;
  feat[HH+CVD+1] = (s==0) ? x[(size_t)rr*(TT*IND) + (TT-1)*IND + 0] : y[(size_t)rr*NOUT + (s-1)];
  #pragma unroll
  for (int f=0; f<F2; ++f)
    feat[f] = (feat[f] - m2[s*F2+f]) * r2[s*F2+f] * g2[f] + b2[f];
  float yvv = Cd[s];
  #pragma unroll 1
  for (int jb=0; jb<HID; jb+=10){
    float a[10];
    #pragma unroll
    for (int jt=0;jt<10;++jt) a[jt] = Bd[(size_t)s*HID + jb + jt];
    #pragma unroll 4
    for (int k=0;k<F2;++k){
      const float v = feat[k];
      #pragma unroll
      for (int jt=0;jt<10;++jt)
        a[jt] += v * Wd[((size_t)s*F2 + k)*HID + jb + jt];
    }
    #pragma unroll
    for (int jt=0;jt<10;++jt)
      yvv += fmaxf(a[jt], 0.f) * Ud[(size_t)s*HID + jb + jt];
  }
  out[(size_t)rr*NOUT + s] = yvv;
}

// ---------------- host ----------------
extern "C" void kernel_launch(void* const* d_in, const int* in_sizes, int n_in,
                              void* d_out, int out_size, void* d_ws, size_t ws_size,
                              hipStream_t stream)
{
  const float* x    = (const float*)d_in[0];
  const float* y    = (const float*)d_in[1];
  const float* h0i  = (const float*)d_in[2];
  const float* c0i  = (const float*)d_in[3];
  const float* wih0 = (const float*)d_in[4];
  const float* whh0 = (const float*)d_in[5];
  const float* bih0 = (const float*)d_in[6];
  const float* bhh0 = (const float*)d_in[7];
  const float* wih1 = (const float*)d_in[8];
  const float* whh1 = (const float*)d_in[9];
  const float* bih1 = (const float*)d_in[10];
  const float* bhh1 = (const float*)d_in[11];
  const float* w2ih0= (const float*)d_in[12];
  const float* w2hh0= (const float*)d_in[13];
  const float* b2ih0= (const float*)d_in[14];
  const float* b2hh0= (const float*)d_in[15];
  const float* w2ih1= (const float*)d_in[16];
  const float* w2hh1= (const float*)d_in[17];
  const float* b2ih1= (const float*)d_in[18];
  const float* b2hh1= (const float*)d_in[19];
  const float* c1w  = (const float*)d_in[20];
  const float* c1b  = (const float*)d_in[21];
  const float* c2w  = (const float*)d_in[22];
  const float* c2b  = (const float*)d_in[23];
  const float* c3w  = (const float*)d_in[24];
  const float* c3b  = (const float*)d_in[25];
  const float* fcw  = (const float*)d_in[26];
  const float* fcb  = (const float*)d_in[27];
  const float* bn1g = (const float*)d_in[28];
  const float* bn1b = (const float*)d_in[29];
  const float* bn2g = (const float*)d_in[30];
  const float* bn2b = (const float*)d_in[31];
  const float* Wd   = (const float*)d_in[32];
  const float* Bd   = (const float*)d_in[33];
  const float* Ud   = (const float*)d_in[34];
  const float* Cd   = (const float*)d_in[35];
  float* out = (float*)d_out;

  char* base = (char*)d_ws;
  size_t off = 0;
  auto take = [&](size_t bytes)->char*{
    char* p = base + off;
    off = (off + bytes + 255) & ~(size_t)255;
    return p;
  };
  float*  h0f = (float*) take((size_t)NB*HH*sizeof(float));
  float*  h1f = (float*) take((size_t)NB*HH*sizeof(float));
  float*  c0f = (float*) take((size_t)NB*HH*sizeof(float));
  float*  c1f = (float*) take((size_t)NB*HH*sizeof(float));
  float*  xcg = (float*) take((size_t)NB*CVD*sizeof(float));
  float*  ctx = (float*) take((size_t)NB*CTXD*sizeof(float));
  double* s1  = (double*)take((size_t)CTXD*2*sizeof(double));
  float*  st1 = (float*) take((size_t)CTXD*2*sizeof(float));
  float*  m2  = (float*) take((size_t)NOUT*F2*sizeof(float));
  float*  r2  = (float*) take((size_t)NOUT*F2*sizeof(float));
  unsigned short* wb2 = (unsigned short*) take((size_t)48*512*sizeof(unsigned short));
  float*  tb  = (float*) take((size_t)4*128*sizeof(float));
  unsigned short* wb3 = (unsigned short*) take((size_t)32*512*sizeof(unsigned short));
  float*  tbe = (float*) take((size_t)2*128*sizeof(float));
  size_t fixed = off;
  size_t rem = (ws_size > fixed) ? (ws_size - fixed) : 0;
  bool f32st = rem >= (size_t)NOUT*HH*NB*sizeof(float);
  void* h1n = (void*)(base + off);

  k_tw2<<<dim3((48*512+512+255)/256), dim3(256), 0, stream>>>(w2ih0, w2hh0, w2ih1, w2hh1,
      b2ih0, b2hh0, b2ih1, b2hh1, wb2, tb);
  k_tw3<<<dim3((32*512+256+255)/256), dim3(256), 0, stream>>>(wih0, whh0, wih1, whh1,
      bih0, bhh0, bih1, bhh1, wb3, tbe);
  k_zero<<<dim3(1), dim3(256), 0, stream>>>(s1);
  k_encm<<<dim3(NB/64), dim3(512), 0, stream>>>(x, h0i, c0i, wb3, tbe, h0f, h1f, c0f, c1f);
  k_conv<<<dim3(NB), dim3(64), 0, stream>>>(x, c1w, c1b, c2w, c2b, c3w, c3b, fcw, fcb, xcg);
  k_bn1s<<<dim3(NB/128), dim3(128), 0, stream>>>(h0f, h1f, xcg, s1);
  k_fin1<<<dim3(1), dim3(128), 0, stream>>>(s1, st1);
  k_context<<<dim3((NB*CTXD + 255)/256), dim3(256), 0, stream>>>(h0f, h1f, xcg, st1, bn1g, bn1b, ctx);
  if (f32st){
    k_dec1m<float><<<dim3(NB/64), dim3(512), 0, stream>>>(x, y, ctx, wb2, tb,
        h0f, h1f, c0f, c1f, (float*)h1n);
    k_bn2s<float><<<dim3(NOUT, F2), dim3(256), 0, stream>>>((const float*)h1n, xcg, x, y, m2, r2);
    k_readout<float><<<dim3(NB/256, NOUT), dim3(256), 0, stream>>>(x, y, (const float*)h1n,
        xcg, m2, r2, bn2g, bn2b, Wd, Bd, Ud, Cd, out);
  } else {
    k_dec1m<__hip_bfloat16><<<dim3(NB/64), dim3(512), 0, stream>>>(x, y, ctx, wb2, tb,
        h0f, h1f, c0f, c1f, (__hip_bfloat16*)h1n);
    k_bn2s<__hip_bfloat16><<<dim3(NOUT, F2), dim3(256), 0, stream>>>((const __hip_bfloat16*)h1n, xcg, x, y, m2, r2);
    k_readout<__hip_bfloat16><<<dim3(NB/256, NOUT), dim3(256), 0, stream>>>(x, y, (const __hip_bfloat16*)h1n,
        xcg, m2, r2, bn2g, bn2b, Wd, Bd, Ud, Cd, out);
  }
}

// Round 8
// 967.966 us; speedup vs baseline: 25.5355x; 1.3810x over previous
//
#include <hip/hip_runtime.h>
#include <hip/hip_bf16.h>

#define NB   16384
#define TT   50
#define HH   30
#define IND  8
#define CTXD 80
#define IN2  82
#define F2   52
#define NOUT 50
#define HID  100
#define CVD  20

typedef __attribute__((ext_vector_type(8))) short s8v;
typedef __attribute__((ext_vector_type(4))) float f4v;

__device__ __forceinline__ float sg(float x){
  x = fminf(fmaxf(x, -30.f), 30.f);
  return 1.f/(1.f+__expf(-x));
}
__device__ __forceinline__ float th(float x){
  x = fminf(fmaxf(x, -15.f), 15.f);
  float e = __expf(2.f*x);
  return (e-1.f)/(e+1.f);
}
__device__ __forceinline__ float ldv(const float* p){ return *p; }
__device__ __forceinline__ float ldv(const __hip_bfloat16* p){ return __bfloat162float(*p); }
__device__ __forceinline__ void stv(float* p, float v){ *p = v; }
__device__ __forceinline__ void stv(__hip_bfloat16* p, float v){ *p = __float2bfloat16(v); }
__device__ __forceinline__ unsigned short f2b(float f){
  __hip_bfloat16 h = __float2bfloat16(f);
  return *reinterpret_cast<unsigned short*>(&h);
}
__device__ __forceinline__ float b2f(unsigned short u){
  __hip_bfloat16 h;
  *reinterpret_cast<unsigned short*>(&h) = u;
  return __bfloat162float(h);
}

// ---------------- decoder MFMA fragment tables ----------------
__global__ void k_tw2(const float* __restrict__ w2ih0, const float* __restrict__ w2hh0,
                      const float* __restrict__ w2ih1, const float* __restrict__ w2hh1,
                      const float* __restrict__ b2ih0, const float* __restrict__ b2hh0,
                      const float* __restrict__ b2ih1, const float* __restrict__ b2hh1,
                      unsigned short* __restrict__ wb2, float* __restrict__ tb)
{
  int idx = blockIdx.x*256 + threadIdx.x;
  if (idx < 48*512){
    int f = idx >> 9, rem = idx & 511;
    int l = rem >> 3, j = rem & 7;
    int lr = l & 15, lq = l >> 4;
    float v = 0.f;
    if (f < 8){
      int ct = f, k = 8*lq + j, col = ct*16 + lr;
      int g = col>>5, u = col&31;
      if (k < HH && u < HH) v = w2hh0[(size_t)(g*HH+u)*HH + k];
    } else if (f < 24){
      int ct = (f-8)>>1, ks = (f-8)&1, k = 8*lq + j, col = ct*16 + lr;
      int g = col>>5, u = col&31;
      if (k < HH && u < HH) v = ks ? w2hh1[(size_t)(g*HH+u)*HH + k] : w2ih1[(size_t)(g*HH+u)*HH + k];
    } else {
      int ct = (f-24)/3, ks = (f-24)%3, k = ks*32 + 8*lq + j, col = ct*16 + lr;
      int g = col>>5, u = col&31;
      if (k < CTXD && u < HH) v = w2ih0[(size_t)(g*HH+u)*IN2 + k];
    }
    wb2[idx] = f2b(v);
  } else if (idx < 48*512 + 512){
    int t = idx - 48*512;
    int col = t & 127, sel = t >> 7;
    int g = col>>5, u = col&31;
    float v = 0.f;
    if (u < HH){
      int r = g*HH + u;
      if (sel == 0) v = b2ih0[r] + b2hh0[r];
      else if (sel == 1) v = b2ih1[r] + b2hh1[r];
      else if (sel == 2) v = w2ih0[(size_t)r*IN2 + 80];
      else v = w2ih0[(size_t)r*IN2 + 81];
    }
    tb[sel*128 + col] = v;
  }
}

// ---------------- encoder MFMA fragment tables ----------------
__global__ void k_tw3(const float* __restrict__ wih0, const float* __restrict__ whh0,
                      const float* __restrict__ wih1, const float* __restrict__ whh1,
                      const float* __restrict__ bih0, const float* __restrict__ bhh0,
                      const float* __restrict__ bih1, const float* __restrict__ bhh1,
                      unsigned short* __restrict__ wb3, float* __restrict__ tbe)
{
  int idx = blockIdx.x*256 + threadIdx.x;
  if (idx < 32*512){
    int f = idx >> 9, rem = idx & 511;
    int l = rem >> 3, j = rem & 7;
    int lr = l & 15, lq = l >> 4;
    int k = 8*lq + j;
    float v = 0.f;
    if (f < 8){
      int col = f*16 + lr; int g = col>>5, u = col&31;
      if (k < IND && u < HH) v = wih0[(size_t)(g*HH+u)*IND + k];
    } else if (f < 16){
      int ct = f-8; int col = ct*16 + lr; int g = col>>5, u = col&31;
      if (k < HH && u < HH) v = whh0[(size_t)(g*HH+u)*HH + k];
    } else {
      int ct = (f-16)>>1, ks = (f-16)&1; int col = ct*16 + lr; int g = col>>5, u = col&31;
      if (k < HH && u < HH) v = ks ? whh1[(size_t)(g*HH+u)*HH + k] : wih1[(size_t)(g*HH+u)*HH + k];
    }
    wb3[idx] = f2b(v);
  } else if (idx < 32*512 + 256){
    int t2 = idx - 32*512;
    int col = t2 & 127, sel = t2 >> 7;
    int g = col>>5, u = col&31;
    float v = 0.f;
    if (u < HH){
      int r = g*HH + u;
      v = sel ? (bih1[r] + bhh1[r]) : (bih0[r] + bhh0[r]);
    }
    tbe[sel*128 + col] = v;
  }
}

// ---------------- conv MFMA fragment tables ----------------
// f 0..3 conv1 (K=40: k=kk*8+ic, 2 ks × 2 ct); f 4..15 conv2 (K=96: kk*32+ic, 3 ks × 4 ct);
// f 16..63 conv3 (K=192: kk*64+ic, 6 ks × 8 ct); f 64..95 fc (K=512: p*128+oc, 16 ks × 2 ct)
__global__ void k_tw4(const float* __restrict__ c1w, const float* __restrict__ c2w,
                      const float* __restrict__ c3w, const float* __restrict__ fcw,
                      unsigned short* __restrict__ wc)
{
  int idx = blockIdx.x*256 + threadIdx.x;
  if (idx >= 96*512) return;
  int f = idx >> 9, rem = idx & 511;
  int l = rem >> 3, j = rem & 7;
  int lr = l & 15, lq = l >> 4;
  int k = 8*lq + j;
  float v = 0.f;
  if (f < 4){
    int ks = f>>1, ct = f&1; int kk2 = ks*32 + k;
    if (kk2 < 40){ int kk = kk2>>3, ic = kk2&7; v = c1w[((size_t)(ct*16+lr)*8 + ic)*5 + kk]; }
  } else if (f < 16){
    int fi = f-4; int ks = fi>>2, ct = fi&3;
    v = c2w[((size_t)(ct*16+lr)*32 + k)*3 + ks];
  } else if (f < 64){
    int fi = f-16; int ks = fi>>3, ct = fi&7; int kk2 = ks*32 + k;
    int kk = kk2>>6, ic = kk2&63;
    v = c3w[((size_t)(ct*16+lr)*64 + ic)*3 + kk];
  } else {
    int fi = f-64; int ks = fi>>1, ct = fi&1; int kk2 = ks*32 + k;
    int p = kk2>>7, ocb = kk2&127;
    int n = ct*16 + lr;
    if (n < 20) v = fcw[(size_t)n*512 + ocb*4 + p];
  }
  wc[idx] = f2b(v);
}

// ---------------- zero BN1 accumulators ----------------
__global__ void k_zero(double* a){
  int i = threadIdx.x;
  if (i < CTXD*2) a[i] = 0.0;
}

// ---------------- encoder: MFMA LSTM ----------------
__global__ __launch_bounds__(512, 2) void k_encm(
    const float* __restrict__ x, const float* __restrict__ h0i, const float* __restrict__ c0i,
    const unsigned short* __restrict__ wb3, const float* __restrict__ tbe,
    float* __restrict__ h0f, float* __restrict__ h1f,
    float* __restrict__ c0f, float* __restrict__ c1f)
{
  __shared__ __align__(16) unsigned short XS[TT*64*8];
  __shared__ __align__(16) unsigned short H0[2][64*32];
  __shared__ __align__(16) unsigned short H1[2][64*32];
  const int tid = threadIdx.x;
  const int l = tid & 63, w = tid >> 6;
  const int st = w & 3, ug = w >> 2;
  const int lr = l & 15, lq = l >> 4, l3 = l & 3;
  const int blk = blockIdx.x;

  for (int i = tid; i < 64*100; i += 512){
    int smp = i/100, q = i - smp*100;
    float4 v = ((const float4*)(x + (size_t)(blk*64+smp)*(TT*IND)))[q];
    int td = q*4;
    int t = td >> 3, d = td & 7;
    unsigned short* p = &XS[t*512 + smp*8 + d];
    p[0]=f2b(v.x); p[1]=f2b(v.y); p[2]=f2b(v.z); p[3]=f2b(v.w);
  }
  for (int i = tid; i < 64*32; i += 512){
    H0[0][i]=0; H0[1][i]=0; H1[0][i]=0; H1[1][i]=0;
  }
  __syncthreads();
  for (int i = tid; i < 64*HH; i += 512){
    int r = i/HH, u2 = i - r*HH;
    int off = r*32 + (((u2>>3) ^ (r&3))<<3) + (u2&7);
    H0[0][off] = f2b(h0i[u2]);
    H1[0][off] = f2b(h0i[HH+u2]);
  }

  const int u  = ug*16 + lr;
  const int uc = u < HH ? u : HH-1;
  const int arow = st*16 + lr;
  const int aoff = arow*32 + ((lq ^ l3)<<3);
  int wr[4];
  float c0[4], c1[4];
  #pragma unroll
  for (int i=0;i<4;++i){
    int smp = st*16 + 4*lq + i;
    wr[i] = smp*32 + (((u>>3) ^ i)<<3) + (u&7);
    c0[i] = c0i[uc];
    c1[i] = c0i[HH+uc];
  }
  s8v BX[4], BH[4], B10[4], B11[4];
  float b0v[4], b1v[4];
  #pragma unroll
  for (int g=0; g<4; ++g){
    const int ct = g*2 + ug;
    const int col = ct*16 + lr;
    BX[g]  = *(const s8v*)(wb3 + ((size_t)(ct)*64 + l)*8);
    BH[g]  = *(const s8v*)(wb3 + ((size_t)(8 + ct)*64 + l)*8);
    B10[g] = *(const s8v*)(wb3 + ((size_t)(16 + ct*2 + 0)*64 + l)*8);
    B11[g] = *(const s8v*)(wb3 + ((size_t)(16 + ct*2 + 1)*64 + l)*8);
    b0v[g] = tbe[col]; b1v[g] = tbe[128+col];
  }
  __syncthreads();

  int cur = 0;
  for (int t=0; t<TT; ++t){
    const int nxt = cur ^ 1;
    s8v ax = {0,0,0,0,0,0,0,0};
    if (lq == 0) ax = *(const s8v*)&XS[t*512 + arow*8];
    const s8v ah = *(const s8v*)&H0[cur][aoff];
    f4v ac[4];
    #pragma unroll
    for (int g=0; g<4; ++g){
      f4v a = {b0v[g], b0v[g], b0v[g], b0v[g]};
      a = __builtin_amdgcn_mfma_f32_16x16x32_bf16(ax, BX[g], a, 0, 0, 0);
      ac[g] = __builtin_amdgcn_mfma_f32_16x16x32_bf16(ah, BH[g], a, 0, 0, 0);
    }
    unsigned short hw[4];
    #pragma unroll
    for (int i=0;i<4;++i){
      float iv = sg(ac[0][i]), fv = sg(ac[1][i]), gv = th(ac[2][i]), ov = sg(ac[3][i]);
      c0[i] = fv*c0[i] + iv*gv;
      hw[i] = f2b(ov*th(c0[i]));
    }
    if (u < HH){
      #pragma unroll
      for (int i=0;i<4;++i) H0[nxt][wr[i]] = hw[i];
    }
    __syncthreads();
    const s8v a1 = *(const s8v*)&H0[nxt][aoff];
    const s8v a2 = *(const s8v*)&H1[cur][aoff];
    #pragma unroll
    for (int g=0; g<4; ++g){
      f4v a = {b1v[g], b1v[g], b1v[g], b1v[g]};
      a = __builtin_amdgcn_mfma_f32_16x16x32_bf16(a1, B10[g], a, 0, 0, 0);
      ac[g] = __builtin_amdgcn_mfma_f32_16x16x32_bf16(a2, B11[g], a, 0, 0, 0);
    }
    #pragma unroll
    for (int i=0;i<4;++i){
      float iv = sg(ac[0][i]), fv = sg(ac[1][i]), gv = th(ac[2][i]), ov = sg(ac[3][i]);
      c1[i] = fv*c1[i] + iv*gv;
      hw[i] = f2b(ov*th(c1[i]));
    }
    if (u < HH){
      #pragma unroll
      for (int i=0;i<4;++i) H1[nxt][wr[i]] = hw[i];
    }
    __syncthreads();
    cur = nxt;
  }
  for (int i2 = tid; i2 < 64*HH; i2 += 512){
    int sl = i2 / HH, uu = i2 - sl*HH;
    int off = sl*32 + (((uu>>3) ^ (sl&3))<<3) + (uu&7);
    h0f[((size_t)blk*64 + sl)*HH + uu] = b2f(H0[cur][off]);
    h1f[((size_t)blk*64 + sl)*HH + uu] = b2f(H1[cur][off]);
  }
  if (u < HH){
    #pragma unroll
    for (int i=0;i<4;++i){
      int gS = blk*64 + st*16 + 4*lq + i;
      c0f[(size_t)gS*HH + u] = c0[i];
      c1f[(size_t)gS*HH + u] = c1[i];
    }
  }
}

// ---------------- conv path: MFMA (16 samples per 256-thread block) ----------------
__global__ __launch_bounds__(256, 2) void k_convm(
    const float* __restrict__ x, const unsigned short* __restrict__ wc,
    const float* __restrict__ b1, const float* __restrict__ b2,
    const float* __restrict__ b3, const float* __restrict__ fb,
    float* __restrict__ xcg)
{
  __shared__ __align__(16) unsigned short XT[16*52*8];    // [smp][t(52)][ic(8)]
  __shared__ __align__(16) unsigned short P1[16*26*32];   // [smp][pos(26)][ic(32)] chunk-swizzled by pos&3
  __shared__ __align__(16) unsigned short P2[16*10*64];   // [smp][pos(10)][ic(64)] swz pos&7
  __shared__ __align__(16) unsigned short P3[16*4*128];   // [smp][p(4)][oc(128)] swz smp&7
  const int tid = threadIdx.x, l = tid & 63, w = tid >> 6;
  const int lr = l & 15, lq = l >> 4;
  const int blk = blockIdx.x;
  // zero pads (XT t=50,51; P1 pos=23..25)
  for (int i=tid; i<16*16; i+=256){ int s=i>>4, q=i&15; XT[s*416 + 400 + q] = 0; }
  for (int i=tid; i<16*96; i+=256){ int s=i/96, q=i - (i/96)*96; P1[s*832 + 736 + q] = 0; }
  // stage x -> XT bf16
  for (int i=tid; i<1600; i+=256){
    int s = i/100, q = i - s*100;
    float4 v = ((const float4*)(x + (size_t)(blk*16+s)*400))[q];
    int t = q>>1, d = (q&1)*4;
    unsigned short* p = &XT[s*416 + t*8 + d];
    p[0]=f2b(v.x); p[1]=f2b(v.y); p[2]=f2b(v.z); p[3]=f2b(v.w);
  }
  __syncthreads();
  // ---- conv1: rows=(smp,pos48), K=40, N=32 ----
  {
    s8v B[2][2];
    #pragma unroll
    for (int ks=0;ks<2;++ks)
      #pragma unroll
      for (int ct=0;ct<2;++ct)
        B[ks][ct] = *(const s8v*)(wc + ((size_t)(ks*2+ct)*512) + l*8);
    float bv[2] = { b1[lr], b1[16+lr] };
    for (int t5=w; t5<48; t5+=4){
      int row = t5*16 + lr, s = row/48, pos = row - s*48;
      s8v a0 = *(const s8v*)&XT[s*416 + (pos+lq)*8];
      s8v a1 = {0,0,0,0,0,0,0,0};
      if (lq == 0) a1 = *(const s8v*)&XT[s*416 + (pos+4)*8];
      int rb = t5*16 + 4*lq, s2 = rb/48, pp = rb - s2*48;
      #pragma unroll
      for (int ct=0;ct<2;++ct){
        f4v acc = {bv[ct],bv[ct],bv[ct],bv[ct]};
        acc = __builtin_amdgcn_mfma_f32_16x16x32_bf16(a0, B[0][ct], acc, 0, 0, 0);
        acc = __builtin_amdgcn_mfma_f32_16x16x32_bf16(a1, B[1][ct], acc, 0, 0, 0);
        int oc = ct*16 + lr;
        #pragma unroll
        for (int pr=0;pr<2;++pr){
          int pos2 = (pp>>1) + pr;
          if (pos2 < 23){
            float v = fmaxf(fmaxf(acc[2*pr],0.f), fmaxf(acc[2*pr+1],0.f));
            int ch = (oc>>3) ^ (pos2&3);
            P1[s2*832 + pos2*32 + ch*8 + (oc&7)] = f2b(v);
          }
        }
      }
    }
  }
  __syncthreads();
  // ---- conv2: rows=(smp,pos24), K=96, N=64 ----
  {
    s8v B[3][4];
    #pragma unroll
    for (int ks=0;ks<3;++ks)
      #pragma unroll
      for (int ct=0;ct<4;++ct)
        B[ks][ct] = *(const s8v*)(wc + ((size_t)(4+ks*4+ct)*512) + l*8);
    float bv[4] = { b2[lr], b2[16+lr], b2[32+lr], b2[48+lr] };
    for (int t6=w; t6<24; t6+=4){
      int row = t6*16 + lr, s = row/24, pos = row - s*24;
      s8v a[3];
      #pragma unroll
      for (int ks=0;ks<3;++ks){
        int pr = pos + ks, ch = lq ^ (pr&3);
        a[ks] = *(const s8v*)&P1[s*832 + pr*32 + ch*8];
      }
      int rb = t6*16 + 4*lq, s2 = rb/24, pp = rb - s2*24;
      #pragma unroll
      for (int ct=0;ct<4;++ct){
        f4v acc = {bv[ct],bv[ct],bv[ct],bv[ct]};
        #pragma unroll
        for (int ks=0;ks<3;++ks)
          acc = __builtin_amdgcn_mfma_f32_16x16x32_bf16(a[ks], B[ks][ct], acc, 0, 0, 0);
        int oc = ct*16 + lr;
        #pragma unroll
        for (int pr=0;pr<2;++pr){
          int pos2 = (pp>>1) + pr;
          if (pos2 < 10){
            float v = fmaxf(fmaxf(acc[2*pr],0.f), fmaxf(acc[2*pr+1],0.f));
            int ch = (oc>>3) ^ (pos2&7);
            P2[s2*640 + pos2*64 + ch*8 + (oc&7)] = f2b(v);
          }
        }
      }
    }
  }
  __syncthreads();
  // ---- conv3: rows=(smp,pos8), K=192, N=128 ----
  {
    s8v A[2][6]; int sS[2], ppS[2];
    #pragma unroll
    for (int tt=0;tt<2;++tt){
      int t7 = w*2 + tt;
      int row = t7*16 + lr, s = row>>3, pos = row&7;
      #pragma unroll
      for (int ks=0;ks<6;++ks){
        int pr = pos + (ks>>1);
        int cb = 4*(ks&1) + lq;
        int ch = cb ^ (pr&7);
        A[tt][ks] = *(const s8v*)&P2[s*640 + pr*64 + ch*8];
      }
      int rb = t7*16 + 4*lq;
      sS[tt] = rb>>3; ppS[tt] = rb&7;
    }
    for (int ct=0;ct<8;++ct){
      s8v B[6];
      #pragma unroll
      for (int ks=0;ks<6;++ks)
        B[ks] = *(const s8v*)(wc + ((size_t)(16+ks*8+ct)*512) + l*8);
      int oc = ct*16 + lr;
      float bb = b3[oc];
      #pragma unroll
      for (int tt=0;tt<2;++tt){
        f4v acc = {bb,bb,bb,bb};
        #pragma unroll
        for (int ks=0;ks<6;++ks)
          acc = __builtin_amdgcn_mfma_f32_16x16x32_bf16(A[tt][ks], B[ks], acc, 0, 0, 0);
        #pragma unroll
        for (int pr=0;pr<2;++pr){
          int pos2 = (ppS[tt]>>1) + pr;
          float v = fmaxf(fmaxf(acc[2*pr],0.f), fmaxf(acc[2*pr+1],0.f));
          int flat = pos2*128 + oc;
          int ch = (flat>>3) ^ (sS[tt]&7);
          P3[sS[tt]*512 + ch*8 + (oc&7)] = f2b(v);
        }
      }
    }
  }
  __syncthreads();
  // ---- fc: rows=smp(16), K=512, N=20(pad32) — wave 0 only ----
  if (w == 0){
    f4v acc[2];
    float fb0 = fb[lr];
    float fb1 = (lr < 4) ? fb[16+lr] : 0.f;
    acc[0] = (f4v){fb0,fb0,fb0,fb0};
    acc[1] = (f4v){fb1,fb1,fb1,fb1};
    for (int ks=0;ks<16;++ks){
      int k0 = ks*32 + 8*lq;
      int ch = (k0>>3) ^ (lr&7);
      s8v a = *(const s8v*)&P3[lr*512 + ch*8];
      #pragma unroll
      for (int ct=0;ct<2;++ct){
        s8v Bf = *(const s8v*)(wc + ((size_t)(64+ks*2+ct)*512) + l*8);
        acc[ct] = __builtin_amdgcn_mfma_f32_16x16x32_bf16(a, Bf, acc[ct], 0, 0, 0);
      }
    }
    #pragma unroll
    for (int ct=0;ct<2;++ct){
      int oc = ct*16 + lr;
      if (oc < 20){
        #pragma unroll
        for (int i=0;i<4;++i){
          int smp = 4*lq + i;
          xcg[(size_t)(blk*16+smp)*CVD + oc] = fmaxf(acc[ct][i], 0.f);
        }
      }
    }
  }
}

// ---------------- BN1 stats ----------------
__global__ __launch_bounds__(128) void k_bn1s(const float* __restrict__ h0f, const float* __restrict__ h1f,
    const float* __restrict__ xcg, double* __restrict__ s1)
{
  int f = threadIdx.x;
  if (f >= CTXD) return;
  int r0 = blockIdx.x*128;
  double s=0.0, q=0.0;
  for (int i=0;i<128;++i){
    int r = r0+i;
    float v = (f<HH) ? h0f[(size_t)r*HH+f] : (f<2*HH) ? h1f[(size_t)r*HH + f-HH] : xcg[(size_t)r*CVD + f-2*HH];
    s += (double)v; q += (double)v*(double)v;
  }
  atomicAdd(&s1[f*2],   s);
  atomicAdd(&s1[f*2+1], q);
}

__global__ void k_fin1(const double* __restrict__ s1, float* __restrict__ st1){
  int f = threadIdx.x;
  if (f >= CTXD) return;
  double m = s1[f*2]/(double)NB;
  double var = s1[f*2+1]/(double)NB - m*m;
  if (var < 0.0) var = 0.0;
  st1[f*2]   = (float)m;
  st1[f*2+1] = (float)(1.0/sqrt(var + 1e-5));
}

__global__ __launch_bounds__(256) void k_context(const float* __restrict__ h0f, const float* __restrict__ h1f,
    const float* __restrict__ xcg, const float* __restrict__ st1,
    const float* __restrict__ g1, const float* __restrict__ bb1, float* __restrict__ ctx)
{
  int idx = blockIdx.x*256 + threadIdx.x;
  if (idx >= NB*CTXD) return;
  int rr = idx / CTXD, f = idx - rr*CTXD;
  float v = (f<HH) ? h0f[(size_t)rr*HH+f] : (f<2*HH) ? h1f[(size_t)rr*HH + f-HH] : xcg[(size_t)rr*CVD + f-2*HH];
  ctx[idx] = (v - st1[f*2]) * st1[f*2+1] * g1[f] + bb1[f];
}

// ---------------- decoder pass 1: MFMA LSTM ----------------
template<typename ST>
__global__ __launch_bounds__(512, 2) void k_dec1m(
    const float* __restrict__ x, const float* __restrict__ y,
    const float* __restrict__ ctx,
    const unsigned short* __restrict__ wb2, const float* __restrict__ tb,
    const float* __restrict__ h0fi, const float* __restrict__ h1fi,
    const float* __restrict__ c0fi, const float* __restrict__ c1fi,
    ST* __restrict__ h1n)
{
  __shared__ __align__(16) unsigned short CT[64*96];
  __shared__ __align__(16) unsigned short Hh0[2][64*32];
  __shared__ __align__(16) unsigned short Hh1[2][64*32];
  const int tid = threadIdx.x;
  const int l  = tid & 63, w = tid >> 6;
  const int st = w & 3, ug = w >> 2;
  const int lr = l & 15, lq = l >> 4, l3 = l & 3;
  const int blk = blockIdx.x;

  for (int i = tid; i < 64*32; i += 512){
    Hh0[0][i] = 0; Hh0[1][i] = 0; Hh1[0][i] = 0; Hh1[1][i] = 0;
  }
  for (int i = tid; i < 64*96; i += 512) CT[i] = 0;
  __syncthreads();
  for (int i = tid; i < 64*CTXD; i += 512){
    int r = i / CTXD, kk = i - r*CTXD;
    float v = ctx[((size_t)blk*64 + r)*CTXD + kk];
    CT[r*96 + (((kk>>3) ^ (r&3))<<3) + (kk&7)] = f2b(v);
  }
  for (int i = tid; i < 64*HH; i += 512){
    int r = i / HH, u2 = i - r*HH;
    int off = r*32 + (((u2>>3) ^ (r&3))<<3) + (u2&7);
    Hh0[0][off] = f2b(h0fi[((size_t)blk*64 + r)*HH + u2]);
    Hh1[0][off] = f2b(h1fi[((size_t)blk*64 + r)*HH + u2]);
  }

  const int u  = ug*16 + lr;
  const int uc = u < HH ? u : HH-1;
  const int arow = st*16 + lr;
  const int aoff = arow*32 + ((lq ^ l3)<<3);

  int wr[4]; int gS[4];
  float c0[4], c1[4], tt[4], yv[4];
  #pragma unroll
  for (int i=0;i<4;++i){
    int smp = st*16 + 4*lq + i;
    gS[i] = blk*64 + smp;
    wr[i] = smp*32 + (((u>>3) ^ i)<<3) + (u&7);
    c0[i] = c0fi[(size_t)gS[i]*HH + uc];
    c1[i] = c1fi[(size_t)gS[i]*HH + uc];
    tt[i] = x[(size_t)gS[i]*(TT*IND) + (TT-1)*IND + 7];
    yv[i] = x[(size_t)gS[i]*(TT*IND) + (TT-1)*IND + 0];
  }

  s8v B0[4], B10[4], B11[4], BC0[4], BC1[4], BC2[4];
  float bias0[4], bias1[4], wtt[4], wty[4];
  #pragma unroll
  for (int g=0; g<4; ++g){
    const int ct = g*2 + ug;
    const int col = ct*16 + lr;
    B0[g]  = *(const s8v*)(wb2 + ((size_t)(ct)*64 + l)*8);
    B10[g] = *(const s8v*)(wb2 + ((size_t)(8 + ct*2 + 0)*64 + l)*8);
    B11[g] = *(const s8v*)(wb2 + ((size_t)(8 + ct*2 + 1)*64 + l)*8);
    BC0[g] = *(const s8v*)(wb2 + ((size_t)(24 + ct*3 + 0)*64 + l)*8);
    BC1[g] = *(const s8v*)(wb2 + ((size_t)(24 + ct*3 + 1)*64 + l)*8);
    BC2[g] = *(const s8v*)(wb2 + ((size_t)(24 + ct*3 + 2)*64 + l)*8);
    bias0[g] = tb[col]; bias1[g] = tb[128+col];
    wtt[g] = tb[256+col]; wty[g] = tb[384+col];
  }
  __syncthreads();

  f4v pc[4];
  #pragma unroll
  for (int g=0; g<4; ++g){
    f4v a = {bias0[g], bias0[g], bias0[g], bias0[g]};
    {
      const s8v av = *(const s8v*)&CT[arow*96 + (((0*4+lq) ^ l3)<<3)];
      a = __builtin_amdgcn_mfma_f32_16x16x32_bf16(av, BC0[g], a, 0, 0, 0);
    }
    {
      const s8v av = *(const s8v*)&CT[arow*96 + (((1*4+lq) ^ l3)<<3)];
      a = __builtin_amdgcn_mfma_f32_16x16x32_bf16(av, BC1[g], a, 0, 0, 0);
    }
    {
      const s8v av = *(const s8v*)&CT[arow*96 + (((2*4+lq) ^ l3)<<3)];
      a = __builtin_amdgcn_mfma_f32_16x16x32_bf16(av, BC2[g], a, 0, 0, 0);
    }
    pc[g] = a;
  }

  int cur = 0;
  for (int s = 0; s < NOUT; ++s){
    const int nxt = cur ^ 1;
    #pragma unroll
    for (int i=0;i<4;++i) tt[i] = fmodf(tt[i] + 15.f, 1440.f);
    const s8v a0 = *(const s8v*)&Hh0[cur][aoff];
    f4v ac[4];
    #pragma unroll
    for (int g=0; g<4; ++g){
      f4v a = pc[g];
      #pragma unroll
      for (int i=0;i<4;++i) a[i] += tt[i]*wtt[g] + yv[i]*wty[g];
      ac[g] = __builtin_amdgcn_mfma_f32_16x16x32_bf16(a0, B0[g], a, 0, 0, 0);
    }
    unsigned short hw[4];
    #pragma unroll
    for (int i=0;i<4;++i){
      float iv = sg(ac[0][i]), fv = sg(ac[1][i]), gv = th(ac[2][i]), ov = sg(ac[3][i]);
      c0[i] = fv*c0[i] + iv*gv;
      hw[i] = f2b(ov*th(c0[i]));
    }
    if (u < HH){
      #pragma unroll
      for (int i=0;i<4;++i) Hh0[nxt][wr[i]] = hw[i];
    }
    __syncthreads();
    const s8v a1 = *(const s8v*)&Hh0[nxt][aoff];
    const s8v a2 = *(const s8v*)&Hh1[cur][aoff];
    #pragma unroll
    for (int g=0; g<4; ++g){
      f4v a = {bias1[g], bias1[g], bias1[g], bias1[g]};
      a = __builtin_amdgcn_mfma_f32_16x16x32_bf16(a1, B10[g], a, 0, 0, 0);
      ac[g] = __builtin_amdgcn_mfma_f32_16x16x32_bf16(a2, B11[g], a, 0, 0, 0);
    }
    #pragma unroll
    for (int i=0;i<4;++i){
      float iv = sg(ac[0][i]), fv = sg(ac[1][i]), gv = th(ac[2][i]), ov = sg(ac[3][i]);
      c1[i] = fv*c1[i] + iv*gv;
      hw[i] = f2b(ov*th(c1[i]));
    }
    if (u < HH){
      #pragma unroll
      for (int i=0;i<4;++i) Hh1[nxt][wr[i]] = hw[i];
    }
    __syncthreads();
    for (int i2 = tid; i2 < 64*HH; i2 += 512){
      int uu = i2 >> 6, sl = i2 & 63;
      unsigned short hv = Hh1[nxt][sl*32 + (((uu>>3) ^ (sl&3))<<3) + (uu&7)];
      stv(&h1n[((size_t)s*HH + uu)*NB + (size_t)blk*64 + sl], b2f(hv));
    }
    #pragma unroll
    for (int i=0;i<4;++i) yv[i] = y[(size_t)gS[i]*NOUT + s];
    cur = nxt;
  }
}

// ---------------- BN2 stats ----------------
template<typename ST>
__global__ __launch_bounds__(256) void k_bn2s(
    const ST* __restrict__ h1n, const float* __restrict__ xcg,
    const float* __restrict__ x, const float* __restrict__ y,
    float* __restrict__ m2, float* __restrict__ r2)
{
  __shared__ double sd[256];
  __shared__ double qd[256];
  const int s = blockIdx.x;
  const int f = blockIdx.y;
  double sv = 0.0, sq = 0.0;
  if (f < HH){
    const ST* p = h1n + ((size_t)s*HH + f)*NB;
    for (int i = threadIdx.x*8; i < NB; i += 256*8){
      #pragma unroll
      for (int u=0;u<8;++u){ float v = ldv(p + i + u); sv += v; sq += (double)v*(double)v; }
    }
  } else if (f < HH+CVD){
    const float* p = xcg + (f-HH);
    for (int i = threadIdx.x; i < NB; i += 256){
      float v = p[(size_t)i*CVD]; sv += v; sq += (double)v*(double)v;
    }
  } else if (f == HH+CVD){
    for (int i = threadIdx.x; i < NB; i += 256){
      float t = x[(size_t)i*(TT*IND) + (TT-1)*IND + 7];
      for (int k=0;k<=s;++k) t = fmodf(t + 15.f, 1440.f);
      sv += t; sq += (double)t*(double)t;
    }
  } else {
    for (int i = threadIdx.x; i < NB; i += 256){
      float v = (s==0) ? x[(size_t)i*(TT*IND) + (TT-1)*IND + 0] : y[(size_t)i*NOUT + (s-1)];
      sv += v; sq += (double)v*(double)v;
    }
  }
  sd[threadIdx.x] = sv; qd[threadIdx.x] = sq;
  __syncthreads();
  for (int st2=128; st2>0; st2>>=1){
    if ((int)threadIdx.x < st2){
      sd[threadIdx.x] += sd[threadIdx.x+st2];
      qd[threadIdx.x] += qd[threadIdx.x+st2];
    }
    __syncthreads();
  }
  if (threadIdx.x == 0){
    double m = sd[0]/(double)NB;
    double var = qd[0]/(double)NB - m*m;
    if (var < 0.0) var = 0.0;
    m2[s*F2+f] = (float)m;
    r2[s*F2+f] = (float)(1.0/sqrt(var + 1e-5));
  }
}

// ---------------- decoder pass 2: BN2 + dense readout ----------------
template<typename ST>
__global__ __launch_bounds__(256) void k_readout(
    const float* __restrict__ x, const float* __restrict__ y, const ST* __restrict__ h1n,
    const float* __restrict__ xcg, const float* __restrict__ m2, const float* __restrict__ r2,
    const float* __restrict__ g2, const float* __restrict__ b2,
    const float* __restrict__ Wd, const float* __restrict__ Bd,
    const float* __restrict__ Ud, const float* __restrict__ Cd, float* __restrict__ out)
{
  const int s  = blockIdx.y;
  const int rr = blockIdx.x*256 + threadIdx.x;
  float feat[F2];
  #pragma unroll
  for (int f=0; f<HH; ++f) feat[f] = ldv(&h1n[((size_t)s*HH+f)*NB + rr]);
  #pragma unroll
  for (int f=0; f<CVD; ++f) feat[HH+f] = xcg[(size_t)rr*CVD + f];
  float t0 = x[(size_t)rr*(TT*IND) + (TT-1)*IND + 7];
  for (int i=0;i<=s;++i) t0 = fmodf(t0 + 15.f, 1440.f);
  feat[HH+CVD] = t0;
  feat[HH+CVD+1] = (s==0) ? x[(size_t)rr*(TT*IND) + (TT-1)*IND + 0] : y[(size_t)rr*NOUT + (s-1)];
  #pragma unroll
  for (int f=0; f<F2; ++f)
    feat[f] = (feat[f] - m2[s*F2+f]) * r2[s*F2+f] * g2[f] + b2[f];
  float yvv = Cd[s];
  #pragma unroll 1
  for (int jb=0; jb<HID; jb+=10){
    float a[10];
    #pragma unroll
    for (int jt=0;jt<10;++jt) a[jt] = Bd[(size_t)s*HID + jb + jt];
    #pragma unroll 4
    for (int k=0;k<F2;++k){
      const float v = feat[k];
      #pragma unroll
      for (int jt=0;jt<10;++jt)
        a[jt] += v * Wd[((size_t)s*F2 + k)*HID + jb + jt];
    }
    #pragma unroll
    for (int jt=0;jt<10;++jt)
      yvv += fmaxf(a[jt], 0.f) * Ud[(size_t)s*HID + jb + jt];
  }
  out[(size_t)rr*NOUT + s] = yvv;
}

// ---------------- host ----------------
extern "C" void kernel_launch(void* const* d_in, const int* in_sizes, int n_in,
                              void* d_out, int out_size, void* d_ws, size_t ws_size,
                              hipStream_t stream)
{
  const float* x    = (const float*)d_in[0];
  const float* y    = (const float*)d_in[1];
  const float* h0i  = (const float*)d_in[2];
  const float* c0i  = (const float*)d_in[3];
  const float* wih0 = (const float*)d_in[4];
  const float* whh0 = (const float*)d_in[5];
  const float* bih0 = (const float*)d_in[6];
  const float* bhh0 = (const float*)d_in[7];
  const float* wih1 = (const float*)d_in[8];
  const float* whh1 = (const float*)d_in[9];
  const float* bih1 = (const float*)d_in[10];
  const float* bhh1 = (const float*)d_in[11];
  const float* w2ih0= (const float*)d_in[12];
  const float* w2hh0= (const float*)d_in[13];
  const float* b2ih0= (const float*)d_in[14];
  const float* b2hh0= (const float*)d_in[15];
  const float* w2ih1= (const float*)d_in[16];
  const float* w2hh1= (const float*)d_in[17];
  const float* b2ih1= (const float*)d_in[18];
  const float* b2hh1= (const float*)d_in[19];
  const float* c1w  = (const float*)d_in[20];
  const float* c1b  = (const float*)d_in[21];
  const float* c2w  = (const float*)d_in[22];
  const float* c2b  = (const float*)d_in[23];
  const float* c3w  = (const float*)d_in[24];
  const float* c3b  = (const float*)d_in[25];
  const float* fcw  = (const float*)d_in[26];
  const float* fcb  = (const float*)d_in[27];
  const float* bn1g = (const float*)d_in[28];
  const float* bn1b = (const float*)d_in[29];
  const float* bn2g = (const float*)d_in[30];
  const float* bn2b = (const float*)d_in[31];
  const float* Wd   = (const float*)d_in[32];
  const float* Bd   = (const float*)d_in[33];
  const float* Ud   = (const float*)d_in[34];
  const float* Cd   = (const float*)d_in[35];
  float* out = (float*)d_out;

  char* base = (char*)d_ws;
  size_t off = 0;
  auto take = [&](size_t bytes)->char*{
    char* p = base + off;
    off = (off + bytes + 255) & ~(size_t)255;
    return p;
  };
  float*  h0f = (float*) take((size_t)NB*HH*sizeof(float));
  float*  h1f = (float*) take((size_t)NB*HH*sizeof(float));
  float*  c0f = (float*) take((size_t)NB*HH*sizeof(float));
  float*  c1f = (float*) take((size_t)NB*HH*sizeof(float));
  float*  xcg = (float*) take((size_t)NB*CVD*sizeof(float));
  float*  ctx = (float*) take((size_t)NB*CTXD*sizeof(float));
  double* s1  = (double*)take((size_t)CTXD*2*sizeof(double));
  float*  st1 = (float*) take((size_t)CTXD*2*sizeof(float));
  float*  m2  = (float*) take((size_t)NOUT*F2*sizeof(float));
  float*  r2  = (float*) take((size_t)NOUT*F2*sizeof(float));
  unsigned short* wb2 = (unsigned short*) take((size_t)48*512*sizeof(unsigned short));
  float*  tb  = (float*) take((size_t)4*128*sizeof(float));
  unsigned short* wb3 = (unsigned short*) take((size_t)32*512*sizeof(unsigned short));
  float*  tbe = (float*) take((size_t)2*128*sizeof(float));
  unsigned short* wc  = (unsigned short*) take((size_t)96*512*sizeof(unsigned short));
  size_t fixed = off;
  size_t rem = (ws_size > fixed) ? (ws_size - fixed) : 0;
  bool f32st = rem >= (size_t)NOUT*HH*NB*sizeof(float);
  void* h1n = (void*)(base + off);

  k_tw2<<<dim3((48*512+512+255)/256), dim3(256), 0, stream>>>(w2ih0, w2hh0, w2ih1, w2hh1,
      b2ih0, b2hh0, b2ih1, b2hh1, wb2, tb);
  k_tw3<<<dim3((32*512+256+255)/256), dim3(256), 0, stream>>>(wih0, whh0, wih1, whh1,
      bih0, bhh0, bih1, bhh1, wb3, tbe);
  k_tw4<<<dim3((96*512+255)/256), dim3(256), 0, stream>>>(c1w, c2w, c3w, fcw, wc);
  k_zero<<<dim3(1), dim3(256), 0, stream>>>(s1);
  k_encm<<<dim3(NB/64), dim3(512), 0, stream>>>(x, h0i, c0i, wb3, tbe, h0f, h1f, c0f, c1f);
  k_convm<<<dim3(NB/16), dim3(256), 0, stream>>>(x, wc, c1b, c2b, c3b, fcb, xcg);
  k_bn1s<<<dim3(NB/128), dim3(128), 0, stream>>>(h0f, h1f, xcg, s1);
  k_fin1<<<dim3(1), dim3(128), 0, stream>>>(s1, st1);
  k_context<<<dim3((NB*CTXD + 255)/256), dim3(256), 0, stream>>>(h0f, h1f, xcg, st1, bn1g, bn1b, ctx);
  if (f32st){
    k_dec1m<float><<<dim3(NB/64), dim3(512), 0, stream>>>(x, y, ctx, wb2, tb,
        h0f, h1f, c0f, c1f, (float*)h1n);
    k_bn2s<float><<<dim3(NOUT, F2), dim3(256), 0, stream>>>((const float*)h1n, xcg, x, y, m2, r2);
    k_readout<float><<<dim3(NB/256, NOUT), dim3(256), 0, stream>>>(x, y, (const float*)h1n,
        xcg, m2, r2, bn2g, bn2b, Wd, Bd, Ud, Cd, out);
  } else {
    k_dec1m<__hip_bfloat16><<<dim3(NB/64), dim3(512), 0, stream>>>(x, y, ctx, wb2, tb,
        h0f, h1f, c0f, c1f, (__hip_bfloat16*)h1n);
    k_bn2s<__hip_bfloat16><<<dim3(NOUT, F2), dim3(256), 0, stream>>>((const __hip_bfloat16*)h1n, xcg, x, y, m2, r2);
    k_readout<__hip_bfloat16><<<dim3(NB/256, NOUT), dim3(256), 0, stream>>>(x, y, (const __hip_bfloat16*)h1n,
        xcg, m2, r2, bn2g, bn2b, Wd, Bd, Ud, Cd, out);
  }
}

// Round 9
// 771.219 us; speedup vs baseline: 32.0499x; 1.2551x over previous
//
#include <hip/hip_runtime.h>
#include <hip/hip_bf16.h>

#define NB   16384
#define TT   50
#define HH   30
#define IND  8
#define CTXD 80
#define IN2  82
#define F2   52
#define NOUT 50
#define HID  100
#define CVD  20

typedef __attribute__((ext_vector_type(8))) short s8v;
typedef __attribute__((ext_vector_type(4))) float f4v;

__device__ __forceinline__ float sg(float x){
  x = fminf(fmaxf(x, -30.f), 30.f);
  return 1.f/(1.f+__expf(-x));
}
__device__ __forceinline__ float th(float x){
  x = fminf(fmaxf(x, -15.f), 15.f);
  float e = __expf(2.f*x);
  return (e-1.f)/(e+1.f);
}
__device__ __forceinline__ unsigned short f2b(float f){
  __hip_bfloat16 h = __float2bfloat16(f);
  return *reinterpret_cast<unsigned short*>(&h);
}
__device__ __forceinline__ float b2f(unsigned short u){
  __hip_bfloat16 h;
  *reinterpret_cast<unsigned short*>(&h) = u;
  return __bfloat162float(h);
}

// ---------------- decoder MFMA fragment tables ----------------
__global__ void k_tw2(const float* __restrict__ w2ih0, const float* __restrict__ w2hh0,
                      const float* __restrict__ w2ih1, const float* __restrict__ w2hh1,
                      const float* __restrict__ b2ih0, const float* __restrict__ b2hh0,
                      const float* __restrict__ b2ih1, const float* __restrict__ b2hh1,
                      unsigned short* __restrict__ wb2, float* __restrict__ tb)
{
  int idx = blockIdx.x*256 + threadIdx.x;
  if (idx < 48*512){
    int f = idx >> 9, rem = idx & 511;
    int l = rem >> 3, j = rem & 7;
    int lr = l & 15, lq = l >> 4;
    float v = 0.f;
    if (f < 8){
      int ct = f, k = 8*lq + j, col = ct*16 + lr;
      int g = col>>5, u = col&31;
      if (k < HH && u < HH) v = w2hh0[(size_t)(g*HH+u)*HH + k];
    } else if (f < 24){
      int ct = (f-8)>>1, ks = (f-8)&1, k = 8*lq + j, col = ct*16 + lr;
      int g = col>>5, u = col&31;
      if (k < HH && u < HH) v = ks ? w2hh1[(size_t)(g*HH+u)*HH + k] : w2ih1[(size_t)(g*HH+u)*HH + k];
    } else {
      int ct = (f-24)/3, ks = (f-24)%3, k = ks*32 + 8*lq + j, col = ct*16 + lr;
      int g = col>>5, u = col&31;
      if (k < CTXD && u < HH) v = w2ih0[(size_t)(g*HH+u)*IN2 + k];
    }
    wb2[idx] = f2b(v);
  } else if (idx < 48*512 + 512){
    int t = idx - 48*512;
    int col = t & 127, sel = t >> 7;
    int g = col>>5, u = col&31;
    float v = 0.f;
    if (u < HH){
      int r = g*HH + u;
      if (sel == 0) v = b2ih0[r] + b2hh0[r];
      else if (sel == 1) v = b2ih1[r] + b2hh1[r];
      else if (sel == 2) v = w2ih0[(size_t)r*IN2 + 80];
      else v = w2ih0[(size_t)r*IN2 + 81];
    }
    tb[sel*128 + col] = v;
  }
}

// ---------------- encoder MFMA fragment tables ----------------
__global__ void k_tw3(const float* __restrict__ wih0, const float* __restrict__ whh0,
                      const float* __restrict__ wih1, const float* __restrict__ whh1,
                      const float* __restrict__ bih0, const float* __restrict__ bhh0,
                      const float* __restrict__ bih1, const float* __restrict__ bhh1,
                      unsigned short* __restrict__ wb3, float* __restrict__ tbe)
{
  int idx = blockIdx.x*256 + threadIdx.x;
  if (idx < 32*512){
    int f = idx >> 9, rem = idx & 511;
    int l = rem >> 3, j = rem & 7;
    int lr = l & 15, lq = l >> 4;
    int k = 8*lq + j;
    float v = 0.f;
    if (f < 8){
      int col = f*16 + lr; int g = col>>5, u = col&31;
      if (k < IND && u < HH) v = wih0[(size_t)(g*HH+u)*IND + k];
    } else if (f < 16){
      int ct = f-8; int col = ct*16 + lr; int g = col>>5, u = col&31;
      if (k < HH && u < HH) v = whh0[(size_t)(g*HH+u)*HH + k];
    } else {
      int ct = (f-16)>>1, ks = (f-16)&1; int col = ct*16 + lr; int g = col>>5, u = col&31;
      if (k < HH && u < HH) v = ks ? whh1[(size_t)(g*HH+u)*HH + k] : wih1[(size_t)(g*HH+u)*HH + k];
    }
    wb3[idx] = f2b(v);
  } else if (idx < 32*512 + 256){
    int t2 = idx - 32*512;
    int col = t2 & 127, sel = t2 >> 7;
    int g = col>>5, u = col&31;
    float v = 0.f;
    if (u < HH){
      int r = g*HH + u;
      v = sel ? (bih1[r] + bhh1[r]) : (bih0[r] + bhh0[r]);
    }
    tbe[sel*128 + col] = v;
  }
}

// ---------------- conv MFMA fragment tables ----------------
__global__ void k_tw4(const float* __restrict__ c1w, const float* __restrict__ c2w,
                      const float* __restrict__ c3w, const float* __restrict__ fcw,
                      unsigned short* __restrict__ wc)
{
  int idx = blockIdx.x*256 + threadIdx.x;
  if (idx >= 96*512) return;
  int f = idx >> 9, rem = idx & 511;
  int l = rem >> 3, j = rem & 7;
  int lr = l & 15, lq = l >> 4;
  int k = 8*lq + j;
  float v = 0.f;
  if (f < 4){
    int ks = f>>1, ct = f&1; int kk2 = ks*32 + k;
    if (kk2 < 40){ int kk = kk2>>3, ic = kk2&7; v = c1w[((size_t)(ct*16+lr)*8 + ic)*5 + kk]; }
  } else if (f < 16){
    int fi = f-4; int ks = fi>>2, ct = fi&3;
    v = c2w[((size_t)(ct*16+lr)*32 + k)*3 + ks];
  } else if (f < 64){
    int fi = f-16; int ks = fi>>3, ct = fi&7; int kk2 = ks*32 + k;
    int kk = kk2>>6, ic = kk2&63;
    v = c3w[((size_t)(ct*16+lr)*64 + ic)*3 + kk];
  } else {
    int fi = f-64; int ks = fi>>1, ct = fi&1; int kk2 = ks*32 + k;
    int p = kk2>>7, ocb = kk2&127;
    int n = ct*16 + lr;
    if (n < 20) v = fcw[(size_t)n*512 + ocb*4 + p];
  }
  wc[idx] = f2b(v);
}

// ---------------- readout Wd fragment table ----------------
// wd5[(s*14 + ks*7 + ct)*512 + l*8 + j] = Wd[s][k=ks*32+8*lq+j][col=ct*16+lr]
__global__ void k_tw5(const float* __restrict__ Wd, unsigned short* __restrict__ wd5){
  int idx = blockIdx.x*256 + threadIdx.x;
  if (idx >= NOUT*14*512) return;
  int s = idx / (14*512), rem = idx - s*(14*512);
  int fi = rem >> 9, r2i = rem & 511;
  int l = r2i >> 3, j = r2i & 7;
  int lr = l & 15, lq = l >> 4;
  int ks = fi / 7, ct = fi - ks*7;
  int k = ks*32 + 8*lq + j, col = ct*16 + lr;
  float v = (k < F2 && col < HID) ? Wd[((size_t)s*F2 + k)*HID + col] : 0.f;
  wd5[idx] = f2b(v);
}

// ---------------- pack/transpose helpers ----------------
__global__ void k_pack(const float* __restrict__ x, float* __restrict__ tpack, float* __restrict__ ypack){
  int r = blockIdx.x*256 + threadIdx.x;
  if (r < NB){
    tpack[r] = x[(size_t)r*(TT*IND) + (TT-1)*IND + 7];
    ypack[r] = x[(size_t)r*(TT*IND) + (TT-1)*IND + 0];
  }
}

__global__ __launch_bounds__(256) void k_ty(const float* __restrict__ y, float* __restrict__ yT){
  __shared__ float tile[NOUT*65];
  int rr0 = blockIdx.x*64;
  for (int i=threadIdx.x; i<64*NOUT; i+=256){
    int r = i/NOUT, s = i - r*NOUT;
    tile[s*65 + r] = y[(size_t)(rr0+r)*NOUT + s];
  }
  __syncthreads();
  for (int i=threadIdx.x; i<64*NOUT; i+=256){
    int s = i>>6, r = i&63;
    yT[(size_t)s*NB + rr0 + r] = tile[s*65 + r];
  }
}

__global__ __launch_bounds__(256) void k_tro(const float* __restrict__ outT, float* __restrict__ out){
  __shared__ float tile[NOUT*65];
  int rr0 = blockIdx.x*64;
  for (int i=threadIdx.x; i<64*NOUT; i+=256){
    int s = i>>6, r = i&63;
    tile[s*65 + r] = outT[(size_t)s*NB + rr0 + r];
  }
  __syncthreads();
  for (int i=threadIdx.x; i<64*NOUT; i+=256){
    int r = i/NOUT, s = i - r*NOUT;
    out[(size_t)(rr0+r)*NOUT + s] = tile[s*65 + r];
  }
}

// ---------------- zero BN1 accumulators ----------------
__global__ void k_zero(double* a){
  int i = threadIdx.x;
  if (i < CTXD*2) a[i] = 0.0;
}

// ---------------- encoder: MFMA LSTM ----------------
__global__ __launch_bounds__(512, 2) void k_encm(
    const float* __restrict__ x, const float* __restrict__ h0i, const float* __restrict__ c0i,
    const unsigned short* __restrict__ wb3, const float* __restrict__ tbe,
    float* __restrict__ h0f, float* __restrict__ h1f,
    float* __restrict__ c0f, float* __restrict__ c1f)
{
  __shared__ __align__(16) unsigned short XS[TT*64*8];
  __shared__ __align__(16) unsigned short H0[2][64*32];
  __shared__ __align__(16) unsigned short H1[2][64*32];
  const int tid = threadIdx.x;
  const int l = tid & 63, w = tid >> 6;
  const int st = w & 3, ug = w >> 2;
  const int lr = l & 15, lq = l >> 4, l3 = l & 3;
  const int blk = blockIdx.x;

  for (int i = tid; i < 64*100; i += 512){
    int smp = i/100, q = i - smp*100;
    float4 v = ((const float4*)(x + (size_t)(blk*64+smp)*(TT*IND)))[q];
    int td = q*4;
    int t = td >> 3, d = td & 7;
    unsigned short* p = &XS[t*512 + smp*8 + d];
    p[0]=f2b(v.x); p[1]=f2b(v.y); p[2]=f2b(v.z); p[3]=f2b(v.w);
  }
  for (int i = tid; i < 64*32; i += 512){
    H0[0][i]=0; H0[1][i]=0; H1[0][i]=0; H1[1][i]=0;
  }
  __syncthreads();
  for (int i = tid; i < 64*HH; i += 512){
    int r = i/HH, u2 = i - r*HH;
    int off = r*32 + (((u2>>3) ^ (r&3))<<3) + (u2&7);
    H0[0][off] = f2b(h0i[u2]);
    H1[0][off] = f2b(h0i[HH+u2]);
  }

  const int u  = ug*16 + lr;
  const int uc = u < HH ? u : HH-1;
  const int arow = st*16 + lr;
  const int aoff = arow*32 + ((lq ^ l3)<<3);
  int wr[4];
  float c0[4], c1[4];
  #pragma unroll
  for (int i=0;i<4;++i){
    int smp = st*16 + 4*lq + i;
    wr[i] = smp*32 + (((u>>3) ^ i)<<3) + (u&7);
    c0[i] = c0i[uc];
    c1[i] = c0i[HH+uc];
  }
  s8v BX[4], BH[4], B10[4], B11[4];
  float b0v[4], b1v[4];
  #pragma unroll
  for (int g=0; g<4; ++g){
    const int ct = g*2 + ug;
    const int col = ct*16 + lr;
    BX[g]  = *(const s8v*)(wb3 + ((size_t)(ct)*64 + l)*8);
    BH[g]  = *(const s8v*)(wb3 + ((size_t)(8 + ct)*64 + l)*8);
    B10[g] = *(const s8v*)(wb3 + ((size_t)(16 + ct*2 + 0)*64 + l)*8);
    B11[g] = *(const s8v*)(wb3 + ((size_t)(16 + ct*2 + 1)*64 + l)*8);
    b0v[g] = tbe[col]; b1v[g] = tbe[128+col];
  }
  __syncthreads();

  int cur = 0;
  for (int t=0; t<TT; ++t){
    const int nxt = cur ^ 1;
    s8v ax = {0,0,0,0,0,0,0,0};
    if (lq == 0) ax = *(const s8v*)&XS[t*512 + arow*8];
    const s8v ah = *(const s8v*)&H0[cur][aoff];
    f4v ac[4];
    #pragma unroll
    for (int g=0; g<4; ++g){
      f4v a = {b0v[g], b0v[g], b0v[g], b0v[g]};
      a = __builtin_amdgcn_mfma_f32_16x16x32_bf16(ax, BX[g], a, 0, 0, 0);
      ac[g] = __builtin_amdgcn_mfma_f32_16x16x32_bf16(ah, BH[g], a, 0, 0, 0);
    }
    unsigned short hw[4];
    #pragma unroll
    for (int i=0;i<4;++i){
      float iv = sg(ac[0][i]), fv = sg(ac[1][i]), gv = th(ac[2][i]), ov = sg(ac[3][i]);
      c0[i] = fv*c0[i] + iv*gv;
      hw[i] = f2b(ov*th(c0[i]));
    }
    if (u < HH){
      #pragma unroll
      for (int i=0;i<4;++i) H0[nxt][wr[i]] = hw[i];
    }
    __syncthreads();
    const s8v a1 = *(const s8v*)&H0[nxt][aoff];
    const s8v a2 = *(const s8v*)&H1[cur][aoff];
    #pragma unroll
    for (int g=0; g<4; ++g){
      f4v a = {b1v[g], b1v[g], b1v[g], b1v[g]};
      a = __builtin_amdgcn_mfma_f32_16x16x32_bf16(a1, B10[g], a, 0, 0, 0);
      ac[g] = __builtin_amdgcn_mfma_f32_16x16x32_bf16(a2, B11[g], a, 0, 0, 0);
    }
    #pragma unroll
    for (int i=0;i<4;++i){
      float iv = sg(ac[0][i]), fv = sg(ac[1][i]), gv = th(ac[2][i]), ov = sg(ac[3][i]);
      c1[i] = fv*c1[i] + iv*gv;
      hw[i] = f2b(ov*th(c1[i]));
    }
    if (u < HH){
      #pragma unroll
      for (int i=0;i<4;++i) H1[nxt][wr[i]] = hw[i];
    }
    __syncthreads();
    cur = nxt;
  }
  for (int i2 = tid; i2 < 64*HH; i2 += 512){
    int sl = i2 / HH, uu = i2 - sl*HH;
    int off = sl*32 + (((uu>>3) ^ (sl&3))<<3) + (uu&7);
    h0f[((size_t)blk*64 + sl)*HH + uu] = b2f(H0[cur][off]);
    h1f[((size_t)blk*64 + sl)*HH + uu] = b2f(H1[cur][off]);
  }
  if (u < HH){
    #pragma unroll
    for (int i=0;i<4;++i){
      int gS = blk*64 + st*16 + 4*lq + i;
      c0f[(size_t)gS*HH + u] = c0[i];
      c1f[(size_t)gS*HH + u] = c1[i];
    }
  }
}

// ---------------- conv path: MFMA ----------------
__global__ __launch_bounds__(256, 2) void k_convm(
    const float* __restrict__ x, const unsigned short* __restrict__ wc,
    const float* __restrict__ b1, const float* __restrict__ b2,
    const float* __restrict__ b3, const float* __restrict__ fb,
    float* __restrict__ xcg)
{
  __shared__ __align__(16) unsigned short XT[16*52*8];
  __shared__ __align__(16) unsigned short P1[16*26*32];
  __shared__ __align__(16) unsigned short P2[16*10*64];
  __shared__ __align__(16) unsigned short P3[16*4*128];
  const int tid = threadIdx.x, l = tid & 63, w = tid >> 6;
  const int lr = l & 15, lq = l >> 4;
  const int blk = blockIdx.x;
  for (int i=tid; i<16*16; i+=256){ int s=i>>4, q=i&15; XT[s*416 + 400 + q] = 0; }
  for (int i=tid; i<16*96; i+=256){ int s=i/96, q=i - (i/96)*96; P1[s*832 + 736 + q] = 0; }
  for (int i=tid; i<1600; i+=256){
    int s = i/100, q = i - s*100;
    float4 v = ((const float4*)(x + (size_t)(blk*16+s)*400))[q];
    int t = q>>1, d = (q&1)*4;
    unsigned short* p = &XT[s*416 + t*8 + d];
    p[0]=f2b(v.x); p[1]=f2b(v.y); p[2]=f2b(v.z); p[3]=f2b(v.w);
  }
  __syncthreads();
  {
    s8v B[2][2];
    #pragma unroll
    for (int ks=0;ks<2;++ks)
      #pragma unroll
      for (int ct=0;ct<2;++ct)
        B[ks][ct] = *(const s8v*)(wc + ((size_t)(ks*2+ct)*512) + l*8);
    float bv[2] = { b1[lr], b1[16+lr] };
    for (int t5=w; t5<48; t5+=4){
      int row = t5*16 + lr, s = row/48, pos = row - s*48;
      s8v a0 = *(const s8v*)&XT[s*416 + (pos+lq)*8];
      s8v a1 = {0,0,0,0,0,0,0,0};
      if (lq == 0) a1 = *(const s8v*)&XT[s*416 + (pos+4)*8];
      int rb = t5*16 + 4*lq, s2 = rb/48, pp = rb - s2*48;
      #pragma unroll
      for (int ct=0;ct<2;++ct){
        f4v acc = {bv[ct],bv[ct],bv[ct],bv[ct]};
        acc = __builtin_amdgcn_mfma_f32_16x16x32_bf16(a0, B[0][ct], acc, 0, 0, 0);
        acc = __builtin_amdgcn_mfma_f32_16x16x32_bf16(a1, B[1][ct], acc, 0, 0, 0);
        int oc = ct*16 + lr;
        #pragma unroll
        for (int pr=0;pr<2;++pr){
          int pos2 = (pp>>1) + pr;
          if (pos2 < 23){
            float v = fmaxf(fmaxf(acc[2*pr],0.f), fmaxf(acc[2*pr+1],0.f));
            int ch = (oc>>3) ^ (pos2&3);
            P1[s2*832 + pos2*32 + ch*8 + (oc&7)] = f2b(v);
          }
        }
      }
    }
  }
  __syncthreads();
  {
    s8v B[3][4];
    #pragma unroll
    for (int ks=0;ks<3;++ks)
      #pragma unroll
      for (int ct=0;ct<4;++ct)
        B[ks][ct] = *(const s8v*)(wc + ((size_t)(4+ks*4+ct)*512) + l*8);
    float bv[4] = { b2[lr], b2[16+lr], b2[32+lr], b2[48+lr] };
    for (int t6=w; t6<24; t6+=4){
      int row = t6*16 + lr, s = row/24, pos = row - s*24;
      s8v a[3];
      #pragma unroll
      for (int ks=0;ks<3;++ks){
        int pr = pos + ks, ch = lq ^ (pr&3);
        a[ks] = *(const s8v*)&P1[s*832 + pr*32 + ch*8];
      }
      int rb = t6*16 + 4*lq, s2 = rb/24, pp = rb - s2*24;
      #pragma unroll
      for (int ct=0;ct<4;++ct){
        f4v acc = {bv[ct],bv[ct],bv[ct],bv[ct]};
        #pragma unroll
        for (int ks=0;ks<3;++ks)
          acc = __builtin_amdgcn_mfma_f32_16x16x32_bf16(a[ks], B[ks][ct], acc, 0, 0, 0);
        int oc = ct*16 + lr;
        #pragma unroll
        for (int pr=0;pr<2;++pr){
          int pos2 = (pp>>1) + pr;
          if (pos2 < 10){
            float v = fmaxf(fmaxf(acc[2*pr],0.f), fmaxf(acc[2*pr+1],0.f));
            int ch = (oc>>3) ^ (pos2&7);
            P2[s2*640 + pos2*64 + ch*8 + (oc&7)] = f2b(v);
          }
        }
      }
    }
  }
  __syncthreads();
  {
    s8v A[2][6]; int sS[2], ppS[2];
    #pragma unroll
    for (int tt=0;tt<2;++tt){
      int t7 = w*2 + tt;
      int row = t7*16 + lr, s = row>>3, pos = row&7;
      #pragma unroll
      for (int ks=0;ks<6;++ks){
        int pr = pos + (ks>>1);
        int cb = 4*(ks&1) + lq;
        int ch = cb ^ (pr&7);
        A[tt][ks] = *(const s8v*)&P2[s*640 + pr*64 + ch*8];
      }
      int rb = t7*16 + 4*lq;
      sS[tt] = rb>>3; ppS[tt] = rb&7;
    }
    for (int ct=0;ct<8;++ct){
      s8v B[6];
      #pragma unroll
      for (int ks=0;ks<6;++ks)
        B[ks] = *(const s8v*)(wc + ((size_t)(16+ks*8+ct)*512) + l*8);
      int oc = ct*16 + lr;
      float bb = b3[oc];
      #pragma unroll
      for (int tt=0;tt<2;++tt){
        f4v acc = {bb,bb,bb,bb};
        #pragma unroll
        for (int ks=0;ks<6;++ks)
          acc = __builtin_amdgcn_mfma_f32_16x16x32_bf16(A[tt][ks], B[ks], acc, 0, 0, 0);
        #pragma unroll
        for (int pr=0;pr<2;++pr){
          int pos2 = (ppS[tt]>>1) + pr;
          float v = fmaxf(fmaxf(acc[2*pr],0.f), fmaxf(acc[2*pr+1],0.f));
          int flat = pos2*128 + oc;
          int ch = (flat>>3) ^ (sS[tt]&7);
          P3[sS[tt]*512 + ch*8 + (oc&7)] = f2b(v);
        }
      }
    }
  }
  __syncthreads();
  if (w == 0){
    f4v acc[2];
    float fb0 = fb[lr];
    float fb1 = (lr < 4) ? fb[16+lr] : 0.f;
    acc[0] = (f4v){fb0,fb0,fb0,fb0};
    acc[1] = (f4v){fb1,fb1,fb1,fb1};
    for (int ks=0;ks<16;++ks){
      int k0 = ks*32 + 8*lq;
      int ch = (k0>>3) ^ (lr&7);
      s8v a = *(const s8v*)&P3[lr*512 + ch*8];
      #pragma unroll
      for (int ct=0;ct<2;++ct){
        s8v Bf = *(const s8v*)(wc + ((size_t)(64+ks*2+ct)*512) + l*8);
        acc[ct] = __builtin_amdgcn_mfma_f32_16x16x32_bf16(a, Bf, acc[ct], 0, 0, 0);
      }
    }
    #pragma unroll
    for (int ct=0;ct<2;++ct){
      int oc = ct*16 + lr;
      if (oc < 20){
        #pragma unroll
        for (int i=0;i<4;++i){
          int smp = 4*lq + i;
          xcg[(size_t)(blk*16+smp)*CVD + oc] = fmaxf(acc[ct][i], 0.f);
        }
      }
    }
  }
}

// ---------------- BN1 stats ----------------
__global__ __launch_bounds__(128) void k_bn1s(const float* __restrict__ h0f, const float* __restrict__ h1f,
    const float* __restrict__ xcg, double* __restrict__ s1)
{
  int f = threadIdx.x;
  if (f >= CTXD) return;
  int r0 = blockIdx.x*128;
  double s=0.0, q=0.0;
  for (int i=0;i<128;++i){
    int r = r0+i;
    float v = (f<HH) ? h0f[(size_t)r*HH+f] : (f<2*HH) ? h1f[(size_t)r*HH + f-HH] : xcg[(size_t)r*CVD + f-2*HH];
    s += (double)v; q += (double)v*(double)v;
  }
  atomicAdd(&s1[f*2],   s);
  atomicAdd(&s1[f*2+1], q);
}

__global__ void k_fin1(const double* __restrict__ s1, float* __restrict__ st1){
  int f = threadIdx.x;
  if (f >= CTXD) return;
  double m = s1[f*2]/(double)NB;
  double var = s1[f*2+1]/(double)NB - m*m;
  if (var < 0.0) var = 0.0;
  st1[f*2]   = (float)m;
  st1[f*2+1] = (float)(1.0/sqrt(var + 1e-5));
}

__global__ __launch_bounds__(256) void k_context(const float* __restrict__ h0f, const float* __restrict__ h1f,
    const float* __restrict__ xcg, const float* __restrict__ st1,
    const float* __restrict__ g1, const float* __restrict__ bb1, float* __restrict__ ctx)
{
  int idx = blockIdx.x*256 + threadIdx.x;
  if (idx >= NB*CTXD) return;
  int rr = idx / CTXD, f = idx - rr*CTXD;
  float v = (f<HH) ? h0f[(size_t)rr*HH+f] : (f<2*HH) ? h1f[(size_t)rr*HH + f-HH] : xcg[(size_t)rr*CVD + f-2*HH];
  ctx[idx] = (v - st1[f*2]) * st1[f*2+1] * g1[f] + bb1[f];
}

// ---------------- decoder pass 1: MFMA LSTM (h1n in bf16) ----------------
__global__ __launch_bounds__(512, 2) void k_dec1m(
    const float* __restrict__ tpack, const float* __restrict__ ypack, const float* __restrict__ yT,
    const float* __restrict__ ctx,
    const unsigned short* __restrict__ wb2, const float* __restrict__ tb,
    const float* __restrict__ h0fi, const float* __restrict__ h1fi,
    const float* __restrict__ c0fi, const float* __restrict__ c1fi,
    __hip_bfloat16* __restrict__ h1n)
{
  __shared__ __align__(16) unsigned short CT[64*96];
  __shared__ __align__(16) unsigned short Hh0[2][64*32];
  __shared__ __align__(16) unsigned short Hh1[2][64*32];
  const int tid = threadIdx.x;
  const int l  = tid & 63, w = tid >> 6;
  const int st = w & 3, ug = w >> 2;
  const int lr = l & 15, lq = l >> 4, l3 = l & 3;
  const int blk = blockIdx.x;

  for (int i = tid; i < 64*32; i += 512){
    Hh0[0][i] = 0; Hh0[1][i] = 0; Hh1[0][i] = 0; Hh1[1][i] = 0;
  }
  for (int i = tid; i < 64*96; i += 512) CT[i] = 0;
  __syncthreads();
  for (int i = tid; i < 64*CTXD; i += 512){
    int r = i / CTXD, kk = i - r*CTXD;
    float v = ctx[((size_t)blk*64 + r)*CTXD + kk];
    CT[r*96 + (((kk>>3) ^ (r&3))<<3) + (kk&7)] = f2b(v);
  }
  for (int i = tid; i < 64*HH; i += 512){
    int r = i / HH, u2 = i - r*HH;
    int off = r*32 + (((u2>>3) ^ (r&3))<<3) + (u2&7);
    Hh0[0][off] = f2b(h0fi[((size_t)blk*64 + r)*HH + u2]);
    Hh1[0][off] = f2b(h1fi[((size_t)blk*64 + r)*HH + u2]);
  }

  const int u  = ug*16 + lr;
  const int uc = u < HH ? u : HH-1;
  const int arow = st*16 + lr;
  const int aoff = arow*32 + ((lq ^ l3)<<3);

  int wr[4]; int gS[4];
  float c0[4], c1[4], tt[4], yv[4];
  #pragma unroll
  for (int i=0;i<4;++i){
    int smp = st*16 + 4*lq + i;
    gS[i] = blk*64 + smp;
    wr[i] = smp*32 + (((u>>3) ^ i)<<3) + (u&7);
    c0[i] = c0fi[(size_t)gS[i]*HH + uc];
    c1[i] = c1fi[(size_t)gS[i]*HH + uc];
    tt[i] = tpack[gS[i]];
    yv[i] = ypack[gS[i]];
  }

  s8v B0[4], B10[4], B11[4], BC0[4], BC1[4], BC2[4];
  float bias0[4], bias1[4], wtt[4], wty[4];
  #pragma unroll
  for (int g=0; g<4; ++g){
    const int ct = g*2 + ug;
    const int col = ct*16 + lr;
    B0[g]  = *(const s8v*)(wb2 + ((size_t)(ct)*64 + l)*8);
    B10[g] = *(const s8v*)(wb2 + ((size_t)(8 + ct*2 + 0)*64 + l)*8);
    B11[g] = *(const s8v*)(wb2 + ((size_t)(8 + ct*2 + 1)*64 + l)*8);
    BC0[g] = *(const s8v*)(wb2 + ((size_t)(24 + ct*3 + 0)*64 + l)*8);
    BC1[g] = *(const s8v*)(wb2 + ((size_t)(24 + ct*3 + 1)*64 + l)*8);
    BC2[g] = *(const s8v*)(wb2 + ((size_t)(24 + ct*3 + 2)*64 + l)*8);
    bias0[g] = tb[col]; bias1[g] = tb[128+col];
    wtt[g] = tb[256+col]; wty[g] = tb[384+col];
  }
  __syncthreads();

  f4v pc[4];
  #pragma unroll
  for (int g=0; g<4; ++g){
    f4v a = {bias0[g], bias0[g], bias0[g], bias0[g]};
    {
      const s8v av = *(const s8v*)&CT[arow*96 + (((0*4+lq) ^ l3)<<3)];
      a = __builtin_amdgcn_mfma_f32_16x16x32_bf16(av, BC0[g], a, 0, 0, 0);
    }
    {
      const s8v av = *(const s8v*)&CT[arow*96 + (((1*4+lq) ^ l3)<<3)];
      a = __builtin_amdgcn_mfma_f32_16x16x32_bf16(av, BC1[g], a, 0, 0, 0);
    }
    {
      const s8v av = *(const s8v*)&CT[arow*96 + (((2*4+lq) ^ l3)<<3)];
      a = __builtin_amdgcn_mfma_f32_16x16x32_bf16(av, BC2[g], a, 0, 0, 0);
    }
    pc[g] = a;
  }

  int cur = 0;
  for (int s = 0; s < NOUT; ++s){
    const int nxt = cur ^ 1;
    #pragma unroll
    for (int i=0;i<4;++i) tt[i] = fmodf(tt[i] + 15.f, 1440.f);
    const s8v a0 = *(const s8v*)&Hh0[cur][aoff];
    f4v ac[4];
    #pragma unroll
    for (int g=0; g<4; ++g){
      f4v a = pc[g];
      #pragma unroll
      for (int i=0;i<4;++i) a[i] += tt[i]*wtt[g] + yv[i]*wty[g];
      ac[g] = __builtin_amdgcn_mfma_f32_16x16x32_bf16(a0, B0[g], a, 0, 0, 0);
    }
    unsigned short hw[4];
    #pragma unroll
    for (int i=0;i<4;++i){
      float iv = sg(ac[0][i]), fv = sg(ac[1][i]), gv = th(ac[2][i]), ov = sg(ac[3][i]);
      c0[i] = fv*c0[i] + iv*gv;
      hw[i] = f2b(ov*th(c0[i]));
    }
    if (u < HH){
      #pragma unroll
      for (int i=0;i<4;++i) Hh0[nxt][wr[i]] = hw[i];
    }
    __syncthreads();
    const s8v a1 = *(const s8v*)&Hh0[nxt][aoff];
    const s8v a2 = *(const s8v*)&Hh1[cur][aoff];
    #pragma unroll
    for (int g=0; g<4; ++g){
      f4v a = {bias1[g], bias1[g], bias1[g], bias1[g]};
      a = __builtin_amdgcn_mfma_f32_16x16x32_bf16(a1, B10[g], a, 0, 0, 0);
      ac[g] = __builtin_amdgcn_mfma_f32_16x16x32_bf16(a2, B11[g], a, 0, 0, 0);
    }
    #pragma unroll
    for (int i=0;i<4;++i){
      float iv = sg(ac[0][i]), fv = sg(ac[1][i]), gv = th(ac[2][i]), ov = sg(ac[3][i]);
      c1[i] = fv*c1[i] + iv*gv;
      hw[i] = f2b(ov*th(c1[i]));
    }
    if (u < HH){
      #pragma unroll
      for (int i=0;i<4;++i) Hh1[nxt][wr[i]] = hw[i];
    }
    __syncthreads();
    for (int i2 = tid; i2 < 64*HH; i2 += 512){
      int uu = i2 >> 6, sl = i2 & 63;
      unsigned short hv = Hh1[nxt][sl*32 + (((uu>>3) ^ (sl&3))<<3) + (uu&7)];
      *reinterpret_cast<unsigned short*>(&h1n[((size_t)s*HH + uu)*NB + (size_t)blk*64 + sl]) = hv;
    }
    #pragma unroll
    for (int i=0;i<4;++i) yv[i] = yT[(size_t)s*NB + gS[i]];
    cur = nxt;
  }
}

// ---------------- BN2 stats ----------------
__global__ __launch_bounds__(256) void k_bn2s(
    const __hip_bfloat16* __restrict__ h1n, const float* __restrict__ xcg,
    const float* __restrict__ tpack, const float* __restrict__ ypack, const float* __restrict__ yT,
    float* __restrict__ m2, float* __restrict__ r2)
{
  __shared__ double sd[256];
  __shared__ double qd[256];
  const int s = blockIdx.x;
  const int f = blockIdx.y;
  double sv = 0.0, sq = 0.0;
  if (f < HH){
    const __hip_bfloat16* p = h1n + ((size_t)s*HH + f)*NB;
    for (int i = threadIdx.x*8; i < NB; i += 256*8){
      #pragma unroll
      for (int u=0;u<8;++u){ float v = __bfloat162float(p[i+u]); sv += v; sq += (double)v*(double)v; }
    }
  } else if (f < HH+CVD){
    const float* p = xcg + (f-HH);
    for (int i = threadIdx.x; i < NB; i += 256){
      float v = p[(size_t)i*CVD]; sv += v; sq += (double)v*(double)v;
    }
  } else if (f == HH+CVD){
    for (int i = threadIdx.x; i < NB; i += 256){
      float t = tpack[i];
      for (int k=0;k<=s;++k) t = fmodf(t + 15.f, 1440.f);
      sv += t; sq += (double)t*(double)t;
    }
  } else {
    for (int i = threadIdx.x; i < NB; i += 256){
      float v = (s==0) ? ypack[i] : yT[(size_t)(s-1)*NB + i];
      sv += v; sq += (double)v*(double)v;
    }
  }
  sd[threadIdx.x] = sv; qd[threadIdx.x] = sq;
  __syncthreads();
  for (int st2=128; st2>0; st2>>=1){
    if ((int)threadIdx.x < st2){
      sd[threadIdx.x] += sd[threadIdx.x+st2];
      qd[threadIdx.x] += qd[threadIdx.x+st2];
    }
    __syncthreads();
  }
  if (threadIdx.x == 0){
    double m = sd[0]/(double)NB;
    double var = qd[0]/(double)NB - m*m;
    if (var < 0.0) var = 0.0;
    m2[s*F2+f] = (float)m;
    r2[s*F2+f] = (float)(1.0/sqrt(var + 1e-5));
  }
}

// ---------------- readout: MFMA GEMM with split-A bf16 ----------------
__global__ __launch_bounds__(256, 4) void k_rdm(
    const __hip_bfloat16* __restrict__ h1n, const float* __restrict__ xcg,
    const float* __restrict__ tpack, const float* __restrict__ ypack, const float* __restrict__ yT,
    const float* __restrict__ m2, const float* __restrict__ r2,
    const float* __restrict__ g2, const float* __restrict__ b2v,
    const unsigned short* __restrict__ wd5, const float* __restrict__ Bd,
    const float* __restrict__ Ud, const float* __restrict__ Cd,
    float* __restrict__ outT)
{
  __shared__ __align__(16) unsigned short FH[64*64];
  __shared__ __align__(16) unsigned short FL[64*64];
  __shared__ float scl[F2], sft[F2];
  const int tid = threadIdx.x, l = tid & 63, w = tid >> 6;
  const int lr = l & 15, lq = l >> 4;
  const int s = blockIdx.y, rr0 = blockIdx.x*64;
  if (tid < F2){
    float m = m2[s*F2+tid], rv = r2[s*F2+tid];
    float sc = rv * g2[tid];
    scl[tid] = sc;
    sft[tid] = b2v[tid] - m*sc;
  }
  __syncthreads();
  for (int i = tid; i < 64*64; i += 256){
    int f = i >> 6, r = i & 63;
    float v;
    if (f < HH) v = __bfloat162float(h1n[((size_t)s*HH + f)*NB + rr0 + r]);
    else if (f < HH+CVD) v = xcg[(size_t)(rr0+r)*CVD + (f-HH)];
    else if (f == 50){
      float t0 = tpack[rr0+r];
      for (int k=0;k<=s;++k) t0 = fmodf(t0 + 15.f, 1440.f);
      v = t0;
    }
    else if (f == 51) v = (s==0) ? ypack[rr0+r] : yT[(size_t)(s-1)*NB + rr0 + r];
    else v = 0.f;
    if (f < F2) v = v*scl[f] + sft[f];
    unsigned short hi = f2b(v);
    float lo = v - b2f(hi);
    int off = r*64 + ((((f>>3) ^ (r&7))&7)<<3) + (f&7);
    FH[off] = hi;
    FL[off] = f2b(lo);
  }
  __syncthreads();
  const int row = w*16 + lr;
  s8v ah[2], al[2];
  #pragma unroll
  for (int ks=0;ks<2;++ks){
    int ch = ((ks*4+lq) ^ (row&7)) & 7;
    ah[ks] = *(const s8v*)&FH[row*64 + ch*8];
    al[ks] = *(const s8v*)&FL[row*64 + ch*8];
  }
  f4v ps = {0.f,0.f,0.f,0.f};
  #pragma unroll 7
  for (int ct=0; ct<7; ++ct){
    int col = ct*16 + lr;
    float bd = (col < HID) ? Bd[(size_t)s*HID + col] : 0.f;
    f4v acc = {bd,bd,bd,bd};
    #pragma unroll
    for (int ks=0;ks<2;++ks){
      s8v B = *(const s8v*)(wd5 + ((size_t)(s*14 + ks*7 + ct)*512) + l*8);
      acc = __builtin_amdgcn_mfma_f32_16x16x32_bf16(ah[ks], B, acc, 0, 0, 0);
      acc = __builtin_amdgcn_mfma_f32_16x16x32_bf16(al[ks], B, acc, 0, 0, 0);
    }
    float ud = (col < HID) ? Ud[(size_t)s*HID + col] : 0.f;
    #pragma unroll
    for (int i=0;i<4;++i) ps[i] += fmaxf(acc[i], 0.f) * ud;
  }
  #pragma unroll
  for (int m=1; m<16; m<<=1){
    #pragma unroll
    for (int i=0;i<4;++i) ps[i] += __shfl_xor(ps[i], m, 64);
  }
  if (lr == 0){
    float cd = Cd[s];
    float4 o = { ps[0]+cd, ps[1]+cd, ps[2]+cd, ps[3]+cd };
    *(float4*)&outT[(size_t)s*NB + rr0 + w*16 + lq*4] = o;
  }
}

// ---------------- host ----------------
extern "C" void kernel_launch(void* const* d_in, const int* in_sizes, int n_in,
                              void* d_out, int out_size, void* d_ws, size_t ws_size,
                              hipStream_t stream)
{
  const float* x    = (const float*)d_in[0];
  const float* y    = (const float*)d_in[1];
  const float* h0i  = (const float*)d_in[2];
  const float* c0i  = (const float*)d_in[3];
  const float* wih0 = (const float*)d_in[4];
  const float* whh0 = (const float*)d_in[5];
  const float* bih0 = (const float*)d_in[6];
  const float* bhh0 = (const float*)d_in[7];
  const float* wih1 = (const float*)d_in[8];
  const float* whh1 = (const float*)d_in[9];
  const float* bih1 = (const float*)d_in[10];
  const float* bhh1 = (const float*)d_in[11];
  const float* w2ih0= (const float*)d_in[12];
  const float* w2hh0= (const float*)d_in[13];
  const float* b2ih0= (const float*)d_in[14];
  const float* b2hh0= (const float*)d_in[15];
  const float* w2ih1= (const float*)d_in[16];
  const float* w2hh1= (const float*)d_in[17];
  const float* b2ih1= (const float*)d_in[18];
  const float* b2hh1= (const float*)d_in[19];
  const float* c1w  = (const float*)d_in[20];
  const float* c1b  = (const float*)d_in[21];
  const float* c2w  = (const float*)d_in[22];
  const float* c2b  = (const float*)d_in[23];
  const float* c3w  = (const float*)d_in[24];
  const float* c3b  = (const float*)d_in[25];
  const float* fcw  = (const float*)d_in[26];
  const float* fcb  = (const float*)d_in[27];
  const float* bn1g = (const float*)d_in[28];
  const float* bn1b = (const float*)d_in[29];
  const float* bn2g = (const float*)d_in[30];
  const float* bn2b = (const float*)d_in[31];
  const float* Wd   = (const float*)d_in[32];
  const float* Bd   = (const float*)d_in[33];
  const float* Ud   = (const float*)d_in[34];
  const float* Cd   = (const float*)d_in[35];
  float* out = (float*)d_out;

  char* base = (char*)d_ws;
  size_t off = 0;
  auto take = [&](size_t bytes)->char*{
    char* p = base + off;
    off = (off + bytes + 255) & ~(size_t)255;
    return p;
  };
  float*  h0f = (float*) take((size_t)NB*HH*sizeof(float));
  float*  h1f = (float*) take((size_t)NB*HH*sizeof(float));
  float*  c0f = (float*) take((size_t)NB*HH*sizeof(float));
  float*  c1f = (float*) take((size_t)NB*HH*sizeof(float));
  float*  xcg = (float*) take((size_t)NB*CVD*sizeof(float));
  float*  ctx = (float*) take((size_t)NB*CTXD*sizeof(float));
  double* s1  = (double*)take((size_t)CTXD*2*sizeof(double));
  float*  st1 = (float*) take((size_t)CTXD*2*sizeof(float));
  float*  m2  = (float*) take((size_t)NOUT*F2*sizeof(float));
  float*  r2  = (float*) take((size_t)NOUT*F2*sizeof(float));
  unsigned short* wb2 = (unsigned short*) take((size_t)48*512*sizeof(unsigned short));
  float*  tb  = (float*) take((size_t)4*128*sizeof(float));
  unsigned short* wb3 = (unsigned short*) take((size_t)32*512*sizeof(unsigned short));
  float*  tbe = (float*) take((size_t)2*128*sizeof(float));
  unsigned short* wc  = (unsigned short*) take((size_t)96*512*sizeof(unsigned short));
  unsigned short* wd5 = (unsigned short*) take((size_t)NOUT*14*512*sizeof(unsigned short));
  float*  tpk = (float*) take((size_t)NB*sizeof(float));
  float*  ypk = (float*) take((size_t)NB*sizeof(float));
  float*  yT  = (float*) take((size_t)NOUT*NB*sizeof(float));
  float*  oT  = (float*) take((size_t)NOUT*NB*sizeof(float));
  __hip_bfloat16* h1n = (__hip_bfloat16*) take((size_t)NOUT*HH*NB*sizeof(__hip_bfloat16));
  (void)ws_size;

  k_tw2<<<dim3((48*512+512+255)/256), dim3(256), 0, stream>>>(w2ih0, w2hh0, w2ih1, w2hh1,
      b2ih0, b2hh0, b2ih1, b2hh1, wb2, tb);
  k_tw3<<<dim3((32*512+256+255)/256), dim3(256), 0, stream>>>(wih0, whh0, wih1, whh1,
      bih0, bhh0, bih1, bhh1, wb3, tbe);
  k_tw4<<<dim3((96*512+255)/256), dim3(256), 0, stream>>>(c1w, c2w, c3w, fcw, wc);
  k_tw5<<<dim3((NOUT*14*512+255)/256), dim3(256), 0, stream>>>(Wd, wd5);
  k_pack<<<dim3(NB/256), dim3(256), 0, stream>>>(x, tpk, ypk);
  k_ty<<<dim3(NB/64), dim3(256), 0, stream>>>(y, yT);
  k_zero<<<dim3(1), dim3(256), 0, stream>>>(s1);
  k_encm<<<dim3(NB/64), dim3(512), 0, stream>>>(x, h0i, c0i, wb3, tbe, h0f, h1f, c0f, c1f);
  k_convm<<<dim3(NB/16), dim3(256), 0, stream>>>(x, wc, c1b, c2b, c3b, fcb, xcg);
  k_bn1s<<<dim3(NB/128), dim3(128), 0, stream>>>(h0f, h1f, xcg, s1);
  k_fin1<<<dim3(1), dim3(128), 0, stream>>>(s1, st1);
  k_context<<<dim3((NB*CTXD + 255)/256), dim3(256), 0, stream>>>(h0f, h1f, xcg, st1, bn1g, bn1b, ctx);
  k_dec1m<<<dim3(NB/64), dim3(512), 0, stream>>>(tpk, ypk, yT, ctx, wb2, tb,
      h0f, h1f, c0f, c1f, h1n);
  k_bn2s<<<dim3(NOUT, F2), dim3(256), 0, stream>>>(h1n, xcg, tpk, ypk, yT, m2, r2);
  k_rdm<<<dim3(NB/64, NOUT), dim3(256), 0, stream>>>(h1n, xcg, tpk, ypk, yT,
      m2, r2, bn2g, bn2b, wd5, Bd, Ud, Cd, oT);
  k_tro<<<dim3(NB/64), dim3(256), 0, stream>>>(oT, out);
}

// Round 10
// 586.337 us; speedup vs baseline: 42.1557x; 1.3153x over previous
//
#include <hip/hip_runtime.h>
#include <hip/hip_bf16.h>

#define NB   16384
#define TT   50
#define HH   30
#define IND  8
#define CTXD 80
#define IN2  82
#define F2   52
#define NOUT 50
#define HID  100
#define CVD  20

typedef __attribute__((ext_vector_type(8))) short s8v;
typedef __attribute__((ext_vector_type(4))) float f4v;

__device__ __forceinline__ float sg(float x){
  x = fminf(fmaxf(x, -30.f), 30.f);
  return 1.f/(1.f+__expf(-x));
}
__device__ __forceinline__ float th(float x){
  x = fminf(fmaxf(x, -15.f), 15.f);
  float e = __expf(2.f*x);
  return (e-1.f)/(e+1.f);
}
__device__ __forceinline__ unsigned short f2b(float f){
  __hip_bfloat16 h = __float2bfloat16(f);
  return *reinterpret_cast<unsigned short*>(&h);
}
__device__ __forceinline__ float b2f(unsigned short u){
  __hip_bfloat16 h;
  *reinterpret_cast<unsigned short*>(&h) = u;
  return __bfloat162float(h);
}
__device__ __forceinline__ double shfl_xor_d(double v, int m){
  long long ll = __double_as_longlong(v);
  int lo = (int)(ll & 0xffffffffLL), hi = (int)(ll >> 32);
  lo = __shfl_xor(lo, m, 64); hi = __shfl_xor(hi, m, 64);
  return __longlong_as_double(((long long)hi << 32) | (unsigned int)(unsigned)lo);
}

// ---------------- decoder MFMA fragment tables ----------------
__global__ void k_tw2(const float* __restrict__ w2ih0, const float* __restrict__ w2hh0,
                      const float* __restrict__ w2ih1, const float* __restrict__ w2hh1,
                      const float* __restrict__ b2ih0, const float* __restrict__ b2hh0,
                      const float* __restrict__ b2ih1, const float* __restrict__ b2hh1,
                      unsigned short* __restrict__ wb2, float* __restrict__ tb)
{
  int idx = blockIdx.x*256 + threadIdx.x;
  if (idx < 48*512){
    int f = idx >> 9, rem = idx & 511;
    int l = rem >> 3, j = rem & 7;
    int lr = l & 15, lq = l >> 4;
    float v = 0.f;
    if (f < 8){
      int ct = f, k = 8*lq + j, col = ct*16 + lr;
      int g = col>>5, u = col&31;
      if (k < HH && u < HH) v = w2hh0[(size_t)(g*HH+u)*HH + k];
    } else if (f < 24){
      int ct = (f-8)>>1, ks = (f-8)&1, k = 8*lq + j, col = ct*16 + lr;
      int g = col>>5, u = col&31;
      if (k < HH && u < HH) v = ks ? w2hh1[(size_t)(g*HH+u)*HH + k] : w2ih1[(size_t)(g*HH+u)*HH + k];
    } else {
      int ct = (f-24)/3, ks = (f-24)%3, k = ks*32 + 8*lq + j, col = ct*16 + lr;
      int g = col>>5, u = col&31;
      if (k < CTXD && u < HH) v = w2ih0[(size_t)(g*HH+u)*IN2 + k];
    }
    wb2[idx] = f2b(v);
  } else if (idx < 48*512 + 512){
    int t = idx - 48*512;
    int col = t & 127, sel = t >> 7;
    int g = col>>5, u = col&31;
    float v = 0.f;
    if (u < HH){
      int r = g*HH + u;
      if (sel == 0) v = b2ih0[r] + b2hh0[r];
      else if (sel == 1) v = b2ih1[r] + b2hh1[r];
      else if (sel == 2) v = w2ih0[(size_t)r*IN2 + 80];
      else v = w2ih0[(size_t)r*IN2 + 81];
    }
    tb[sel*128 + col] = v;
  }
}

// ---------------- encoder MFMA fragment tables ----------------
__global__ void k_tw3(const float* __restrict__ wih0, const float* __restrict__ whh0,
                      const float* __restrict__ wih1, const float* __restrict__ whh1,
                      const float* __restrict__ bih0, const float* __restrict__ bhh0,
                      const float* __restrict__ bih1, const float* __restrict__ bhh1,
                      unsigned short* __restrict__ wb3, float* __restrict__ tbe)
{
  int idx = blockIdx.x*256 + threadIdx.x;
  if (idx < 32*512){
    int f = idx >> 9, rem = idx & 511;
    int l = rem >> 3, j = rem & 7;
    int lr = l & 15, lq = l >> 4;
    int k = 8*lq + j;
    float v = 0.f;
    if (f < 8){
      int col = f*16 + lr; int g = col>>5, u = col&31;
      if (k < IND && u < HH) v = wih0[(size_t)(g*HH+u)*IND + k];
    } else if (f < 16){
      int ct = f-8; int col = ct*16 + lr; int g = col>>5, u = col&31;
      if (k < HH && u < HH) v = whh0[(size_t)(g*HH+u)*HH + k];
    } else {
      int ct = (f-16)>>1, ks = (f-16)&1; int col = ct*16 + lr; int g = col>>5, u = col&31;
      if (k < HH && u < HH) v = ks ? whh1[(size_t)(g*HH+u)*HH + k] : wih1[(size_t)(g*HH+u)*HH + k];
    }
    wb3[idx] = f2b(v);
  } else if (idx < 32*512 + 256){
    int t2 = idx - 32*512;
    int col = t2 & 127, sel = t2 >> 7;
    int g = col>>5, u = col&31;
    float v = 0.f;
    if (u < HH){
      int r = g*HH + u;
      v = sel ? (bih1[r] + bhh1[r]) : (bih0[r] + bhh0[r]);
    }
    tbe[sel*128 + col] = v;
  }
}

// ---------------- conv MFMA fragment tables ----------------
__global__ void k_tw4(const float* __restrict__ c1w, const float* __restrict__ c2w,
                      const float* __restrict__ c3w, const float* __restrict__ fcw,
                      unsigned short* __restrict__ wc)
{
  int idx = blockIdx.x*256 + threadIdx.x;
  if (idx >= 96*512) return;
  int f = idx >> 9, rem = idx & 511;
  int l = rem >> 3, j = rem & 7;
  int lr = l & 15, lq = l >> 4;
  int k = 8*lq + j;
  float v = 0.f;
  if (f < 4){
    int ks = f>>1, ct = f&1; int kk2 = ks*32 + k;
    if (kk2 < 40){ int kk = kk2>>3, ic = kk2&7; v = c1w[((size_t)(ct*16+lr)*8 + ic)*5 + kk]; }
  } else if (f < 16){
    int fi = f-4; int ks = fi>>2, ct = fi&3;
    v = c2w[((size_t)(ct*16+lr)*32 + k)*3 + ks];
  } else if (f < 64){
    int fi = f-16; int ks = fi>>3, ct = fi&7; int kk2 = ks*32 + k;
    int kk = kk2>>6, ic = kk2&63;
    v = c3w[((size_t)(ct*16+lr)*64 + ic)*3 + kk];
  } else {
    int fi = f-64; int ks = fi>>1, ct = fi&1; int kk2 = ks*32 + k;
    int p = kk2>>7, ocb = kk2&127;
    int n = ct*16 + lr;
    if (n < 20) v = fcw[(size_t)n*512 + ocb*4 + p];
  }
  wc[idx] = f2b(v);
}

// ---------------- readout Wd fragment table ----------------
__global__ void k_tw5(const float* __restrict__ Wd, unsigned short* __restrict__ wd5){
  int idx = blockIdx.x*256 + threadIdx.x;
  if (idx >= NOUT*14*512) return;
  int s = idx / (14*512), rem = idx - s*(14*512);
  int fi = rem >> 9, r2i = rem & 511;
  int l = r2i >> 3, j = r2i & 7;
  int lr = l & 15, lq = l >> 4;
  int ks = fi / 7, ct = fi - ks*7;
  int k = ks*32 + 8*lq + j, col = ct*16 + lr;
  float v = (k < F2 && col < HID) ? Wd[((size_t)s*F2 + k)*HID + col] : 0.f;
  wd5[idx] = f2b(v);
}

// ---------------- pack/transpose helpers ----------------
__global__ void k_pack(const float* __restrict__ x, float* __restrict__ tpack, float* __restrict__ ypack){
  int r = blockIdx.x*256 + threadIdx.x;
  if (r < NB){
    tpack[r] = x[(size_t)r*(TT*IND) + (TT-1)*IND + 7];
    ypack[r] = x[(size_t)r*(TT*IND) + (TT-1)*IND + 0];
  }
}

__global__ __launch_bounds__(256) void k_ty(const float* __restrict__ y, float* __restrict__ yT){
  __shared__ float tile[NOUT*65];
  int rr0 = blockIdx.x*64;
  for (int i=threadIdx.x; i<64*NOUT; i+=256){
    int r = i/NOUT, s = i - r*NOUT;
    tile[s*65 + r] = y[(size_t)(rr0+r)*NOUT + s];
  }
  __syncthreads();
  for (int i=threadIdx.x; i<64*NOUT; i+=256){
    int s = i>>6, r = i&63;
    yT[(size_t)s*NB + rr0 + r] = tile[s*65 + r];
  }
}

__global__ __launch_bounds__(256) void k_tro(const float* __restrict__ outT, float* __restrict__ out){
  __shared__ float tile[NOUT*65];
  int rr0 = blockIdx.x*64;
  for (int i=threadIdx.x; i<64*NOUT; i+=256){
    int s = i>>6, r = i&63;
    tile[s*65 + r] = outT[(size_t)s*NB + rr0 + r];
  }
  __syncthreads();
  for (int i=threadIdx.x; i<64*NOUT; i+=256){
    int r = i/NOUT, s = i - r*NOUT;
    out[(size_t)(rr0+r)*NOUT + s] = tile[s*65 + r];
  }
}

// ---------------- zero accumulators (s1 + s2) ----------------
__global__ void k_zero(double* s1, double* s2){
  int i = blockIdx.x*256 + threadIdx.x;
  if (i < CTXD*2) s1[i] = 0.0;
  if (i < NOUT*F2*2) s2[i] = 0.0;
}

// ---------------- encoder: MFMA LSTM ----------------
__global__ __launch_bounds__(512, 2) void k_encm(
    const float* __restrict__ x, const float* __restrict__ h0i, const float* __restrict__ c0i,
    const unsigned short* __restrict__ wb3, const float* __restrict__ tbe,
    float* __restrict__ h0f, float* __restrict__ h1f,
    float* __restrict__ c0f, float* __restrict__ c1f)
{
  __shared__ __align__(16) unsigned short XS[TT*64*8];
  __shared__ __align__(16) unsigned short H0[2][64*32];
  __shared__ __align__(16) unsigned short H1[2][64*32];
  const int tid = threadIdx.x;
  const int l = tid & 63, w = tid >> 6;
  const int st = w & 3, ug = w >> 2;
  const int lr = l & 15, lq = l >> 4, l3 = l & 3;
  const int blk = blockIdx.x;

  for (int i = tid; i < 64*100; i += 512){
    int smp = i/100, q = i - smp*100;
    float4 v = ((const float4*)(x + (size_t)(blk*64+smp)*(TT*IND)))[q];
    int td = q*4;
    int t = td >> 3, d = td & 7;
    unsigned short* p = &XS[t*512 + smp*8 + d];
    p[0]=f2b(v.x); p[1]=f2b(v.y); p[2]=f2b(v.z); p[3]=f2b(v.w);
  }
  for (int i = tid; i < 64*32; i += 512){
    H0[0][i]=0; H0[1][i]=0; H1[0][i]=0; H1[1][i]=0;
  }
  __syncthreads();
  for (int i = tid; i < 64*HH; i += 512){
    int r = i/HH, u2 = i - r*HH;
    int off = r*32 + (((u2>>3) ^ (r&3))<<3) + (u2&7);
    H0[0][off] = f2b(h0i[u2]);
    H1[0][off] = f2b(h0i[HH+u2]);
  }

  const int u  = ug*16 + lr;
  const int uc = u < HH ? u : HH-1;
  const int arow = st*16 + lr;
  const int aoff = arow*32 + ((lq ^ l3)<<3);
  int wr[4];
  float c0[4], c1[4];
  #pragma unroll
  for (int i=0;i<4;++i){
    int smp = st*16 + 4*lq + i;
    wr[i] = smp*32 + (((u>>3) ^ i)<<3) + (u&7);
    c0[i] = c0i[uc];
    c1[i] = c0i[HH+uc];
  }
  s8v BX[4], BH[4], B10[4], B11[4];
  float b0v[4], b1v[4];
  #pragma unroll
  for (int g=0; g<4; ++g){
    const int ct = g*2 + ug;
    const int col = ct*16 + lr;
    BX[g]  = *(const s8v*)(wb3 + ((size_t)(ct)*64 + l)*8);
    BH[g]  = *(const s8v*)(wb3 + ((size_t)(8 + ct)*64 + l)*8);
    B10[g] = *(const s8v*)(wb3 + ((size_t)(16 + ct*2 + 0)*64 + l)*8);
    B11[g] = *(const s8v*)(wb3 + ((size_t)(16 + ct*2 + 1)*64 + l)*8);
    b0v[g] = tbe[col]; b1v[g] = tbe[128+col];
  }
  __syncthreads();

  int cur = 0;
  for (int t=0; t<TT; ++t){
    const int nxt = cur ^ 1;
    s8v ax = {0,0,0,0,0,0,0,0};
    if (lq == 0) ax = *(const s8v*)&XS[t*512 + arow*8];
    const s8v ah = *(const s8v*)&H0[cur][aoff];
    f4v ac[4];
    #pragma unroll
    for (int g=0; g<4; ++g){
      f4v a = {b0v[g], b0v[g], b0v[g], b0v[g]};
      a = __builtin_amdgcn_mfma_f32_16x16x32_bf16(ax, BX[g], a, 0, 0, 0);
      ac[g] = __builtin_amdgcn_mfma_f32_16x16x32_bf16(ah, BH[g], a, 0, 0, 0);
    }
    unsigned short hw[4];
    #pragma unroll
    for (int i=0;i<4;++i){
      float iv = sg(ac[0][i]), fv = sg(ac[1][i]), gv = th(ac[2][i]), ov = sg(ac[3][i]);
      c0[i] = fv*c0[i] + iv*gv;
      hw[i] = f2b(ov*th(c0[i]));
    }
    if (u < HH){
      #pragma unroll
      for (int i=0;i<4;++i) H0[nxt][wr[i]] = hw[i];
    }
    __syncthreads();
    const s8v a1 = *(const s8v*)&H0[nxt][aoff];
    const s8v a2 = *(const s8v*)&H1[cur][aoff];
    #pragma unroll
    for (int g=0; g<4; ++g){
      f4v a = {b1v[g], b1v[g], b1v[g], b1v[g]};
      a = __builtin_amdgcn_mfma_f32_16x16x32_bf16(a1, B10[g], a, 0, 0, 0);
      ac[g] = __builtin_amdgcn_mfma_f32_16x16x32_bf16(a2, B11[g], a, 0, 0, 0);
    }
    #pragma unroll
    for (int i=0;i<4;++i){
      float iv = sg(ac[0][i]), fv = sg(ac[1][i]), gv = th(ac[2][i]), ov = sg(ac[3][i]);
      c1[i] = fv*c1[i] + iv*gv;
      hw[i] = f2b(ov*th(c1[i]));
    }
    if (u < HH){
      #pragma unroll
      for (int i=0;i<4;++i) H1[nxt][wr[i]] = hw[i];
    }
    __syncthreads();
    cur = nxt;
  }
  for (int i2 = tid; i2 < 64*HH; i2 += 512){
    int sl = i2 / HH, uu = i2 - sl*HH;
    int off = sl*32 + (((uu>>3) ^ (sl&3))<<3) + (uu&7);
    h0f[((size_t)blk*64 + sl)*HH + uu] = b2f(H0[cur][off]);
    h1f[((size_t)blk*64 + sl)*HH + uu] = b2f(H1[cur][off]);
  }
  if (u < HH){
    #pragma unroll
    for (int i=0;i<4;++i){
      int gS = blk*64 + st*16 + 4*lq + i;
      c0f[(size_t)gS*HH + u] = c0[i];
      c1f[(size_t)gS*HH + u] = c1[i];
    }
  }
}

// ---------------- conv path: MFMA ----------------
__global__ __launch_bounds__(256, 2) void k_convm(
    const float* __restrict__ x, const unsigned short* __restrict__ wc,
    const float* __restrict__ b1, const float* __restrict__ b2,
    const float* __restrict__ b3, const float* __restrict__ fb,
    float* __restrict__ xcg)
{
  __shared__ __align__(16) unsigned short XT[16*52*8];
  __shared__ __align__(16) unsigned short P1[16*26*32];
  __shared__ __align__(16) unsigned short P2[16*10*64];
  __shared__ __align__(16) unsigned short P3[16*4*128];
  const int tid = threadIdx.x, l = tid & 63, w = tid >> 6;
  const int lr = l & 15, lq = l >> 4;
  const int blk = blockIdx.x;
  for (int i=tid; i<16*16; i+=256){ int s=i>>4, q=i&15; XT[s*416 + 400 + q] = 0; }
  for (int i=tid; i<16*96; i+=256){ int s=i/96, q=i - (i/96)*96; P1[s*832 + 736 + q] = 0; }
  for (int i=tid; i<1600; i+=256){
    int s = i/100, q = i - s*100;
    float4 v = ((const float4*)(x + (size_t)(blk*16+s)*400))[q];
    int t = q>>1, d = (q&1)*4;
    unsigned short* p = &XT[s*416 + t*8 + d];
    p[0]=f2b(v.x); p[1]=f2b(v.y); p[2]=f2b(v.z); p[3]=f2b(v.w);
  }
  __syncthreads();
  {
    s8v B[2][2];
    #pragma unroll
    for (int ks=0;ks<2;++ks)
      #pragma unroll
      for (int ct=0;ct<2;++ct)
        B[ks][ct] = *(const s8v*)(wc + ((size_t)(ks*2+ct)*512) + l*8);
    float bv[2] = { b1[lr], b1[16+lr] };
    for (int t5=w; t5<48; t5+=4){
      int row = t5*16 + lr, s = row/48, pos = row - s*48;
      s8v a0 = *(const s8v*)&XT[s*416 + (pos+lq)*8];
      s8v a1 = {0,0,0,0,0,0,0,0};
      if (lq == 0) a1 = *(const s8v*)&XT[s*416 + (pos+4)*8];
      int rb = t5*16 + 4*lq, s2 = rb/48, pp = rb - s2*48;
      #pragma unroll
      for (int ct=0;ct<2;++ct){
        f4v acc = {bv[ct],bv[ct],bv[ct],bv[ct]};
        acc = __builtin_amdgcn_mfma_f32_16x16x32_bf16(a0, B[0][ct], acc, 0, 0, 0);
        acc = __builtin_amdgcn_mfma_f32_16x16x32_bf16(a1, B[1][ct], acc, 0, 0, 0);
        int oc = ct*16 + lr;
        #pragma unroll
        for (int pr=0;pr<2;++pr){
          int pos2 = (pp>>1) + pr;
          if (pos2 < 23){
            float v = fmaxf(fmaxf(acc[2*pr],0.f), fmaxf(acc[2*pr+1],0.f));
            int ch = (oc>>3) ^ (pos2&3);
            P1[s2*832 + pos2*32 + ch*8 + (oc&7)] = f2b(v);
          }
        }
      }
    }
  }
  __syncthreads();
  {
    s8v B[3][4];
    #pragma unroll
    for (int ks=0;ks<3;++ks)
      #pragma unroll
      for (int ct=0;ct<4;++ct)
        B[ks][ct] = *(const s8v*)(wc + ((size_t)(4+ks*4+ct)*512) + l*8);
    float bv[4] = { b2[lr], b2[16+lr], b2[32+lr], b2[48+lr] };
    for (int t6=w; t6<24; t6+=4){
      int row = t6*16 + lr, s = row/24, pos = row - s*24;
      s8v a[3];
      #pragma unroll
      for (int ks=0;ks<3;++ks){
        int pr = pos + ks, ch = lq ^ (pr&3);
        a[ks] = *(const s8v*)&P1[s*832 + pr*32 + ch*8];
      }
      int rb = t6*16 + 4*lq, s2 = rb/24, pp = rb - s2*24;
      #pragma unroll
      for (int ct=0;ct<4;++ct){
        f4v acc = {bv[ct],bv[ct],bv[ct],bv[ct]};
        #pragma unroll
        for (int ks=0;ks<3;++ks)
          acc = __builtin_amdgcn_mfma_f32_16x16x32_bf16(a[ks], B[ks][ct], acc, 0, 0, 0);
        int oc = ct*16 + lr;
        #pragma unroll
        for (int pr=0;pr<2;++pr){
          int pos2 = (pp>>1) + pr;
          if (pos2 < 10){
            float v = fmaxf(fmaxf(acc[2*pr],0.f), fmaxf(acc[2*pr+1],0.f));
            int ch = (oc>>3) ^ (pos2&7);
            P2[s2*640 + pos2*64 + ch*8 + (oc&7)] = f2b(v);
          }
        }
      }
    }
  }
  __syncthreads();
  {
    s8v A[2][6]; int sS[2], ppS[2];
    #pragma unroll
    for (int tt=0;tt<2;++tt){
      int t7 = w*2 + tt;
      int row = t7*16 + lr, s = row>>3, pos = row&7;
      #pragma unroll
      for (int ks=0;ks<6;++ks){
        int pr = pos + (ks>>1);
        int cb = 4*(ks&1) + lq;
        int ch = cb ^ (pr&7);
        A[tt][ks] = *(const s8v*)&P2[s*640 + pr*64 + ch*8];
      }
      int rb = t7*16 + 4*lq;
      sS[tt] = rb>>3; ppS[tt] = rb&7;
    }
    for (int ct=0;ct<8;++ct){
      s8v B[6];
      #pragma unroll
      for (int ks=0;ks<6;++ks)
        B[ks] = *(const s8v*)(wc + ((size_t)(16+ks*8+ct)*512) + l*8);
      int oc = ct*16 + lr;
      float bb = b3[oc];
      #pragma unroll
      for (int tt=0;tt<2;++tt){
        f4v acc = {bb,bb,bb,bb};
        #pragma unroll
        for (int ks=0;ks<6;++ks)
          acc = __builtin_amdgcn_mfma_f32_16x16x32_bf16(A[tt][ks], B[ks], acc, 0, 0, 0);
        #pragma unroll
        for (int pr=0;pr<2;++pr){
          int pos2 = (ppS[tt]>>1) + pr;
          float v = fmaxf(fmaxf(acc[2*pr],0.f), fmaxf(acc[2*pr+1],0.f));
          int flat = pos2*128 + oc;
          int ch = (flat>>3) ^ (sS[tt]&7);
          P3[sS[tt]*512 + ch*8 + (oc&7)] = f2b(v);
        }
      }
    }
  }
  __syncthreads();
  if (w == 0){
    f4v acc[2];
    float fb0 = fb[lr];
    float fb1 = (lr < 4) ? fb[16+lr] : 0.f;
    acc[0] = (f4v){fb0,fb0,fb0,fb0};
    acc[1] = (f4v){fb1,fb1,fb1,fb1};
    for (int ks=0;ks<16;++ks){
      int k0 = ks*32 + 8*lq;
      int ch = (k0>>3) ^ (lr&7);
      s8v a = *(const s8v*)&P3[lr*512 + ch*8];
      #pragma unroll
      for (int ct=0;ct<2;++ct){
        s8v Bf = *(const s8v*)(wc + ((size_t)(64+ks*2+ct)*512) + l*8);
        acc[ct] = __builtin_amdgcn_mfma_f32_16x16x32_bf16(a, Bf, acc[ct], 0, 0, 0);
      }
    }
    #pragma unroll
    for (int ct=0;ct<2;++ct){
      int oc = ct*16 + lr;
      if (oc < 20){
        #pragma unroll
        for (int i=0;i<4;++i){
          int smp = 4*lq + i;
          xcg[(size_t)(blk*16+smp)*CVD + oc] = fmaxf(acc[ct][i], 0.f);
        }
      }
    }
  }
}

// ---------------- BN1 stats ----------------
__global__ __launch_bounds__(128) void k_bn1s(const float* __restrict__ h0f, const float* __restrict__ h1f,
    const float* __restrict__ xcg, double* __restrict__ s1)
{
  int f = threadIdx.x;
  if (f >= CTXD) return;
  int r0 = blockIdx.x*128;
  double s=0.0, q=0.0;
  for (int i=0;i<128;++i){
    int r = r0+i;
    float v = (f<HH) ? h0f[(size_t)r*HH+f] : (f<2*HH) ? h1f[(size_t)r*HH + f-HH] : xcg[(size_t)r*CVD + f-2*HH];
    s += (double)v; q += (double)v*(double)v;
  }
  atomicAdd(&s1[f*2],   s);
  atomicAdd(&s1[f*2+1], q);
}

__global__ void k_fin1(const double* __restrict__ s1, float* __restrict__ st1){
  int f = threadIdx.x;
  if (f >= CTXD) return;
  double m = s1[f*2]/(double)NB;
  double var = s1[f*2+1]/(double)NB - m*m;
  if (var < 0.0) var = 0.0;
  st1[f*2]   = (float)m;
  st1[f*2+1] = (float)(1.0/sqrt(var + 1e-5));
}

__global__ __launch_bounds__(256) void k_context(const float* __restrict__ h0f, const float* __restrict__ h1f,
    const float* __restrict__ xcg, const float* __restrict__ st1,
    const float* __restrict__ g1, const float* __restrict__ bb1, float* __restrict__ ctx)
{
  int idx = blockIdx.x*256 + threadIdx.x;
  if (idx >= NB*CTXD) return;
  int rr = idx / CTXD, f = idx - rr*CTXD;
  float v = (f<HH) ? h0f[(size_t)rr*HH+f] : (f<2*HH) ? h1f[(size_t)rr*HH + f-HH] : xcg[(size_t)rr*CVD + f-2*HH];
  ctx[idx] = (v - st1[f*2]) * st1[f*2+1] * g1[f] + bb1[f];
}

// ---------------- decoder pass 1: MFMA LSTM (h1n in bf16) ----------------
__global__ __launch_bounds__(512, 2) void k_dec1m(
    const float* __restrict__ tpack, const float* __restrict__ ypack, const float* __restrict__ yT,
    const float* __restrict__ ctx,
    const unsigned short* __restrict__ wb2, const float* __restrict__ tb,
    const float* __restrict__ h0fi, const float* __restrict__ h1fi,
    const float* __restrict__ c0fi, const float* __restrict__ c1fi,
    __hip_bfloat16* __restrict__ h1n)
{
  __shared__ __align__(16) unsigned short CT[64*96];
  __shared__ __align__(16) unsigned short Hh0[2][64*32];
  __shared__ __align__(16) unsigned short Hh1[2][64*32];
  const int tid = threadIdx.x;
  const int l  = tid & 63, w = tid >> 6;
  const int st = w & 3, ug = w >> 2;
  const int lr = l & 15, lq = l >> 4, l3 = l & 3;
  const int blk = blockIdx.x;

  for (int i = tid; i < 64*32; i += 512){
    Hh0[0][i] = 0; Hh0[1][i] = 0; Hh1[0][i] = 0; Hh1[1][i] = 0;
  }
  for (int i = tid; i < 64*96; i += 512) CT[i] = 0;
  __syncthreads();
  for (int i = tid; i < 64*CTXD; i += 512){
    int r = i / CTXD, kk = i - r*CTXD;
    float v = ctx[((size_t)blk*64 + r)*CTXD + kk];
    CT[r*96 + (((kk>>3) ^ (r&3))<<3) + (kk&7)] = f2b(v);
  }
  for (int i = tid; i < 64*HH; i += 512){
    int r = i / HH, u2 = i - r*HH;
    int off = r*32 + (((u2>>3) ^ (r&3))<<3) + (u2&7);
    Hh0[0][off] = f2b(h0fi[((size_t)blk*64 + r)*HH + u2]);
    Hh1[0][off] = f2b(h1fi[((size_t)blk*64 + r)*HH + u2]);
  }

  const int u  = ug*16 + lr;
  const int uc = u < HH ? u : HH-1;
  const int arow = st*16 + lr;
  const int aoff = arow*32 + ((lq ^ l3)<<3);

  int wr[4]; int gS[4];
  float c0[4], c1[4], tt[4], yv[4];
  #pragma unroll
  for (int i=0;i<4;++i){
    int smp = st*16 + 4*lq + i;
    gS[i] = blk*64 + smp;
    wr[i] = smp*32 + (((u>>3) ^ i)<<3) + (u&7);
    c0[i] = c0fi[(size_t)gS[i]*HH + uc];
    c1[i] = c1fi[(size_t)gS[i]*HH + uc];
    tt[i] = tpack[gS[i]];
    yv[i] = ypack[gS[i]];
  }

  s8v B0[4], B10[4], B11[4], BC0[4], BC1[4], BC2[4];
  float bias0[4], bias1[4], wtt[4], wty[4];
  #pragma unroll
  for (int g=0; g<4; ++g){
    const int ct = g*2 + ug;
    const int col = ct*16 + lr;
    B0[g]  = *(const s8v*)(wb2 + ((size_t)(ct)*64 + l)*8);
    B10[g] = *(const s8v*)(wb2 + ((size_t)(8 + ct*2 + 0)*64 + l)*8);
    B11[g] = *(const s8v*)(wb2 + ((size_t)(8 + ct*2 + 1)*64 + l)*8);
    BC0[g] = *(const s8v*)(wb2 + ((size_t)(24 + ct*3 + 0)*64 + l)*8);
    BC1[g] = *(const s8v*)(wb2 + ((size_t)(24 + ct*3 + 1)*64 + l)*8);
    BC2[g] = *(const s8v*)(wb2 + ((size_t)(24 + ct*3 + 2)*64 + l)*8);
    bias0[g] = tb[col]; bias1[g] = tb[128+col];
    wtt[g] = tb[256+col]; wty[g] = tb[384+col];
  }
  __syncthreads();

  f4v pc[4];
  #pragma unroll
  for (int g=0; g<4; ++g){
    f4v a = {bias0[g], bias0[g], bias0[g], bias0[g]};
    {
      const s8v av = *(const s8v*)&CT[arow*96 + (((0*4+lq) ^ l3)<<3)];
      a = __builtin_amdgcn_mfma_f32_16x16x32_bf16(av, BC0[g], a, 0, 0, 0);
    }
    {
      const s8v av = *(const s8v*)&CT[arow*96 + (((1*4+lq) ^ l3)<<3)];
      a = __builtin_amdgcn_mfma_f32_16x16x32_bf16(av, BC1[g], a, 0, 0, 0);
    }
    {
      const s8v av = *(const s8v*)&CT[arow*96 + (((2*4+lq) ^ l3)<<3)];
      a = __builtin_amdgcn_mfma_f32_16x16x32_bf16(av, BC2[g], a, 0, 0, 0);
    }
    pc[g] = a;
  }

  int cur = 0;
  for (int s = 0; s < NOUT; ++s){
    const int nxt = cur ^ 1;
    #pragma unroll
    for (int i=0;i<4;++i) tt[i] = fmodf(tt[i] + 15.f, 1440.f);
    const s8v a0 = *(const s8v*)&Hh0[cur][aoff];
    f4v ac[4];
    #pragma unroll
    for (int g=0; g<4; ++g){
      f4v a = pc[g];
      #pragma unroll
      for (int i=0;i<4;++i) a[i] += tt[i]*wtt[g] + yv[i]*wty[g];
      ac[g] = __builtin_amdgcn_mfma_f32_16x16x32_bf16(a0, B0[g], a, 0, 0, 0);
    }
    unsigned short hw[4];
    #pragma unroll
    for (int i=0;i<4;++i){
      float iv = sg(ac[0][i]), fv = sg(ac[1][i]), gv = th(ac[2][i]), ov = sg(ac[3][i]);
      c0[i] = fv*c0[i] + iv*gv;
      hw[i] = f2b(ov*th(c0[i]));
    }
    if (u < HH){
      #pragma unroll
      for (int i=0;i<4;++i) Hh0[nxt][wr[i]] = hw[i];
    }
    __syncthreads();
    const s8v a1 = *(const s8v*)&Hh0[nxt][aoff];
    const s8v a2 = *(const s8v*)&Hh1[cur][aoff];
    #pragma unroll
    for (int g=0; g<4; ++g){
      f4v a = {bias1[g], bias1[g], bias1[g], bias1[g]};
      a = __builtin_amdgcn_mfma_f32_16x16x32_bf16(a1, B10[g], a, 0, 0, 0);
      ac[g] = __builtin_amdgcn_mfma_f32_16x16x32_bf16(a2, B11[g], a, 0, 0, 0);
    }
    #pragma unroll
    for (int i=0;i<4;++i){
      float iv = sg(ac[0][i]), fv = sg(ac[1][i]), gv = th(ac[2][i]), ov = sg(ac[3][i]);
      c1[i] = fv*c1[i] + iv*gv;
      hw[i] = f2b(ov*th(c1[i]));
    }
    if (u < HH){
      #pragma unroll
      for (int i=0;i<4;++i) Hh1[nxt][wr[i]] = hw[i];
    }
    __syncthreads();
    for (int i2 = tid; i2 < 64*HH; i2 += 512){
      int uu = i2 >> 6, sl = i2 & 63;
      unsigned short hv = Hh1[nxt][sl*32 + (((uu>>3) ^ (sl&3))<<3) + (uu&7)];
      *reinterpret_cast<unsigned short*>(&h1n[((size_t)s*HH + uu)*NB + (size_t)blk*64 + sl]) = hv;
    }
    #pragma unroll
    for (int i=0;i<4;++i) yv[i] = yT[(size_t)s*NB + gS[i]];
    cur = nxt;
  }
}

// ---------------- BN2 stats: contiguous-array reductions ----------------
// h features: one block per (s,u), contiguous 16K bf16 array, ushort8 loads
__global__ __launch_bounds__(256) void k_bn2h(
    const __hip_bfloat16* __restrict__ h1n, double* __restrict__ s2)
{
  __shared__ double sd[256];
  __shared__ double qd[256];
  const int s = blockIdx.x, u = blockIdx.y;
  const unsigned short* p = (const unsigned short*)(h1n + ((size_t)s*HH + u)*NB);
  double sv = 0.0, sq = 0.0;
  #pragma unroll
  for (int c = 0; c < 8; ++c){
    s8v v = *(const s8v*)(p + ((size_t)c*256 + threadIdx.x)*8);
    #pragma unroll
    for (int j=0;j<8;++j){
      float f = b2f((unsigned short)v[j]);
      sv += f; sq += (double)f*(double)f;
    }
  }
  sd[threadIdx.x] = sv; qd[threadIdx.x] = sq;
  __syncthreads();
  for (int st2=128; st2>0; st2>>=1){
    if ((int)threadIdx.x < st2){
      sd[threadIdx.x] += sd[threadIdx.x+st2];
      qd[threadIdx.x] += qd[threadIdx.x+st2];
    }
    __syncthreads();
  }
  if (threadIdx.x == 0){
    s2[((size_t)s*F2 + u)*2]   = sd[0];
    s2[((size_t)s*F2 + u)*2+1] = qd[0];
  }
}

// y feature: one block per s over contiguous ypack / yT columns, float4 loads
__global__ __launch_bounds__(256) void k_bn2y(
    const float* __restrict__ ypack, const float* __restrict__ yT, double* __restrict__ s2)
{
  __shared__ double sd[256];
  __shared__ double qd[256];
  const int s = blockIdx.x;
  const float* src = (s == 0) ? ypack : (yT + (size_t)(s-1)*NB);
  double sv = 0.0, sq = 0.0;
  #pragma unroll
  for (int c = 0; c < 16; ++c){
    float4 v = *(const float4*)(src + ((size_t)c*256 + threadIdx.x)*4);
    sv += (double)v.x + (double)v.y + (double)v.z + (double)v.w;
    sq += (double)v.x*v.x + (double)v.y*v.y + (double)v.z*v.z + (double)v.w*v.w;
  }
  sd[threadIdx.x] = sv; qd[threadIdx.x] = sq;
  __syncthreads();
  for (int st2=128; st2>0; st2>>=1){
    if ((int)threadIdx.x < st2){
      sd[threadIdx.x] += sd[threadIdx.x+st2];
      qd[threadIdx.x] += qd[threadIdx.x+st2];
    }
    __syncthreads();
  }
  if (threadIdx.x == 0){
    s2[((size_t)s*F2 + 51)*2]   = sd[0];
    s2[((size_t)s*F2 + 51)*2+1] = qd[0];
  }
}

// t feature: single pass, each thread owns one row's fmod chain
__global__ __launch_bounds__(256) void k_bn2t(
    const float* __restrict__ tpack, double* __restrict__ s2)
{
  const int r = blockIdx.x*256 + threadIdx.x;
  float t = tpack[r];
  const int lane = threadIdx.x & 63;
  for (int s = 0; s < NOUT; ++s){
    t = fmodf(t + 15.f, 1440.f);
    double sv = (double)t, sq = (double)t*(double)t;
    #pragma unroll
    for (int m=32;m>0;m>>=1){ sv += shfl_xor_d(sv,m); sq += shfl_xor_d(sq,m); }
    if (lane == 0){
      atomicAdd(&s2[((size_t)s*F2 + 50)*2],   sv);
      atomicAdd(&s2[((size_t)s*F2 + 50)*2+1], sq);
    }
  }
}

// finalize m2/r2 (xcg features reuse BN1 sums s1[60..79])
__global__ __launch_bounds__(256) void k_fin2b(
    const double* __restrict__ s1, const double* __restrict__ s2,
    float* __restrict__ m2, float* __restrict__ r2)
{
  int i = blockIdx.x*256 + threadIdx.x;
  if (i >= NOUT*F2) return;
  int f = i % F2;
  double sv, sq;
  if (f >= HH && f < HH+CVD){
    sv = s1[(2*HH + (f-HH))*2];
    sq = s1[(2*HH + (f-HH))*2+1];
  } else {
    sv = s2[i*2]; sq = s2[i*2+1];
  }
  double m = sv/(double)NB;
  double var = sq/(double)NB - m*m;
  if (var < 0.0) var = 0.0;
  m2[i] = (float)m;
  r2[i] = (float)(1.0/sqrt(var + 1e-5));
}

// ---------------- readout: MFMA GEMM with split-A bf16 ----------------
__global__ __launch_bounds__(256, 4) void k_rdm(
    const __hip_bfloat16* __restrict__ h1n, const float* __restrict__ xcg,
    const float* __restrict__ tpack, const float* __restrict__ ypack, const float* __restrict__ yT,
    const float* __restrict__ m2, const float* __restrict__ r2,
    const float* __restrict__ g2, const float* __restrict__ b2v,
    const unsigned short* __restrict__ wd5, const float* __restrict__ Bd,
    const float* __restrict__ Ud, const float* __restrict__ Cd,
    float* __restrict__ outT)
{
  __shared__ __align__(16) unsigned short FH[64*64];
  __shared__ __align__(16) unsigned short FL[64*64];
  __shared__ float scl[F2], sft[F2];
  const int tid = threadIdx.x, l = tid & 63, w = tid >> 6;
  const int lr = l & 15, lq = l >> 4;
  const int s = blockIdx.y, rr0 = blockIdx.x*64;
  if (tid < F2){
    float m = m2[s*F2+tid], rv = r2[s*F2+tid];
    float sc = rv * g2[tid];
    scl[tid] = sc;
    sft[tid] = b2v[tid] - m*sc;
  }
  __syncthreads();
  for (int i = tid; i < 64*64; i += 256){
    int f = i >> 6, r = i & 63;
    float v;
    if (f < HH) v = __bfloat162float(h1n[((size_t)s*HH + f)*NB + rr0 + r]);
    else if (f < HH+CVD) v = xcg[(size_t)(rr0+r)*CVD + (f-HH)];
    else if (f == 50){
      float t0 = tpack[rr0+r];
      for (int k=0;k<=s;++k) t0 = fmodf(t0 + 15.f, 1440.f);
      v = t0;
    }
    else if (f == 51) v = (s==0) ? ypack[rr0+r] : yT[(size_t)(s-1)*NB + rr0 + r];
    else v = 0.f;
    if (f < F2) v = v*scl[f] + sft[f];
    unsigned short hi = f2b(v);
    float lo = v - b2f(hi);
    int off = r*64 + ((((f>>3) ^ (r&7))&7)<<3) + (f&7);
    FH[off] = hi;
    FL[off] = f2b(lo);
  }
  __syncthreads();
  const int row = w*16 + lr;
  s8v ah[2], al[2];
  #pragma unroll
  for (int ks=0;ks<2;++ks){
    int ch = ((ks*4+lq) ^ (row&7)) & 7;
    ah[ks] = *(const s8v*)&FH[row*64 + ch*8];
    al[ks] = *(const s8v*)&FL[row*64 + ch*8];
  }
  f4v ps = {0.f,0.f,0.f,0.f};
  #pragma unroll 7
  for (int ct=0; ct<7; ++ct){
    int col = ct*16 + lr;
    float bd = (col < HID) ? Bd[(size_t)s*HID + col] : 0.f;
    f4v acc = {bd,bd,bd,bd};
    #pragma unroll
    for (int ks=0;ks<2;++ks){
      s8v B = *(const s8v*)(wd5 + ((size_t)(s*14 + ks*7 + ct)*512) + l*8);
      acc = __builtin_amdgcn_mfma_f32_16x16x32_bf16(ah[ks], B, acc, 0, 0, 0);
      acc = __builtin_amdgcn_mfma_f32_16x16x32_bf16(al[ks], B, acc, 0, 0, 0);
    }
    float ud = (col < HID) ? Ud[(size_t)s*HID + col] : 0.f;
    #pragma unroll
    for (int i=0;i<4;++i) ps[i] += fmaxf(acc[i], 0.f) * ud;
  }
  #pragma unroll
  for (int m=1; m<16; m<<=1){
    #pragma unroll
    for (int i=0;i<4;++i) ps[i] += __shfl_xor(ps[i], m, 64);
  }
  if (lr == 0){
    float cd = Cd[s];
    float4 o = { ps[0]+cd, ps[1]+cd, ps[2]+cd, ps[3]+cd };
    *(float4*)&outT[(size_t)s*NB + rr0 + w*16 + lq*4] = o;
  }
}

// ---------------- host ----------------
extern "C" void kernel_launch(void* const* d_in, const int* in_sizes, int n_in,
                              void* d_out, int out_size, void* d_ws, size_t ws_size,
                              hipStream_t stream)
{
  const float* x    = (const float*)d_in[0];
  const float* y    = (const float*)d_in[1];
  const float* h0i  = (const float*)d_in[2];
  const float* c0i  = (const float*)d_in[3];
  const float* wih0 = (const float*)d_in[4];
  const float* whh0 = (const float*)d_in[5];
  const float* bih0 = (const float*)d_in[6];
  const float* bhh0 = (const float*)d_in[7];
  const float* wih1 = (const float*)d_in[8];
  const float* whh1 = (const float*)d_in[9];
  const float* bih1 = (const float*)d_in[10];
  const float* bhh1 = (const float*)d_in[11];
  const float* w2ih0= (const float*)d_in[12];
  const float* w2hh0= (const float*)d_in[13];
  const float* b2ih0= (const float*)d_in[14];
  const float* b2hh0= (const float*)d_in[15];
  const float* w2ih1= (const float*)d_in[16];
  const float* w2hh1= (const float*)d_in[17];
  const float* b2ih1= (const float*)d_in[18];
  const float* b2hh1= (const float*)d_in[19];
  const float* c1w  = (const float*)d_in[20];
  const float* c1b  = (const float*)d_in[21];
  const float* c2w  = (const float*)d_in[22];
  const float* c2b  = (const float*)d_in[23];
  const float* c3w  = (const float*)d_in[24];
  const float* c3b  = (const float*)d_in[25];
  const float* fcw  = (const float*)d_in[26];
  const float* fcb  = (const float*)d_in[27];
  const float* bn1g = (const float*)d_in[28];
  const float* bn1b = (const float*)d_in[29];
  const float* bn2g = (const float*)d_in[30];
  const float* bn2b = (const float*)d_in[31];
  const float* Wd   = (const float*)d_in[32];
  const float* Bd   = (const float*)d_in[33];
  const float* Ud   = (const float*)d_in[34];
  const float* Cd   = (const float*)d_in[35];
  float* out = (float*)d_out;

  char* base = (char*)d_ws;
  size_t off = 0;
  auto take = [&](size_t bytes)->char*{
    char* p = base + off;
    off = (off + bytes + 255) & ~(size_t)255;
    return p;
  };
  float*  h0f = (float*) take((size_t)NB*HH*sizeof(float));
  float*  h1f = (float*) take((size_t)NB*HH*sizeof(float));
  float*  c0f = (float*) take((size_t)NB*HH*sizeof(float));
  float*  c1f = (float*) take((size_t)NB*HH*sizeof(float));
  float*  xcg = (float*) take((size_t)NB*CVD*sizeof(float));
  float*  ctx = (float*) take((size_t)NB*CTXD*sizeof(float));
  double* s1  = (double*)take((size_t)CTXD*2*sizeof(double));
  float*  st1 = (float*) take((size_t)CTXD*2*sizeof(float));
  double* s2  = (double*)take((size_t)NOUT*F2*2*sizeof(double));
  float*  m2  = (float*) take((size_t)NOUT*F2*sizeof(float));
  float*  r2  = (float*) take((size_t)NOUT*F2*sizeof(float));
  unsigned short* wb2 = (unsigned short*) take((size_t)48*512*sizeof(unsigned short));
  float*  tb  = (float*) take((size_t)4*128*sizeof(float));
  unsigned short* wb3 = (unsigned short*) take((size_t)32*512*sizeof(unsigned short));
  float*  tbe = (float*) take((size_t)2*128*sizeof(float));
  unsigned short* wc  = (unsigned short*) take((size_t)96*512*sizeof(unsigned short));
  unsigned short* wd5 = (unsigned short*) take((size_t)NOUT*14*512*sizeof(unsigned short));
  float*  tpk = (float*) take((size_t)NB*sizeof(float));
  float*  ypk = (float*) take((size_t)NB*sizeof(float));
  float*  yT  = (float*) take((size_t)NOUT*NB*sizeof(float));
  float*  oT  = (float*) take((size_t)NOUT*NB*sizeof(float));
  __hip_bfloat16* h1n = (__hip_bfloat16*) take((size_t)NOUT*HH*NB*sizeof(__hip_bfloat16));
  (void)ws_size;

  k_tw2<<<dim3((48*512+512+255)/256), dim3(256), 0, stream>>>(w2ih0, w2hh0, w2ih1, w2hh1,
      b2ih0, b2hh0, b2ih1, b2hh1, wb2, tb);
  k_tw3<<<dim3((32*512+256+255)/256), dim3(256), 0, stream>>>(wih0, whh0, wih1, whh1,
      bih0, bhh0, bih1, bhh1, wb3, tbe);
  k_tw4<<<dim3((96*512+255)/256), dim3(256), 0, stream>>>(c1w, c2w, c3w, fcw, wc);
  k_tw5<<<dim3((NOUT*14*512+255)/256), dim3(256), 0, stream>>>(Wd, wd5);
  k_pack<<<dim3(NB/256), dim3(256), 0, stream>>>(x, tpk, ypk);
  k_ty<<<dim3(NB/64), dim3(256), 0, stream>>>(y, yT);
  k_zero<<<dim3((NOUT*F2*2+255)/256), dim3(256), 0, stream>>>(s1, s2);
  k_encm<<<dim3(NB/64), dim3(512), 0, stream>>>(x, h0i, c0i, wb3, tbe, h0f, h1f, c0f, c1f);
  k_convm<<<dim3(NB/16), dim3(256), 0, stream>>>(x, wc, c1b, c2b, c3b, fcb, xcg);
  k_bn1s<<<dim3(NB/128), dim3(128), 0, stream>>>(h0f, h1f, xcg, s1);
  k_fin1<<<dim3(1), dim3(128), 0, stream>>>(s1, st1);
  k_context<<<dim3((NB*CTXD + 255)/256), dim3(256), 0, stream>>>(h0f, h1f, xcg, st1, bn1g, bn1b, ctx);
  k_dec1m<<<dim3(NB/64), dim3(512), 0, stream>>>(tpk, ypk, yT, ctx, wb2, tb,
      h0f, h1f, c0f, c1f, h1n);
  k_bn2h<<<dim3(NOUT, HH), dim3(256), 0, stream>>>(h1n, s2);
  k_bn2y<<<dim3(NOUT), dim3(256), 0, stream>>>(ypk, yT, s2);
  k_bn2t<<<dim3(NB/256), dim3(256), 0, stream>>>(tpk, s2);
  k_fin2b<<<dim3((NOUT*F2+255)/256), dim3(256), 0, stream>>>(s1, s2, m2, r2);
  k_rdm<<<dim3(NB/64, NOUT), dim3(256), 0, stream>>>(h1n, xcg, tpk, ypk, yT,
      m2, r2, bn2g, bn2b, wd5, Bd, Ud, Cd, oT);
  k_tro<<<dim3(NB/64), dim3(256), 0, stream>>>(oT, out);
}